// Round 1
// baseline (1981.093 us; speedup 1.0000x reference)
//
#include <hip/hip_runtime.h>
#include <stdint.h>

#define N_NODES   100000
#define N_EVENTS  50000
#define N_COMM    256
#define DIM_M     128
#define DIM_D     128
#define DIM_F     128
#define DIM_T     64
#define MSG_DIM   448   // 2D + F + T
#define GRU_TN    16

// ---------------- ws layout ----------------
// [0, 800000)            : keys  u64[N]
// [800000, 800004)       : cnt   u32
// [800008, 1200008)      : list  i32[N]
// [1200128, ...)         : partials f32 [8*NCH][32][128]
#define KEYS_BYTES   (N_NODES * 8)
#define CNT_OFF      KEYS_BYTES
#define LIST_OFF     (KEYS_BYTES + 8)
#define PART_OFF     1200128

// ---------- phase 1: per-node last-event via atomicMax on (t, idx+1) ----------
__global__ __launch_bounds__(256) void k_agg(const int* __restrict__ src,
                                             const int* __restrict__ dst,
                                             const int* __restrict__ t,
                                             unsigned long long* __restrict__ keys) {
    int i = blockIdx.x * 256 + threadIdx.x;
    if (i >= 2 * N_EVENTS) return;
    int e = (i < N_EVENTS) ? i : i - N_EVENTS;
    int node = (i < N_EVENTS) ? src[i] : dst[e];
    unsigned long long key =
        ((unsigned long long)(unsigned)t[e] << 32) | (unsigned)(i + 1);
    atomicMax(&keys[node], key);
}

// ---------- phase 2: compact list of nodes that received a message ----------
__global__ __launch_bounds__(256) void k_compact(const unsigned long long* __restrict__ keys,
                                                 unsigned int* __restrict__ cnt,
                                                 int* __restrict__ list) {
    int n = blockIdx.x * 256 + threadIdx.x;
    if (n >= N_NODES) return;
    if (keys[n] != 0ULL) {
        unsigned p = atomicAdd(cnt, 1u);
        list[p] = n;
    }
}

// ---------- phase 3: gather msg + GRU for message nodes ----------
__global__ __launch_bounds__(256) void k_gru(
    const unsigned long long* __restrict__ keys,
    const unsigned int* __restrict__ cnt,
    const int* __restrict__ list,
    const int* __restrict__ t,
    const int* __restrict__ last_update,
    const float* __restrict__ event_feat,
    const float* __restrict__ src_embeds,
    const float* __restrict__ dst_embeds,
    const float* __restrict__ mem,
    const float* __restrict__ w_time,
    const float* __restrict__ b_time,
    const float* __restrict__ W_ih,
    const float* __restrict__ W_hh,
    const float* __restrict__ b_ih,
    const float* __restrict__ b_hh,
    float* __restrict__ out) {
    __shared__ float msg_lds[GRU_TN][MSG_DIM + 1]; // 449: breaks bank alias
    __shared__ float mem_lds[GRU_TN][DIM_M + 1];   // 129

    const unsigned int c = *cnt;
    const int base = blockIdx.x * GRU_TN;
    if ((unsigned)base >= c) return;
    const int nv = min(GRU_TN, (int)(c - (unsigned)base));
    const int tid = threadIdx.x;

    { // staging: 16 threads per node
        const int snn = tid >> 4;
        const int l = tid & 15;
        if (snn < nv) {
            const int node = list[base + snn];
            const unsigned long long key = keys[node];
            const int ia = (int)(key & 0xffffffffull) - 1; // 0..2E-1
            const int e = (ia < N_EVENTS) ? ia : ia - N_EVENTS;
            const float* es = (ia < N_EVENTS) ? (src_embeds + (size_t)e * DIM_D)
                                              : (dst_embeds + (size_t)e * DIM_D);
            const float* ed = (ia < N_EVENTS) ? (dst_embeds + (size_t)e * DIM_D)
                                              : (src_embeds + (size_t)e * DIM_D);
            const float* ef = event_feat + (size_t)e * DIM_F;
            const float dt = (float)(t[e] - last_update[node]);
            for (int k = l; k < MSG_DIM; k += 16) {
                float v;
                if (k < 128) v = es[k];
                else if (k < 256) v = ed[k - 128];
                else if (k < 384) v = ef[k - 256];
                else {
                    int cix = k - 384;
                    // match numpy rounding: mul then add, no contraction
                    float arg = __fadd_rn(__fmul_rn(dt, w_time[cix]), b_time[cix]);
                    v = cosf(arg);
                }
                msg_lds[snn][k] = v;
            }
            const float* hm = mem + (size_t)node * DIM_M;
            for (int k = l; k < DIM_M; k += 16) mem_lds[snn][k] = hm[k];
        }
    }
    __syncthreads();

    const int nn = tid & 15;
    if (nn >= nv) return;
    const int grp = tid >> 4;
    const int m0 = grp * 8;
    const int node = list[base + nn];

    float xr[8], xz[8], xn[8], hr[8], hz[8], hn[8];
#pragma unroll
    for (int j = 0; j < 8; ++j) {
        xr[j] = b_ih[m0 + j];
        xz[j] = b_ih[128 + m0 + j];
        xn[j] = b_ih[256 + m0 + j];
        hr[j] = b_hh[m0 + j];
        hz[j] = b_hh[128 + m0 + j];
        hn[j] = b_hh[256 + m0 + j];
    }
    // gx = msg @ W_ih
    for (int k = 0; k < MSG_DIM; ++k) {
        const float a = msg_lds[nn][k];
        const float* row = W_ih + (size_t)k * 384;
#pragma unroll
        for (int j = 0; j < 8; ++j) xr[j] = fmaf(a, row[m0 + j], xr[j]);
#pragma unroll
        for (int j = 0; j < 8; ++j) xz[j] = fmaf(a, row[128 + m0 + j], xz[j]);
#pragma unroll
        for (int j = 0; j < 8; ++j) xn[j] = fmaf(a, row[256 + m0 + j], xn[j]);
    }
    // gh = h @ W_hh
    for (int k = 0; k < DIM_M; ++k) {
        const float a = mem_lds[nn][k];
        const float* row = W_hh + (size_t)k * 384;
#pragma unroll
        for (int j = 0; j < 8; ++j) hr[j] = fmaf(a, row[m0 + j], hr[j]);
#pragma unroll
        for (int j = 0; j < 8; ++j) hz[j] = fmaf(a, row[128 + m0 + j], hz[j]);
#pragma unroll
        for (int j = 0; j < 8; ++j) hn[j] = fmaf(a, row[256 + m0 + j], hn[j]);
    }
#pragma unroll
    for (int j = 0; j < 8; ++j) {
        float r = 1.0f / (1.0f + expf(-(xr[j] + hr[j])));
        float z = 1.0f / (1.0f + expf(-(xz[j] + hz[j])));
        float nl = tanhf(xn[j] + r * hn[j]);
        float h = mem_lds[nn][m0 + j];
        out[(size_t)node * DIM_M + m0 + j] = (1.0f - z) * nl + z * h;
    }
}

// ---------- phase 4: copy-through for nodes without messages ----------
__global__ __launch_bounds__(256) void k_copy(const unsigned long long* __restrict__ keys,
                                              const float* __restrict__ nm,
                                              float* __restrict__ out) {
    int idx = blockIdx.x * 256 + threadIdx.x; // float4 index, N*32 total
    int n = idx >> 5;
    if (n >= N_NODES) return;
    if (keys[n] == 0ULL) {
        ((float4*)out)[idx] = ((const float4*)nm)[idx];
    }
}

// ---------- phase 5a: comm partials: block = (c_tile, n_chunk) ----------
__global__ __launch_bounds__(256) void k_comm1(const float* __restrict__ inc,
                                               const float* __restrict__ nm,
                                               float* __restrict__ partials,
                                               int cpn) {
    const int bid = blockIdx.x;
    const int ct = bid & 7;
    const int ch = bid >> 3;
    const int n0 = ch * cpn;
    const int n1 = min(N_NODES, n0 + cpn);
    const int tid = threadIdx.x;
    const int cl = (tid & 7) * 4;   // 0..28 within 32-wide c tile
    const int m0 = (tid >> 3) * 4;  // 0..124

    float acc[4][4];
#pragma unroll
    for (int i = 0; i < 4; ++i)
#pragma unroll
        for (int j = 0; j < 4; ++j) acc[i][j] = 0.0f;

    const float* ip = inc + (size_t)n0 * N_COMM + ct * 32 + cl;
    const float* mp = nm + (size_t)n0 * DIM_M + m0;
    for (int n = n0; n < n1; ++n) {
        const float4 iv = *(const float4*)ip;
        const float4 mv = *(const float4*)mp;
        const float ia[4] = {iv.x, iv.y, iv.z, iv.w};
        const float ma[4] = {mv.x, mv.y, mv.z, mv.w};
#pragma unroll
        for (int i = 0; i < 4; ++i)
#pragma unroll
            for (int j = 0; j < 4; ++j) acc[i][j] = fmaf(ia[i], ma[j], acc[i][j]);
        ip += N_COMM;
        mp += DIM_M;
    }
    float* p = partials + (size_t)bid * 4096 + (size_t)cl * 128 + m0;
#pragma unroll
    for (int i = 0; i < 4; ++i) {
        float4 v = make_float4(acc[i][0], acc[i][1], acc[i][2], acc[i][3]);
        *(float4*)(p + (size_t)i * 128) = v;
    }
}

// ---------- phase 5b: reduce partials ----------
__global__ __launch_bounds__(256) void k_comm2(const float* __restrict__ partials,
                                               float* __restrict__ out,
                                               int nch) {
    int idx = blockIdx.x * 256 + threadIdx.x;
    if (idx >= N_COMM * DIM_M) return;
    int c0 = idx >> 7;
    int m = idx & 127;
    int ct = c0 >> 5;
    int cl = c0 & 31;
    float s = 0.0f;
    for (int ch = 0; ch < nch; ++ch)
        s += partials[((size_t)(ch * 8 + ct)) * 4096 + (size_t)cl * 128 + m];
    out[(size_t)N_NODES * DIM_M + idx] = s;
}

extern "C" void kernel_launch(void* const* d_in, const int* in_sizes, int n_in,
                              void* d_out, int out_size, void* d_ws, size_t ws_size,
                              hipStream_t stream) {
    const int* src          = (const int*)d_in[0];
    const int* dst          = (const int*)d_in[1];
    const int* t            = (const int*)d_in[2];
    const int* last_update  = (const int*)d_in[3];
    const float* event_feat = (const float*)d_in[4];
    const float* src_embeds = (const float*)d_in[5];
    const float* dst_embeds = (const float*)d_in[6];
    const float* nodes_mem  = (const float*)d_in[7];
    const float* incidence  = (const float*)d_in[8];
    const float* w_time     = (const float*)d_in[9];
    const float* b_time     = (const float*)d_in[10];
    const float* W_ih       = (const float*)d_in[11];
    const float* W_hh       = (const float*)d_in[12];
    const float* b_ih       = (const float*)d_in[13];
    const float* b_hh       = (const float*)d_in[14];
    float* out = (float*)d_out;

    char* ws = (char*)d_ws;
    unsigned long long* keys = (unsigned long long*)ws;
    unsigned int* cnt = (unsigned int*)(ws + CNT_OFF);
    int* list = (int*)(ws + LIST_OFF);
    float* partials = (float*)(ws + PART_OFF);

    int NCH = 128;
    while (NCH > 1 && (PART_OFF + (size_t)8 * NCH * 4096 * 4) > ws_size) NCH >>= 1;
    int cpn = (N_NODES + NCH - 1) / NCH;

    hipMemsetAsync(d_ws, 0, LIST_OFF, stream); // keys + cnt = 0

    k_agg<<<(2 * N_EVENTS + 255) / 256, 256, 0, stream>>>(src, dst, t, keys);
    k_compact<<<(N_NODES + 255) / 256, 256, 0, stream>>>(keys, cnt, list);
    k_gru<<<(N_NODES + GRU_TN - 1) / GRU_TN, 256, 0, stream>>>(
        keys, cnt, list, t, last_update, event_feat, src_embeds, dst_embeds,
        nodes_mem, w_time, b_time, W_ih, W_hh, b_ih, b_hh, out);
    k_copy<<<(N_NODES * (DIM_M / 4) + 255) / 256, 256, 0, stream>>>(keys, nodes_mem, out);
    k_comm1<<<8 * NCH, 256, 0, stream>>>(incidence, out, partials, cpn);
    k_comm2<<<(N_COMM * DIM_M + 255) / 256, 256, 0, stream>>>(partials, out, NCH);
}

// Round 2
// 465.292 us; speedup vs baseline: 4.2577x; 4.2577x over previous
//
#include <hip/hip_runtime.h>
#include <hip/hip_bf16.h>
#include <stdint.h>

#define N_NODES   100000
#define N_EVENTS  50000
#define N_COMM    256
#define DIM_M     128
#define MSG_DIM   448
#define K_TOT     576   // 448 msg + 128 mem
#define GCOLS     512   // r(128) z(128) xn(128) hn(128)

typedef float f32x4 __attribute__((ext_vector_type(4)));
typedef short s16x8 __attribute__((ext_vector_type(8)));

// ---------------- ws layout ----------------
#define KEYS_OFF  0                         // u64[N]
#define CNT_OFF   800000                    // u32
#define LIST_OFF  800008                    // i32[N]
#define TENC_OFF  1200128                   // bf16 [100032][64] = 12804096 B
#define WT_OFF    (TENC_OFF + 100032*128)   // 14004224; bf16 [512][576] = 589824 B
#define PART_OFF  (WT_OFF + 589824 + 32)    // 14594080; f32 partials

__device__ inline unsigned short f2bf(float x) {
    union { float f; unsigned u; } v; v.f = x;
    unsigned r = v.u + 0x7FFFu + ((v.u >> 16) & 1u);
    return (unsigned short)(r >> 16);
}

// ---------- phase 1: per-node last-event via atomicMax on (t<<32 | idx+1) ----------
__global__ __launch_bounds__(256) void k_agg(const int* __restrict__ src,
                                             const int* __restrict__ dst,
                                             const int* __restrict__ t,
                                             unsigned long long* __restrict__ keys) {
    int i = blockIdx.x * 256 + threadIdx.x;
    if (i >= 2 * N_EVENTS) return;
    int e = (i < N_EVENTS) ? i : i - N_EVENTS;
    int node = (i < N_EVENTS) ? src[i] : dst[e];
    unsigned long long key =
        ((unsigned long long)(unsigned)t[e] << 32) | (unsigned)(i + 1);
    atomicMax(&keys[node], key);
}

// ---------- phase 2: compact node list ----------
__global__ __launch_bounds__(256) void k_compact(const unsigned long long* __restrict__ keys,
                                                 unsigned int* __restrict__ cnt,
                                                 int* __restrict__ list) {
    int n = blockIdx.x * 256 + threadIdx.x;
    if (n >= N_NODES) return;
    if (keys[n] != 0ULL) {
        unsigned p = atomicAdd(cnt, 1u);
        list[p] = n;
    }
}

// ---------- phase 3a: time encodings (bf16) for compacted rows ----------
__global__ __launch_bounds__(256) void k_tenc(const unsigned long long* __restrict__ keys,
                                              const unsigned int* __restrict__ cnt,
                                              const int* __restrict__ list,
                                              const int* __restrict__ t,
                                              const int* __restrict__ last_update,
                                              const float* __restrict__ w_time,
                                              const float* __restrict__ b_time,
                                              unsigned short* __restrict__ tenc) {
    int idx = blockIdx.x * 256 + threadIdx.x;
    int r = idx >> 3, slot = idx & 7;
    const unsigned c = *cnt;
    const unsigned cpad = (c + 63u) & ~63u;
    if ((unsigned)r >= cpad) return;
    s16x8 v;
    if ((unsigned)r < c) {
        int node = list[r];
        unsigned long long key = keys[node];
        int ia = (int)(key & 0xffffffffull) - 1;
        int e = (ia < N_EVENTS) ? ia : ia - N_EVENTS;
        float dt = (float)(t[e] - last_update[node]);
#pragma unroll
        for (int j = 0; j < 8; ++j) {
            int cix = slot * 8 + j;
            float arg = __fadd_rn(__fmul_rn(dt, w_time[cix]), b_time[cix]);
            v[j] = (short)f2bf(cosf(arg));
        }
    } else {
#pragma unroll
        for (int j = 0; j < 8; ++j) v[j] = 0;
    }
    *(s16x8*)&tenc[(size_t)r * 64 + slot * 8] = v;
}

// ---------- phase 3b: fused gate weights, bf16, [col][k] (K-contiguous) ----------
__global__ __launch_bounds__(256) void k_wconv(const float* __restrict__ W_ih,
                                               const float* __restrict__ W_hh,
                                               unsigned short* __restrict__ Wt) {
    int idx = blockIdx.x * 256 + threadIdx.x;
    if (idx >= GCOLS * K_TOT) return;
    int col = idx / K_TOT, k = idx % K_TOT;
    float v;
    if (col < 256) {            // r,z gates: sum paths -> fuse K
        v = (k < 448) ? W_ih[(size_t)k * 384 + col]
                      : W_hh[(size_t)(k - 448) * 384 + col];
    } else if (col < 384) {     // xn: W_ih only
        v = (k < 448) ? W_ih[(size_t)k * 384 + col] : 0.0f;
    } else {                    // hn: W_hh only (gate col = col-128)
        v = (k < 448) ? 0.0f : W_hh[(size_t)(k - 448) * 384 + (col - 128)];
    }
    Wt[idx] = f2bf(v);
}

// ---------- phase 3c: MFMA GEMM + GRU epilogue ----------
// block: 64 rows x 512 cols, 4 waves. wave w owns col-tiles ct = w + 4*i (i=0..7)
// so r/z/xn/hn of m-tiles {w, w+4} land in the same lane for the epilogue.
__global__ __launch_bounds__(256, 2) void k_gemm(
    const unsigned long long* __restrict__ keys,
    const unsigned int* __restrict__ cnt,
    const int* __restrict__ list,
    const float* __restrict__ event_feat,
    const float* __restrict__ src_embeds,
    const float* __restrict__ dst_embeds,
    const float* __restrict__ mem,
    const unsigned short* __restrict__ tenc,
    const unsigned short* __restrict__ Wt,
    const float* __restrict__ b_ih,
    const float* __restrict__ b_hh,
    float* __restrict__ out) {
    __shared__ unsigned short Xs[2][4][64][8];  // [buf][kslot][row][8 bf16] = 16 KB

    const unsigned c = *cnt;
    const int base = blockIdx.x * 64;
    if ((unsigned)base >= c) return;
    const int tid = threadIdx.x;

    // ---- staging identity: thread owns (row = tid>>2, kslot = tid&3) ----
    const int srow = tid >> 2;
    const int kslot = tid & 3;
    const int sgrow = base + srow;
    const bool valid = (unsigned)sgrow < c;
    const float *p_es = nullptr, *p_ed = nullptr, *p_ef = nullptr, *p_mem = nullptr;
    const unsigned short* p_te = nullptr;
    if (valid) {
        int node = list[sgrow];
        unsigned long long key = keys[node];
        int ia = (int)(key & 0xffffffffull) - 1;
        int e = (ia < N_EVENTS) ? ia : ia - N_EVENTS;
        const float* sp = src_embeds + (size_t)e * 128;
        const float* dp = dst_embeds + (size_t)e * 128;
        p_es = (ia < N_EVENTS) ? sp : dp;
        p_ed = (ia < N_EVENTS) ? dp : sp;
        p_ef = event_feat + (size_t)e * 128;
        p_te = tenc + (size_t)sgrow * 64;
        p_mem = mem + (size_t)node * 128;
    }

    auto stage = [&](int ch) {
        const int buf = ch & 1;
        const int k0 = ch * 32 + kslot * 8;
        s16x8 v;
        if (valid) {
            if (k0 < 384) {  // embeds / event_feat (fp32 -> bf16)
                const float* p = (k0 < 128) ? (p_es + k0)
                               : (k0 < 256) ? (p_ed + (k0 - 128))
                                            : (p_ef + (k0 - 256));
                float4 a = *(const float4*)p;
                float4 b = *(const float4*)(p + 4);
                v[0] = (short)f2bf(a.x); v[1] = (short)f2bf(a.y);
                v[2] = (short)f2bf(a.z); v[3] = (short)f2bf(a.w);
                v[4] = (short)f2bf(b.x); v[5] = (short)f2bf(b.y);
                v[6] = (short)f2bf(b.z); v[7] = (short)f2bf(b.w);
            } else if (k0 < 448) {  // time-enc (already bf16)
                v = *(const s16x8*)(p_te + (k0 - 384));
            } else {                // node memory (fp32 -> bf16)
                const float* p = p_mem + (k0 - 448);
                float4 a = *(const float4*)p;
                float4 b = *(const float4*)(p + 4);
                v[0] = (short)f2bf(a.x); v[1] = (short)f2bf(a.y);
                v[2] = (short)f2bf(a.z); v[3] = (short)f2bf(a.w);
                v[4] = (short)f2bf(b.x); v[5] = (short)f2bf(b.y);
                v[6] = (short)f2bf(b.z); v[7] = (short)f2bf(b.w);
            }
        } else {
#pragma unroll
            for (int j = 0; j < 8; ++j) v[j] = 0;
        }
        *(s16x8*)&Xs[buf][kslot][srow][0] = v;
    };

    const int w = tid >> 6;     // wave id
    const int l = tid & 63;
    const int lr = l & 15;      // row/col within 16-tile
    const int lk = l >> 4;      // k-group

    f32x4 acc[4][8];
#pragma unroll
    for (int rt = 0; rt < 4; ++rt)
#pragma unroll
        for (int i = 0; i < 8; ++i) acc[rt][i] = (f32x4){0.f, 0.f, 0.f, 0.f};

    stage(0);
    __syncthreads();

    for (int ch = 0; ch < 18; ++ch) {
        if (ch < 17) stage(ch + 1);
        const int buf = ch & 1;
        s16x8 a[4];
#pragma unroll
        for (int rt = 0; rt < 4; ++rt)
            a[rt] = *(const s16x8*)&Xs[buf][lk][rt * 16 + lr][0];
#pragma unroll
        for (int i = 0; i < 8; ++i) {
            const int col = (w + 4 * i) * 16 + lr;
            s16x8 b = *(const s16x8*)&Wt[(size_t)col * K_TOT + ch * 32 + lk * 8];
#pragma unroll
            for (int rt = 0; rt < 4; ++rt)
                acc[rt][i] = __builtin_amdgcn_mfma_f32_16x16x32_bf16(
                    a[rt], b, acc[rt][i], 0, 0, 0);
        }
        __syncthreads();
    }

    // ---- epilogue: gates -> h_new, scatter to out ----
#pragma unroll
    for (int jj = 0; jj < 2; ++jj) {
        const int mbase = (w + 4 * jj) * 16;
        const int mcol = mbase + lr;
        const float b_r  = b_ih[mcol] + b_hh[mcol];
        const float b_z  = b_ih[128 + mcol] + b_hh[128 + mcol];
        const float b_xn = b_ih[256 + mcol];
        const float b_hn = b_hh[256 + mcol];
#pragma unroll
        for (int rt = 0; rt < 4; ++rt) {
#pragma unroll
            for (int reg = 0; reg < 4; ++reg) {
                const int grow = base + rt * 16 + lk * 4 + reg;
                if ((unsigned)grow < c) {
                    const int node = list[grow];
                    const float h = mem[(size_t)node * 128 + mcol];
                    float rr = acc[rt][0 + jj][reg] + b_r;
                    float zz = acc[rt][2 + jj][reg] + b_z;
                    float xn = acc[rt][4 + jj][reg] + b_xn;
                    float hn = acc[rt][6 + jj][reg] + b_hn;
                    rr = 1.0f / (1.0f + expf(-rr));
                    zz = 1.0f / (1.0f + expf(-zz));
                    float nn = tanhf(xn + rr * hn);
                    out[(size_t)node * 128 + mcol] = (1.0f - zz) * nn + zz * h;
                }
            }
        }
    }
}

// ---------- phase 4: copy-through for nodes without messages ----------
__global__ __launch_bounds__(256) void k_copy(const unsigned long long* __restrict__ keys,
                                              const float* __restrict__ nm,
                                              float* __restrict__ out) {
    int idx = blockIdx.x * 256 + threadIdx.x;
    int n = idx >> 5;
    if (n >= N_NODES) return;
    if (keys[n] != 0ULL) return;
    ((float4*)out)[idx] = ((const float4*)nm)[idx];
}

// ---------- phase 5a: comm partials. bid = ct*NCH + ch (ch fast => chunk on one XCD) ----------
__global__ __launch_bounds__(256) void k_comm1(const float* __restrict__ inc,
                                               const float* __restrict__ nm,
                                               float* __restrict__ partials,
                                               int nch, int cpn) {
    const int bid = blockIdx.x;
    const int ct = bid / nch;
    const int ch = bid % nch;
    const int n0 = ch * cpn;
    const int n1 = min(N_NODES, n0 + cpn);
    const int tid = threadIdx.x;
    const int cl = (tid & 7) * 4;
    const int m0 = (tid >> 3) * 4;

    float acc[4][4];
#pragma unroll
    for (int i = 0; i < 4; ++i)
#pragma unroll
        for (int j = 0; j < 4; ++j) acc[i][j] = 0.0f;

    const float* ip = inc + (size_t)n0 * N_COMM + ct * 32 + cl;
    const float* mp = nm + (size_t)n0 * DIM_M + m0;
    for (int n = n0; n < n1; ++n) {
        const float4 iv = *(const float4*)ip;
        const float4 mv = *(const float4*)mp;
        const float ia[4] = {iv.x, iv.y, iv.z, iv.w};
        const float ma[4] = {mv.x, mv.y, mv.z, mv.w};
#pragma unroll
        for (int i = 0; i < 4; ++i)
#pragma unroll
            for (int j = 0; j < 4; ++j) acc[i][j] = fmaf(ia[i], ma[j], acc[i][j]);
        ip += N_COMM;
        mp += DIM_M;
    }
    float* p = partials + (size_t)bid * 4096 + (size_t)cl * 128 + m0;
#pragma unroll
    for (int i = 0; i < 4; ++i)
        *(float4*)(p + (size_t)i * 128) =
            make_float4(acc[i][0], acc[i][1], acc[i][2], acc[i][3]);
}

// ---------- phase 5b: reduce partials ----------
__global__ __launch_bounds__(256) void k_comm2(const float* __restrict__ partials,
                                               float* __restrict__ out,
                                               int nch) {
    int idx = blockIdx.x * 256 + threadIdx.x;
    if (idx >= N_COMM * DIM_M) return;
    int c0 = idx >> 7;
    int m = idx & 127;
    int ct = c0 >> 5;
    int cl = c0 & 31;
    float s = 0.0f;
    for (int ch = 0; ch < nch; ++ch)
        s += partials[((size_t)ct * nch + ch) * 4096 + (size_t)cl * 128 + m];
    out[(size_t)N_NODES * DIM_M + idx] = s;
}

extern "C" void kernel_launch(void* const* d_in, const int* in_sizes, int n_in,
                              void* d_out, int out_size, void* d_ws, size_t ws_size,
                              hipStream_t stream) {
    const int* src          = (const int*)d_in[0];
    const int* dst          = (const int*)d_in[1];
    const int* t            = (const int*)d_in[2];
    const int* last_update  = (const int*)d_in[3];
    const float* event_feat = (const float*)d_in[4];
    const float* src_embeds = (const float*)d_in[5];
    const float* dst_embeds = (const float*)d_in[6];
    const float* nodes_mem  = (const float*)d_in[7];
    const float* incidence  = (const float*)d_in[8];
    const float* w_time     = (const float*)d_in[9];
    const float* b_time     = (const float*)d_in[10];
    const float* W_ih       = (const float*)d_in[11];
    const float* W_hh       = (const float*)d_in[12];
    const float* b_ih       = (const float*)d_in[13];
    const float* b_hh       = (const float*)d_in[14];
    float* out = (float*)d_out;

    char* ws = (char*)d_ws;
    unsigned long long* keys = (unsigned long long*)(ws + KEYS_OFF);
    unsigned int* cnt        = (unsigned int*)(ws + CNT_OFF);
    int* list                = (int*)(ws + LIST_OFF);
    unsigned short* tenc     = (unsigned short*)(ws + TENC_OFF);
    unsigned short* Wt       = (unsigned short*)(ws + WT_OFF);
    float* partials          = (float*)(ws + PART_OFF);

    int NCH = 256;
    while (NCH > 8 && (PART_OFF + (size_t)8 * NCH * 4096 * 4) > ws_size) NCH >>= 1;
    int cpn = (N_NODES + NCH - 1) / NCH;

    hipMemsetAsync(d_ws, 0, LIST_OFF, stream);  // keys + cnt

    k_agg<<<(2 * N_EVENTS + 255) / 256, 256, 0, stream>>>(src, dst, t, keys);
    k_compact<<<(N_NODES + 255) / 256, 256, 0, stream>>>(keys, cnt, list);
    k_tenc<<<(100032 * 8) / 256, 256, 0, stream>>>(keys, cnt, list, t, last_update,
                                                   w_time, b_time, tenc);
    k_wconv<<<(GCOLS * K_TOT + 255) / 256, 256, 0, stream>>>(W_ih, W_hh, Wt);
    k_gemm<<<100032 / 64, 256, 0, stream>>>(keys, cnt, list, event_feat, src_embeds,
                                            dst_embeds, nodes_mem, tenc, Wt,
                                            b_ih, b_hh, out);
    k_copy<<<(N_NODES * 32 + 255) / 256, 256, 0, stream>>>(keys, nodes_mem, out);
    k_comm1<<<8 * NCH, 256, 0, stream>>>(incidence, out, partials, NCH, cpn);
    k_comm2<<<(N_COMM * DIM_M + 255) / 256, 256, 0, stream>>>(partials, out, NCH);
}

// Round 3
// 418.107 us; speedup vs baseline: 4.7382x; 1.1129x over previous
//
#include <hip/hip_runtime.h>
#include <hip/hip_bf16.h>
#include <stdint.h>

#define N_NODES   100000
#define N_EVENTS  50000
#define N_COMM    256
#define DIM_M     128
#define MSG_DIM   448
#define K_TOT     576   // 448 msg + 128 mem
#define GCOLS     512   // r(128) z(128) xn(128) hn(128)

typedef float f32x4 __attribute__((ext_vector_type(4)));
typedef short s16x8 __attribute__((ext_vector_type(8)));

// ---------------- ws layout ----------------
#define KEYS_OFF  0                         // u64[N]
#define CNT_OFF   800000                    // u32
#define LIST_OFF  800008                    // i32[N]
#define TENC_OFF  1200128                   // bf16 [100032][64] = 12804096 B
#define WT_OFF    (TENC_OFF + 100032*128)   // bf16 [512][576]
#define PART_OFF  (WT_OFF + 589824 + 32)    // 14594080; f32 partials [2*NCH][128][128]

__device__ inline unsigned short f2bf(float x) {
    union { float f; unsigned u; } v; v.f = x;
    unsigned r = v.u + 0x7FFFu + ((v.u >> 16) & 1u);
    return (unsigned short)(r >> 16);
}

// ---------- phase 1: per-node last-event via atomicMax on (t<<32 | idx+1) ----------
__global__ __launch_bounds__(256) void k_agg(const int* __restrict__ src,
                                             const int* __restrict__ dst,
                                             const int* __restrict__ t,
                                             unsigned long long* __restrict__ keys) {
    int i = blockIdx.x * 256 + threadIdx.x;
    if (i >= 2 * N_EVENTS) return;
    int e = (i < N_EVENTS) ? i : i - N_EVENTS;
    int node = (i < N_EVENTS) ? src[i] : dst[e];
    unsigned long long key =
        ((unsigned long long)(unsigned)t[e] << 32) | (unsigned)(i + 1);
    atomicMax(&keys[node], key);
}

// ---------- phase 2: compact node list ----------
__global__ __launch_bounds__(256) void k_compact(const unsigned long long* __restrict__ keys,
                                                 unsigned int* __restrict__ cnt,
                                                 int* __restrict__ list) {
    int n = blockIdx.x * 256 + threadIdx.x;
    if (n >= N_NODES) return;
    if (keys[n] != 0ULL) {
        unsigned p = atomicAdd(cnt, 1u);
        list[p] = n;
    }
}

// ---------- phase 3a: time encodings (bf16) for compacted rows ----------
__global__ __launch_bounds__(256) void k_tenc(const unsigned long long* __restrict__ keys,
                                              const unsigned int* __restrict__ cnt,
                                              const int* __restrict__ list,
                                              const int* __restrict__ t,
                                              const int* __restrict__ last_update,
                                              const float* __restrict__ w_time,
                                              const float* __restrict__ b_time,
                                              unsigned short* __restrict__ tenc) {
    int idx = blockIdx.x * 256 + threadIdx.x;
    int r = idx >> 3, slot = idx & 7;
    const unsigned c = *cnt;
    const unsigned cpad = (c + 63u) & ~63u;
    if ((unsigned)r >= cpad) return;
    s16x8 v;
    if ((unsigned)r < c) {
        int node = list[r];
        unsigned long long key = keys[node];
        int ia = (int)(key & 0xffffffffull) - 1;
        int e = (ia < N_EVENTS) ? ia : ia - N_EVENTS;
        float dt = (float)(t[e] - last_update[node]);
#pragma unroll
        for (int j = 0; j < 8; ++j) {
            int cix = slot * 8 + j;
            float arg = __fadd_rn(__fmul_rn(dt, w_time[cix]), b_time[cix]);
            v[j] = (short)f2bf(cosf(arg));
        }
    } else {
#pragma unroll
        for (int j = 0; j < 8; ++j) v[j] = 0;
    }
    *(s16x8*)&tenc[(size_t)r * 64 + slot * 8] = v;
}

// ---------- phase 3b: fused gate weights, bf16, [col][k] (K-contiguous) ----------
__global__ __launch_bounds__(256) void k_wconv(const float* __restrict__ W_ih,
                                               const float* __restrict__ W_hh,
                                               unsigned short* __restrict__ Wt) {
    int idx = blockIdx.x * 256 + threadIdx.x;
    if (idx >= GCOLS * K_TOT) return;
    int col = idx / K_TOT, k = idx % K_TOT;
    float v;
    if (col < 256) {            // r,z gates: sum paths -> fuse K
        v = (k < 448) ? W_ih[(size_t)k * 384 + col]
                      : W_hh[(size_t)(k - 448) * 384 + col];
    } else if (col < 384) {     // xn: W_ih only
        v = (k < 448) ? W_ih[(size_t)k * 384 + col] : 0.0f;
    } else {                    // hn: W_hh only (gate col = col-128)
        v = (k < 448) ? 0.0f : W_hh[(size_t)(k - 448) * 384 + (col - 128)];
    }
    Wt[idx] = f2bf(v);
}

// ---------- phase 3c: MFMA GEMM + GRU epilogue ----------
__global__ __launch_bounds__(256, 2) void k_gemm(
    const unsigned long long* __restrict__ keys,
    const unsigned int* __restrict__ cnt,
    const int* __restrict__ list,
    const float* __restrict__ event_feat,
    const float* __restrict__ src_embeds,
    const float* __restrict__ dst_embeds,
    const float* __restrict__ mem,
    const unsigned short* __restrict__ tenc,
    const unsigned short* __restrict__ Wt,
    const float* __restrict__ b_ih,
    const float* __restrict__ b_hh,
    float* __restrict__ out) {
    __shared__ unsigned short Xs[2][4][64][8];  // [buf][kslot][row][8 bf16] = 16 KB

    const unsigned c = *cnt;
    const int base = blockIdx.x * 64;
    if ((unsigned)base >= c) return;
    const int tid = threadIdx.x;

    const int srow = tid >> 2;
    const int kslot = tid & 3;
    const int sgrow = base + srow;
    const bool valid = (unsigned)sgrow < c;
    const float *p_es = nullptr, *p_ed = nullptr, *p_ef = nullptr, *p_mem = nullptr;
    const unsigned short* p_te = nullptr;
    if (valid) {
        int node = list[sgrow];
        unsigned long long key = keys[node];
        int ia = (int)(key & 0xffffffffull) - 1;
        int e = (ia < N_EVENTS) ? ia : ia - N_EVENTS;
        const float* sp = src_embeds + (size_t)e * 128;
        const float* dp = dst_embeds + (size_t)e * 128;
        p_es = (ia < N_EVENTS) ? sp : dp;
        p_ed = (ia < N_EVENTS) ? dp : sp;
        p_ef = event_feat + (size_t)e * 128;
        p_te = tenc + (size_t)sgrow * 64;
        p_mem = mem + (size_t)node * 128;
    }

    auto stage = [&](int ch) {
        const int buf = ch & 1;
        const int k0 = ch * 32 + kslot * 8;
        s16x8 v;
        if (valid) {
            if (k0 < 384) {
                const float* p = (k0 < 128) ? (p_es + k0)
                               : (k0 < 256) ? (p_ed + (k0 - 128))
                                            : (p_ef + (k0 - 256));
                float4 a = *(const float4*)p;
                float4 b = *(const float4*)(p + 4);
                v[0] = (short)f2bf(a.x); v[1] = (short)f2bf(a.y);
                v[2] = (short)f2bf(a.z); v[3] = (short)f2bf(a.w);
                v[4] = (short)f2bf(b.x); v[5] = (short)f2bf(b.y);
                v[6] = (short)f2bf(b.z); v[7] = (short)f2bf(b.w);
            } else if (k0 < 448) {
                v = *(const s16x8*)(p_te + (k0 - 384));
            } else {
                const float* p = p_mem + (k0 - 448);
                float4 a = *(const float4*)p;
                float4 b = *(const float4*)(p + 4);
                v[0] = (short)f2bf(a.x); v[1] = (short)f2bf(a.y);
                v[2] = (short)f2bf(a.z); v[3] = (short)f2bf(a.w);
                v[4] = (short)f2bf(b.x); v[5] = (short)f2bf(b.y);
                v[6] = (short)f2bf(b.z); v[7] = (short)f2bf(b.w);
            }
        } else {
#pragma unroll
            for (int j = 0; j < 8; ++j) v[j] = 0;
        }
        *(s16x8*)&Xs[buf][kslot][srow][0] = v;
    };

    const int w = tid >> 6;
    const int l = tid & 63;
    const int lr = l & 15;
    const int lk = l >> 4;

    f32x4 acc[4][8];
#pragma unroll
    for (int rt = 0; rt < 4; ++rt)
#pragma unroll
        for (int i = 0; i < 8; ++i) acc[rt][i] = (f32x4){0.f, 0.f, 0.f, 0.f};

    stage(0);
    __syncthreads();

    for (int ch = 0; ch < 18; ++ch) {
        if (ch < 17) stage(ch + 1);
        const int buf = ch & 1;
        s16x8 a[4];
#pragma unroll
        for (int rt = 0; rt < 4; ++rt)
            a[rt] = *(const s16x8*)&Xs[buf][lk][rt * 16 + lr][0];
#pragma unroll
        for (int i = 0; i < 8; ++i) {
            const int col = (w + 4 * i) * 16 + lr;
            s16x8 b = *(const s16x8*)&Wt[(size_t)col * K_TOT + ch * 32 + lk * 8];
#pragma unroll
            for (int rt = 0; rt < 4; ++rt)
                acc[rt][i] = __builtin_amdgcn_mfma_f32_16x16x32_bf16(
                    a[rt], b, acc[rt][i], 0, 0, 0);
        }
        __syncthreads();
    }

#pragma unroll
    for (int jj = 0; jj < 2; ++jj) {
        const int mcol = (w + 4 * jj) * 16 + lr;
        const float b_r  = b_ih[mcol] + b_hh[mcol];
        const float b_z  = b_ih[128 + mcol] + b_hh[128 + mcol];
        const float b_xn = b_ih[256 + mcol];
        const float b_hn = b_hh[256 + mcol];
#pragma unroll
        for (int rt = 0; rt < 4; ++rt) {
#pragma unroll
            for (int reg = 0; reg < 4; ++reg) {
                const int grow = base + rt * 16 + lk * 4 + reg;
                if ((unsigned)grow < c) {
                    const int node = list[grow];
                    const float h = mem[(size_t)node * 128 + mcol];
                    float rr = acc[rt][0 + jj][reg] + b_r;
                    float zz = acc[rt][2 + jj][reg] + b_z;
                    float xn = acc[rt][4 + jj][reg] + b_xn;
                    float hn = acc[rt][6 + jj][reg] + b_hn;
                    rr = 1.0f / (1.0f + expf(-rr));
                    zz = 1.0f / (1.0f + expf(-zz));
                    float nn = tanhf(xn + rr * hn);
                    out[(size_t)node * 128 + mcol] = (1.0f - zz) * nn + zz * h;
                }
            }
        }
    }
}

// ---------- phase 4: copy-through for nodes without messages ----------
__global__ __launch_bounds__(256) void k_copy(const unsigned long long* __restrict__ keys,
                                              const float* __restrict__ nm,
                                              float* __restrict__ out) {
    int idx = blockIdx.x * 256 + threadIdx.x;
    int n = idx >> 5;
    if (n >= N_NODES) return;
    if (keys[n] != 0ULL) return;
    ((float4*)out)[idx] = ((const float4*)nm)[idx];
}

// ---------- phase 5a: LDS-staged tiled comm partials ----------
// block: 128 c (half) x 128 m x K-chunk. bid = ct2*nch + ch.
__global__ __launch_bounds__(256) void k_comm1(const float* __restrict__ inc,
                                               const float* __restrict__ nm,
                                               float* __restrict__ partials,
                                               int nch, int cpn) {
    __shared__ float inc_s[2][8][128];  // 4 KB x2
    __shared__ float mem_s[2][8][128];  // 4 KB x2

    const int bid = blockIdx.x;
    const int ct2 = bid / nch;            // 0..1 (c half)
    const int ch  = bid % nch;
    const int n0 = ch * cpn;
    const int n1 = min(N_NODES, n0 + cpn);
    const int tid = threadIdx.x;

    const int srow = tid >> 5;            // 0..7
    const int scol = (tid & 31) * 4;      // 0..124

    auto stage = [&](int g, int buf) {
        const int n = n0 + g * 8 + srow;
        float4 iv = make_float4(0.f, 0.f, 0.f, 0.f);
        float4 mv = make_float4(0.f, 0.f, 0.f, 0.f);
        if (n < n1) {
            iv = *(const float4*)(inc + (size_t)n * N_COMM + ct2 * 128 + scol);
            mv = *(const float4*)(nm + (size_t)n * DIM_M + scol);
        }
        *(float4*)&inc_s[buf][srow][scol] = iv;
        *(float4*)&mem_s[buf][srow][scol] = mv;
    };

    const int c0 = (tid >> 3) * 4;        // 0..124 (4 consecutive c)
    const int mb = (tid & 7) * 4;         // m = j*32 + mb, j=0..3

    float acc[4][4][4];                   // [ci][j][mi]
#pragma unroll
    for (int a = 0; a < 4; ++a)
#pragma unroll
        for (int b = 0; b < 4; ++b)
#pragma unroll
            for (int d = 0; d < 4; ++d) acc[a][b][d] = 0.0f;

    const int ngrp = (n1 - n0 + 7) >> 3;
    stage(0, 0);
    __syncthreads();

    for (int g = 0; g < ngrp; ++g) {
        if (g + 1 < ngrp) stage(g + 1, (g + 1) & 1);
        const int buf = g & 1;
#pragma unroll
        for (int i = 0; i < 8; ++i) {
            const float4 cv = *(const float4*)&inc_s[buf][i][c0];
            const float ca[4] = {cv.x, cv.y, cv.z, cv.w};
#pragma unroll
            for (int j = 0; j < 4; ++j) {
                const float4 mv = *(const float4*)&mem_s[buf][i][j * 32 + mb];
                const float ma[4] = {mv.x, mv.y, mv.z, mv.w};
#pragma unroll
                for (int ci = 0; ci < 4; ++ci)
#pragma unroll
                    for (int mi = 0; mi < 4; ++mi)
                        acc[ci][j][mi] = fmaf(ca[ci], ma[mi], acc[ci][j][mi]);
            }
        }
        __syncthreads();
    }

    float* p = partials + (size_t)bid * (128 * 128);
#pragma unroll
    for (int ci = 0; ci < 4; ++ci)
#pragma unroll
        for (int j = 0; j < 4; ++j)
            *(float4*)(p + (size_t)(c0 + ci) * 128 + j * 32 + mb) =
                make_float4(acc[ci][j][0], acc[ci][j][1], acc[ci][j][2], acc[ci][j][3]);
}

// ---------- phase 5b: reduce partials ----------
__global__ __launch_bounds__(256) void k_comm2(const float* __restrict__ partials,
                                               float* __restrict__ out,
                                               int nch) {
    int idx = blockIdx.x * 256 + threadIdx.x;
    if (idx >= N_COMM * DIM_M) return;
    int cg = idx >> 7;        // global c
    int m = idx & 127;
    int ct2 = cg >> 7;
    int cl = cg & 127;
    float s = 0.0f;
    for (int ch = 0; ch < nch; ++ch)
        s += partials[((size_t)ct2 * nch + ch) * 16384 + (size_t)cl * 128 + m];
    out[(size_t)N_NODES * DIM_M + idx] = s;
}

extern "C" void kernel_launch(void* const* d_in, const int* in_sizes, int n_in,
                              void* d_out, int out_size, void* d_ws, size_t ws_size,
                              hipStream_t stream) {
    const int* src          = (const int*)d_in[0];
    const int* dst          = (const int*)d_in[1];
    const int* t            = (const int*)d_in[2];
    const int* last_update  = (const int*)d_in[3];
    const float* event_feat = (const float*)d_in[4];
    const float* src_embeds = (const float*)d_in[5];
    const float* dst_embeds = (const float*)d_in[6];
    const float* nodes_mem  = (const float*)d_in[7];
    const float* incidence  = (const float*)d_in[8];
    const float* w_time     = (const float*)d_in[9];
    const float* b_time     = (const float*)d_in[10];
    const float* W_ih       = (const float*)d_in[11];
    const float* W_hh       = (const float*)d_in[12];
    const float* b_ih       = (const float*)d_in[13];
    const float* b_hh       = (const float*)d_in[14];
    float* out = (float*)d_out;

    char* ws = (char*)d_ws;
    unsigned long long* keys = (unsigned long long*)(ws + KEYS_OFF);
    unsigned int* cnt        = (unsigned int*)(ws + CNT_OFF);
    int* list                = (int*)(ws + LIST_OFF);
    unsigned short* tenc     = (unsigned short*)(ws + TENC_OFF);
    unsigned short* Wt       = (unsigned short*)(ws + WT_OFF);
    float* partials          = (float*)(ws + PART_OFF);

    // partials bytes = 2*NCH*128*128*4 = NCH*131072
    int NCH = 512;
    while (NCH > 8 && (PART_OFF + (size_t)NCH * 131072) > ws_size) NCH >>= 1;
    int cpn = (N_NODES + NCH - 1) / NCH;

    hipMemsetAsync(d_ws, 0, LIST_OFF, stream);  // keys + cnt

    k_agg<<<(2 * N_EVENTS + 255) / 256, 256, 0, stream>>>(src, dst, t, keys);
    k_compact<<<(N_NODES + 255) / 256, 256, 0, stream>>>(keys, cnt, list);
    k_tenc<<<(100032 * 8) / 256, 256, 0, stream>>>(keys, cnt, list, t, last_update,
                                                   w_time, b_time, tenc);
    k_wconv<<<(GCOLS * K_TOT + 255) / 256, 256, 0, stream>>>(W_ih, W_hh, Wt);
    k_gemm<<<100032 / 64, 256, 0, stream>>>(keys, cnt, list, event_feat, src_embeds,
                                            dst_embeds, nodes_mem, tenc, Wt,
                                            b_ih, b_hh, out);
    k_copy<<<(N_NODES * 32 + 255) / 256, 256, 0, stream>>>(keys, nodes_mem, out);
    k_comm1<<<2 * NCH, 256, 0, stream>>>(incidence, out, partials, NCH, cpn);
    k_comm2<<<(N_COMM * DIM_M + 255) / 256, 256, 0, stream>>>(partials, out, NCH);
}

// Round 4
// 404.591 us; speedup vs baseline: 4.8965x; 1.0334x over previous
//
#include <hip/hip_runtime.h>
#include <hip/hip_bf16.h>
#include <stdint.h>

#define N_NODES   100000
#define N_EVENTS  50000
#define N_COMM    256
#define DIM_M     128
#define K_TOT     576   // 448 msg + 128 mem
#define GCOLS     512   // r(128) z(128) xn(128) hn(128)

typedef float f32x4 __attribute__((ext_vector_type(4)));
typedef short s16x8 __attribute__((ext_vector_type(8)));

// ---------------- ws layout (unified) ----------------
#define KEYS_OFF   0                     // u64[N]
#define CNT_OFF    800000                // u32
#define LIST_OFF   800008                // i32[N] -> ends 1200008
#define WT_OFF     1200128               // bf16 [512][576] = 589824 -> ends 1789952
// new path:
#define X_OFF      1789952               // bf16 [100032][576] = 115236864
#define PART_N_OFF 117026816             // f32 partials [2*NCH][128][128]
// fallback path (overlaps X region):
#define TENC_OFF   1789952               // bf16 [100032][64] = 12804096
#define PART_F_OFF 14594048

__device__ inline unsigned short f2bf(float x) {
    union { float f; unsigned u; } v; v.f = x;
    unsigned r = v.u + 0x7FFFu + ((v.u >> 16) & 1u);
    return (unsigned short)(r >> 16);
}

// ---------- phase 1: per-node last-event via atomicMax on (t<<32 | idx+1) ----------
__global__ __launch_bounds__(256) void k_agg(const int* __restrict__ src,
                                             const int* __restrict__ dst,
                                             const int* __restrict__ t,
                                             unsigned long long* __restrict__ keys) {
    int i = blockIdx.x * 256 + threadIdx.x;
    if (i >= 2 * N_EVENTS) return;
    int e = (i < N_EVENTS) ? i : i - N_EVENTS;
    int node = (i < N_EVENTS) ? src[i] : dst[e];
    unsigned long long key =
        ((unsigned long long)(unsigned)t[e] << 32) | (unsigned)(i + 1);
    atomicMax(&keys[node], key);
}

// ---------- phase 2: compact node list ----------
__global__ __launch_bounds__(256) void k_compact(const unsigned long long* __restrict__ keys,
                                                 unsigned int* __restrict__ cnt,
                                                 int* __restrict__ list) {
    int n = blockIdx.x * 256 + threadIdx.x;
    if (n >= N_NODES) return;
    if (keys[n] != 0ULL) {
        unsigned p = atomicAdd(cnt, 1u);
        list[p] = n;
    }
}

// ---------- fused gate weights, bf16, [col][k] (K-contiguous) ----------
__global__ __launch_bounds__(256) void k_wconv(const float* __restrict__ W_ih,
                                               const float* __restrict__ W_hh,
                                               unsigned short* __restrict__ Wt) {
    int idx = blockIdx.x * 256 + threadIdx.x;
    if (idx >= GCOLS * K_TOT) return;
    int col = idx / K_TOT, k = idx % K_TOT;
    float v;
    if (col < 256) {
        v = (k < 448) ? W_ih[(size_t)k * 384 + col]
                      : W_hh[(size_t)(k - 448) * 384 + col];
    } else if (col < 384) {
        v = (k < 448) ? W_ih[(size_t)k * 384 + col] : 0.0f;
    } else {
        v = (k < 448) ? 0.0f : W_hh[(size_t)(k - 448) * 384 + (col - 128)];
    }
    Wt[idx] = f2bf(v);
}

// ---------- NEW phase 3a: build X = [msg | mem] in bf16, coalesced ----------
// row layout (bf16 x 576): [0,128) src-emb, [128,256) dst-emb, [256,384) feat,
// [384,448) cos time-enc, [448,576) node memory. 72 slots of 8 per row.
__global__ __launch_bounds__(256) void k_xbuild(
    const unsigned long long* __restrict__ keys,
    const unsigned int* __restrict__ cnt,
    const int* __restrict__ list,
    const int* __restrict__ t,
    const int* __restrict__ last_update,
    const float* __restrict__ event_feat,
    const float* __restrict__ src_embeds,
    const float* __restrict__ dst_embeds,
    const float* __restrict__ mem,
    const float* __restrict__ w_time,
    const float* __restrict__ b_time,
    unsigned short* __restrict__ X) {
    const unsigned c = *cnt;
    const unsigned cpad = (c + 127u) & ~127u;
    const unsigned total = cpad * 72u;
    for (unsigned idx = blockIdx.x * 256 + threadIdx.x; idx < total;
         idx += gridDim.x * 256) {
        const unsigned row = idx / 72u;
        const int s = (int)(idx - row * 72u);
        unsigned short* xp = X + (size_t)row * K_TOT + s * 8;
        s16x8 v;
        if (row >= c) {
#pragma unroll
            for (int j = 0; j < 8; ++j) v[j] = 0;
            *(s16x8*)xp = v;
            continue;
        }
        const int node = list[row];
        const unsigned long long key = keys[node];
        const int ia = (int)(key & 0xffffffffull) - 1;
        const int e = (ia < N_EVENTS) ? ia : ia - N_EVENTS;
        if (s < 48) {
            const float* p;
            if (s < 16)
                p = ((ia < N_EVENTS) ? src_embeds : dst_embeds) + (size_t)e * 128 + s * 8;
            else if (s < 32)
                p = ((ia < N_EVENTS) ? dst_embeds : src_embeds) + (size_t)e * 128 + (s - 16) * 8;
            else
                p = event_feat + (size_t)e * 128 + (s - 32) * 8;
            float4 a = *(const float4*)p;
            float4 b = *(const float4*)(p + 4);
            v[0] = (short)f2bf(a.x); v[1] = (short)f2bf(a.y);
            v[2] = (short)f2bf(a.z); v[3] = (short)f2bf(a.w);
            v[4] = (short)f2bf(b.x); v[5] = (short)f2bf(b.y);
            v[6] = (short)f2bf(b.z); v[7] = (short)f2bf(b.w);
        } else if (s < 56) {
            const float dt = (float)(t[e] - last_update[node]);
            const int c0 = (s - 48) * 8;
#pragma unroll
            for (int j = 0; j < 8; ++j) {
                float arg = __fadd_rn(__fmul_rn(dt, w_time[c0 + j]), b_time[c0 + j]);
                v[j] = (short)f2bf(cosf(arg));
            }
        } else {
            const float* p = mem + (size_t)node * 128 + (s - 56) * 8;
            float4 a = *(const float4*)p;
            float4 b = *(const float4*)(p + 4);
            v[0] = (short)f2bf(a.x); v[1] = (short)f2bf(a.y);
            v[2] = (short)f2bf(a.z); v[3] = (short)f2bf(a.w);
            v[4] = (short)f2bf(b.x); v[5] = (short)f2bf(b.y);
            v[6] = (short)f2bf(b.z); v[7] = (short)f2bf(b.w);
        }
        *(s16x8*)xp = v;
    }
}

// ---------- NEW phase 3b: streaming MFMA GEMM + GRU epilogue ----------
// A = X (linear, via global_load_lds), B = Wt (L2). 64 rows x 512 cols, BK=64.
__global__ __launch_bounds__(256, 2) void k_gemm_stream(
    const unsigned int* __restrict__ cnt,
    const int* __restrict__ list,
    const unsigned short* __restrict__ X,
    const unsigned short* __restrict__ Wt,
    const float* __restrict__ mem,
    const float* __restrict__ b_ih,
    const float* __restrict__ b_hh,
    float* __restrict__ out) {
    __shared__ unsigned short As[2][64][64];  // [buf][row][64 bf16 = 8 slots] 16 KB

    const unsigned c = *cnt;
    const int base = blockIdx.x * 64;
    if ((unsigned)base >= c) return;
    const int tid = threadIdx.x;
    const int w = tid >> 6;
    const int l = tid & 63;
    const int lr = l & 15;
    const int lk = l >> 4;

    // staging mapping: per wave, call j covers rows w*16+j*8 .. +7, 8 slots each.
    const int sr_in = l >> 3;          // 0..7
    const int sd = l & 7;              // dest slot

    auto stage = [&](int ch) {
        const int buf = ch & 1;
#pragma unroll
        for (int j = 0; j < 2; ++j) {
            const int r = w * 16 + j * 8 + sr_in;
            // dest slot sd at row r holds source slot sd ^ (r&7)
            const unsigned short* g =
                X + (size_t)(base + r) * K_TOT + ch * 64 + ((sd ^ (r & 7)) << 3);
            __builtin_amdgcn_global_load_lds(
                (const __attribute__((address_space(1))) unsigned int*)g,
                (__attribute__((address_space(3))) unsigned int*)&As[buf][w * 16 + j * 8][0],
                16, 0, 0);
        }
    };

    f32x4 acc[4][8];
#pragma unroll
    for (int rt = 0; rt < 4; ++rt)
#pragma unroll
        for (int i = 0; i < 8; ++i) acc[rt][i] = (f32x4){0.f, 0.f, 0.f, 0.f};

    stage(0);
    __syncthreads();

    for (int ch = 0; ch < 9; ++ch) {
        if (ch < 8) stage(ch + 1);
        const int buf = ch & 1;
#pragma unroll
        for (int ks = 0; ks < 2; ++ks) {
            s16x8 a[4];
#pragma unroll
            for (int rt = 0; rt < 4; ++rt) {
                const int r = rt * 16 + lr;
                const int sl = (ks * 4 + lk) ^ (r & 7);
                a[rt] = *(const s16x8*)&As[buf][r][sl << 3];
            }
#pragma unroll
            for (int i = 0; i < 8; ++i) {
                const int col = (w + 4 * i) * 16 + lr;
                s16x8 b = *(const s16x8*)&Wt[(size_t)col * K_TOT + ch * 64 + ks * 32 + lk * 8];
#pragma unroll
                for (int rt = 0; rt < 4; ++rt)
                    acc[rt][i] = __builtin_amdgcn_mfma_f32_16x16x32_bf16(
                        a[rt], b, acc[rt][i], 0, 0, 0);
            }
        }
        __syncthreads();
    }

    // ---- epilogue: gates -> h_new, scatter ----
#pragma unroll
    for (int jj = 0; jj < 2; ++jj) {
        const int mcol = (w + 4 * jj) * 16 + lr;
        const float b_r  = b_ih[mcol] + b_hh[mcol];
        const float b_z  = b_ih[128 + mcol] + b_hh[128 + mcol];
        const float b_xn = b_ih[256 + mcol];
        const float b_hn = b_hh[256 + mcol];
#pragma unroll
        for (int rt = 0; rt < 4; ++rt) {
#pragma unroll
            for (int reg = 0; reg < 4; ++reg) {
                const int grow = base + rt * 16 + lk * 4 + reg;
                if ((unsigned)grow < c) {
                    const int node = list[grow];
                    const float h = mem[(size_t)node * 128 + mcol];
                    float rr = acc[rt][0 + jj][reg] + b_r;
                    float zz = acc[rt][2 + jj][reg] + b_z;
                    float xn = acc[rt][4 + jj][reg] + b_xn;
                    float hn = acc[rt][6 + jj][reg] + b_hn;
                    rr = 1.0f / (1.0f + expf(-rr));
                    zz = 1.0f / (1.0f + expf(-zz));
                    float nn = tanhf(xn + rr * hn);
                    out[(size_t)node * 128 + mcol] = (1.0f - zz) * nn + zz * h;
                }
            }
        }
    }
}

// ---------- FALLBACK phase 3a: time encodings ----------
__global__ __launch_bounds__(256) void k_tenc(const unsigned long long* __restrict__ keys,
                                              const unsigned int* __restrict__ cnt,
                                              const int* __restrict__ list,
                                              const int* __restrict__ t,
                                              const int* __restrict__ last_update,
                                              const float* __restrict__ w_time,
                                              const float* __restrict__ b_time,
                                              unsigned short* __restrict__ tenc) {
    int idx = blockIdx.x * 256 + threadIdx.x;
    int r = idx >> 3, slot = idx & 7;
    const unsigned c = *cnt;
    const unsigned cpad = (c + 63u) & ~63u;
    if ((unsigned)r >= cpad) return;
    s16x8 v;
    if ((unsigned)r < c) {
        int node = list[r];
        unsigned long long key = keys[node];
        int ia = (int)(key & 0xffffffffull) - 1;
        int e = (ia < N_EVENTS) ? ia : ia - N_EVENTS;
        float dt = (float)(t[e] - last_update[node]);
#pragma unroll
        for (int j = 0; j < 8; ++j) {
            int cix = slot * 8 + j;
            float arg = __fadd_rn(__fmul_rn(dt, w_time[cix]), b_time[cix]);
            v[j] = (short)f2bf(cosf(arg));
        }
    } else {
#pragma unroll
        for (int j = 0; j < 8; ++j) v[j] = 0;
    }
    *(s16x8*)&tenc[(size_t)r * 64 + slot * 8] = v;
}

// ---------- FALLBACK phase 3b: fused gather MFMA GEMM ----------
__global__ __launch_bounds__(256, 2) void k_gemm_fused(
    const unsigned long long* __restrict__ keys,
    const unsigned int* __restrict__ cnt,
    const int* __restrict__ list,
    const float* __restrict__ event_feat,
    const float* __restrict__ src_embeds,
    const float* __restrict__ dst_embeds,
    const float* __restrict__ mem,
    const unsigned short* __restrict__ tenc,
    const unsigned short* __restrict__ Wt,
    const float* __restrict__ b_ih,
    const float* __restrict__ b_hh,
    float* __restrict__ out) {
    __shared__ unsigned short Xs[2][4][64][8];

    const unsigned c = *cnt;
    const int base = blockIdx.x * 64;
    if ((unsigned)base >= c) return;
    const int tid = threadIdx.x;

    const int srow = tid >> 2;
    const int kslot = tid & 3;
    const int sgrow = base + srow;
    const bool valid = (unsigned)sgrow < c;
    const float *p_es = nullptr, *p_ed = nullptr, *p_ef = nullptr, *p_mem = nullptr;
    const unsigned short* p_te = nullptr;
    if (valid) {
        int node = list[sgrow];
        unsigned long long key = keys[node];
        int ia = (int)(key & 0xffffffffull) - 1;
        int e = (ia < N_EVENTS) ? ia : ia - N_EVENTS;
        const float* sp = src_embeds + (size_t)e * 128;
        const float* dp = dst_embeds + (size_t)e * 128;
        p_es = (ia < N_EVENTS) ? sp : dp;
        p_ed = (ia < N_EVENTS) ? dp : sp;
        p_ef = event_feat + (size_t)e * 128;
        p_te = tenc + (size_t)sgrow * 64;
        p_mem = mem + (size_t)node * 128;
    }

    auto stage = [&](int ch) {
        const int buf = ch & 1;
        const int k0 = ch * 32 + kslot * 8;
        s16x8 v;
        if (valid) {
            if (k0 < 384) {
                const float* p = (k0 < 128) ? (p_es + k0)
                               : (k0 < 256) ? (p_ed + (k0 - 128))
                                            : (p_ef + (k0 - 256));
                float4 a = *(const float4*)p;
                float4 b = *(const float4*)(p + 4);
                v[0] = (short)f2bf(a.x); v[1] = (short)f2bf(a.y);
                v[2] = (short)f2bf(a.z); v[3] = (short)f2bf(a.w);
                v[4] = (short)f2bf(b.x); v[5] = (short)f2bf(b.y);
                v[6] = (short)f2bf(b.z); v[7] = (short)f2bf(b.w);
            } else if (k0 < 448) {
                v = *(const s16x8*)(p_te + (k0 - 384));
            } else {
                const float* p = p_mem + (k0 - 448);
                float4 a = *(const float4*)p;
                float4 b = *(const float4*)(p + 4);
                v[0] = (short)f2bf(a.x); v[1] = (short)f2bf(a.y);
                v[2] = (short)f2bf(a.z); v[3] = (short)f2bf(a.w);
                v[4] = (short)f2bf(b.x); v[5] = (short)f2bf(b.y);
                v[6] = (short)f2bf(b.z); v[7] = (short)f2bf(b.w);
            }
        } else {
#pragma unroll
            for (int j = 0; j < 8; ++j) v[j] = 0;
        }
        *(s16x8*)&Xs[buf][kslot][srow][0] = v;
    };

    const int w = tid >> 6;
    const int l = tid & 63;
    const int lr = l & 15;
    const int lk = l >> 4;

    f32x4 acc[4][8];
#pragma unroll
    for (int rt = 0; rt < 4; ++rt)
#pragma unroll
        for (int i = 0; i < 8; ++i) acc[rt][i] = (f32x4){0.f, 0.f, 0.f, 0.f};

    stage(0);
    __syncthreads();

    for (int ch = 0; ch < 18; ++ch) {
        if (ch < 17) stage(ch + 1);
        const int buf = ch & 1;
        s16x8 a[4];
#pragma unroll
        for (int rt = 0; rt < 4; ++rt)
            a[rt] = *(const s16x8*)&Xs[buf][lk][rt * 16 + lr][0];
#pragma unroll
        for (int i = 0; i < 8; ++i) {
            const int col = (w + 4 * i) * 16 + lr;
            s16x8 b = *(const s16x8*)&Wt[(size_t)col * K_TOT + ch * 32 + lk * 8];
#pragma unroll
            for (int rt = 0; rt < 4; ++rt)
                acc[rt][i] = __builtin_amdgcn_mfma_f32_16x16x32_bf16(
                    a[rt], b, acc[rt][i], 0, 0, 0);
        }
        __syncthreads();
    }

#pragma unroll
    for (int jj = 0; jj < 2; ++jj) {
        const int mcol = (w + 4 * jj) * 16 + lr;
        const float b_r  = b_ih[mcol] + b_hh[mcol];
        const float b_z  = b_ih[128 + mcol] + b_hh[128 + mcol];
        const float b_xn = b_ih[256 + mcol];
        const float b_hn = b_hh[256 + mcol];
#pragma unroll
        for (int rt = 0; rt < 4; ++rt) {
#pragma unroll
            for (int reg = 0; reg < 4; ++reg) {
                const int grow = base + rt * 16 + lk * 4 + reg;
                if ((unsigned)grow < c) {
                    const int node = list[grow];
                    const float h = mem[(size_t)node * 128 + mcol];
                    float rr = acc[rt][0 + jj][reg] + b_r;
                    float zz = acc[rt][2 + jj][reg] + b_z;
                    float xn = acc[rt][4 + jj][reg] + b_xn;
                    float hn = acc[rt][6 + jj][reg] + b_hn;
                    rr = 1.0f / (1.0f + expf(-rr));
                    zz = 1.0f / (1.0f + expf(-zz));
                    float nn = tanhf(xn + rr * hn);
                    out[(size_t)node * 128 + mcol] = (1.0f - zz) * nn + zz * h;
                }
            }
        }
    }
}

// ---------- phase 4: copy-through for nodes without messages ----------
__global__ __launch_bounds__(256) void k_copy(const unsigned long long* __restrict__ keys,
                                              const float* __restrict__ nm,
                                              float* __restrict__ out) {
    int idx = blockIdx.x * 256 + threadIdx.x;
    int n = idx >> 5;
    if (n >= N_NODES) return;
    if (keys[n] != 0ULL) return;
    ((float4*)out)[idx] = ((const float4*)nm)[idx];
}

// ---------- phase 5a: LDS-staged tiled comm partials ----------
__global__ __launch_bounds__(256) void k_comm1(const float* __restrict__ inc,
                                               const float* __restrict__ nm,
                                               float* __restrict__ partials,
                                               int nch, int cpn) {
    __shared__ float inc_s[2][8][128];
    __shared__ float mem_s[2][8][128];

    const int bid = blockIdx.x;
    const int ct2 = bid / nch;
    const int ch  = bid % nch;
    const int n0 = ch * cpn;
    const int n1 = min(N_NODES, n0 + cpn);
    const int tid = threadIdx.x;

    const int srow = tid >> 5;
    const int scol = (tid & 31) * 4;

    auto stage = [&](int g, int buf) {
        const int n = n0 + g * 8 + srow;
        float4 iv = make_float4(0.f, 0.f, 0.f, 0.f);
        float4 mv = make_float4(0.f, 0.f, 0.f, 0.f);
        if (n < n1) {
            iv = *(const float4*)(inc + (size_t)n * N_COMM + ct2 * 128 + scol);
            mv = *(const float4*)(nm + (size_t)n * DIM_M + scol);
        }
        *(float4*)&inc_s[buf][srow][scol] = iv;
        *(float4*)&mem_s[buf][srow][scol] = mv;
    };

    const int c0 = (tid >> 3) * 4;
    const int mb = (tid & 7) * 4;

    float acc[4][4][4];
#pragma unroll
    for (int a = 0; a < 4; ++a)
#pragma unroll
        for (int b = 0; b < 4; ++b)
#pragma unroll
            for (int d = 0; d < 4; ++d) acc[a][b][d] = 0.0f;

    const int ngrp = (n1 - n0 + 7) >> 3;
    stage(0, 0);
    __syncthreads();

    for (int g = 0; g < ngrp; ++g) {
        if (g + 1 < ngrp) stage(g + 1, (g + 1) & 1);
        const int buf = g & 1;
#pragma unroll
        for (int i = 0; i < 8; ++i) {
            const float4 cv = *(const float4*)&inc_s[buf][i][c0];
            const float ca[4] = {cv.x, cv.y, cv.z, cv.w};
#pragma unroll
            for (int j = 0; j < 4; ++j) {
                const float4 mv = *(const float4*)&mem_s[buf][i][j * 32 + mb];
                const float ma[4] = {mv.x, mv.y, mv.z, mv.w};
#pragma unroll
                for (int ci = 0; ci < 4; ++ci)
#pragma unroll
                    for (int mi = 0; mi < 4; ++mi)
                        acc[ci][j][mi] = fmaf(ca[ci], ma[mi], acc[ci][j][mi]);
            }
        }
        __syncthreads();
    }

    float* p = partials + (size_t)bid * (128 * 128);
#pragma unroll
    for (int ci = 0; ci < 4; ++ci)
#pragma unroll
        for (int j = 0; j < 4; ++j)
            *(float4*)(p + (size_t)(c0 + ci) * 128 + j * 32 + mb) =
                make_float4(acc[ci][j][0], acc[ci][j][1], acc[ci][j][2], acc[ci][j][3]);
}

// ---------- phase 5b: reduce partials ----------
__global__ __launch_bounds__(256) void k_comm2(const float* __restrict__ partials,
                                               float* __restrict__ out,
                                               int nch) {
    int idx = blockIdx.x * 256 + threadIdx.x;
    if (idx >= N_COMM * DIM_M) return;
    int cg = idx >> 7;
    int m = idx & 127;
    int ct2 = cg >> 7;
    int cl = cg & 127;
    float s = 0.0f;
    for (int ch = 0; ch < nch; ++ch)
        s += partials[((size_t)ct2 * nch + ch) * 16384 + (size_t)cl * 128 + m];
    out[(size_t)N_NODES * DIM_M + idx] = s;
}

extern "C" void kernel_launch(void* const* d_in, const int* in_sizes, int n_in,
                              void* d_out, int out_size, void* d_ws, size_t ws_size,
                              hipStream_t stream) {
    const int* src          = (const int*)d_in[0];
    const int* dst          = (const int*)d_in[1];
    const int* t            = (const int*)d_in[2];
    const int* last_update  = (const int*)d_in[3];
    const float* event_feat = (const float*)d_in[4];
    const float* src_embeds = (const float*)d_in[5];
    const float* dst_embeds = (const float*)d_in[6];
    const float* nodes_mem  = (const float*)d_in[7];
    const float* incidence  = (const float*)d_in[8];
    const float* w_time     = (const float*)d_in[9];
    const float* b_time     = (const float*)d_in[10];
    const float* W_ih       = (const float*)d_in[11];
    const float* W_hh       = (const float*)d_in[12];
    const float* b_ih       = (const float*)d_in[13];
    const float* b_hh       = (const float*)d_in[14];
    float* out = (float*)d_out;

    char* ws = (char*)d_ws;
    unsigned long long* keys = (unsigned long long*)(ws + KEYS_OFF);
    unsigned int* cnt        = (unsigned int*)(ws + CNT_OFF);
    int* list                = (int*)(ws + LIST_OFF);
    unsigned short* Wt       = (unsigned short*)(ws + WT_OFF);

    const bool xfit = ws_size >= (size_t)PART_N_OFF + 64ull * 131072ull;

    hipMemsetAsync(d_ws, 0, LIST_OFF, stream);  // keys + cnt

    k_agg<<<(2 * N_EVENTS + 255) / 256, 256, 0, stream>>>(src, dst, t, keys);
    k_compact<<<(N_NODES + 255) / 256, 256, 0, stream>>>(keys, cnt, list);
    k_wconv<<<(GCOLS * K_TOT + 255) / 256, 256, 0, stream>>>(W_ih, W_hh, Wt);

    if (xfit) {
        unsigned short* X = (unsigned short*)(ws + X_OFF);
        float* partials   = (float*)(ws + PART_N_OFF);
        int NCH = 256;
        while (NCH > 64 && (size_t)PART_N_OFF + (size_t)NCH * 131072 > ws_size) NCH >>= 1;
        int cpn = (N_NODES + NCH - 1) / NCH;

        k_xbuild<<<4096, 256, 0, stream>>>(keys, cnt, list, t, last_update,
                                           event_feat, src_embeds, dst_embeds,
                                           nodes_mem, w_time, b_time, X);
        k_gemm_stream<<<100032 / 64, 256, 0, stream>>>(cnt, list, X, Wt, nodes_mem,
                                                       b_ih, b_hh, out);
        k_copy<<<(N_NODES * 32 + 255) / 256, 256, 0, stream>>>(keys, nodes_mem, out);
        k_comm1<<<2 * NCH, 256, 0, stream>>>(incidence, out, partials, NCH, cpn);
        k_comm2<<<(N_COMM * DIM_M + 255) / 256, 256, 0, stream>>>(partials, out, NCH);
    } else {
        unsigned short* tenc = (unsigned short*)(ws + TENC_OFF);
        float* partials      = (float*)(ws + PART_F_OFF);
        int NCH = 512;
        while (NCH > 8 && (size_t)PART_F_OFF + (size_t)NCH * 131072 > ws_size) NCH >>= 1;
        int cpn = (N_NODES + NCH - 1) / NCH;

        k_tenc<<<(100032 * 8) / 256, 256, 0, stream>>>(keys, cnt, list, t, last_update,
                                                       w_time, b_time, tenc);
        k_gemm_fused<<<100032 / 64, 256, 0, stream>>>(keys, cnt, list, event_feat,
                                                      src_embeds, dst_embeds, nodes_mem,
                                                      tenc, Wt, b_ih, b_hh, out);
        k_copy<<<(N_NODES * 32 + 255) / 256, 256, 0, stream>>>(keys, nodes_mem, out);
        k_comm1<<<2 * NCH, 256, 0, stream>>>(incidence, out, partials, NCH, cpn);
        k_comm2<<<(N_COMM * DIM_M + 255) / 256, 256, 0, stream>>>(partials, out, NCH);
    }
}

// Round 5
// 307.009 us; speedup vs baseline: 6.4529x; 1.3178x over previous
//
#include <hip/hip_runtime.h>
#include <hip/hip_bf16.h>
#include <stdint.h>

#define N_NODES   100000
#define N_EVENTS  50000
#define N_COMM    256
#define DIM_M     128
#define K_TOT     576   // 448 msg + 128 mem
#define GCOLS     512   // r(128) z(128) xn(128) hn(128)
#define INV2PI    0.15915494309189535f

typedef float f32x4 __attribute__((ext_vector_type(4)));
typedef short s16x8 __attribute__((ext_vector_type(8)));

// ---------------- ws layout ----------------
#define KEYS_OFF   0                     // u64[N]
#define CNT_OFF    800000                // u32
#define LIST_OFF   800008                // i32[N] -> ends 1200008
#define W2PI_OFF   1200128               // f32[64]
#define B2PI_OFF   1200384               // f32[64]
#define WT_OFF     1200640               // bf16 [512][576] -> ends 1790464
#define X_ROWS     100096
#define X_OFF      1790464               // bf16 [100096][576] = 115310592
// comm partials OVERLAY the X region (X is dead before comm runs)
#define PART_M_OFF X_OFF                 // f32 [NCH_M][256][128]
#define CPN_M      192
#define NCH_M      521                   // 521*192 = 100032 >= 100000
// fallback path:
#define TENC_OFF   1790464               // bf16 [100032][64]
#define PART_F_OFF 14594560

__device__ inline unsigned short f2bf(float x) {
    union { float f; unsigned u; } v; v.f = x;
    unsigned r = v.u + 0x7FFFu + ((v.u >> 16) & 1u);
    return (unsigned short)(r >> 16);
}

__device__ inline float cos_rev(float rev) {
    float fr = rev - floorf(rev);
#if __has_builtin(__builtin_amdgcn_cosf)
    return __builtin_amdgcn_cosf(fr);
#else
    return cosf(fr * 6.283185307179586f);
#endif
}

// ---------- phase 1: per-node last-event via atomicMax on (t<<32 | idx+1) ----------
__global__ __launch_bounds__(256) void k_agg(const int* __restrict__ src,
                                             const int* __restrict__ dst,
                                             const int* __restrict__ t,
                                             unsigned long long* __restrict__ keys) {
    int i = blockIdx.x * 256 + threadIdx.x;
    if (i >= 2 * N_EVENTS) return;
    int e = (i < N_EVENTS) ? i : i - N_EVENTS;
    int node = (i < N_EVENTS) ? src[i] : dst[e];
    unsigned long long key =
        ((unsigned long long)(unsigned)t[e] << 32) | (unsigned)(i + 1);
    atomicMax(&keys[node], key);
}

// ---------- phase 2: compact node list ----------
__global__ __launch_bounds__(256) void k_compact(const unsigned long long* __restrict__ keys,
                                                 unsigned int* __restrict__ cnt,
                                                 int* __restrict__ list) {
    int n = blockIdx.x * 256 + threadIdx.x;
    if (n >= N_NODES) return;
    if (keys[n] != 0ULL) {
        unsigned p = atomicAdd(cnt, 1u);
        list[p] = n;
    }
}

// ---------- tiny prep: time weights in revolution space ----------
__global__ void k_prep(const float* __restrict__ w_time, const float* __restrict__ b_time,
                       float* __restrict__ w2, float* __restrict__ b2) {
    int i = threadIdx.x;
    if (i < 64) { w2[i] = w_time[i] * INV2PI; b2[i] = b_time[i] * INV2PI; }
}

// ---------- fused gate weights, bf16, [col][k] (K-contiguous) ----------
__global__ __launch_bounds__(256) void k_wconv(const float* __restrict__ W_ih,
                                               const float* __restrict__ W_hh,
                                               unsigned short* __restrict__ Wt) {
    int idx = blockIdx.x * 256 + threadIdx.x;
    if (idx >= GCOLS * K_TOT) return;
    int col = idx / K_TOT, k = idx % K_TOT;
    float v;
    if (col < 256) {
        v = (k < 448) ? W_ih[(size_t)k * 384 + col]
                      : W_hh[(size_t)(k - 448) * 384 + col];
    } else if (col < 384) {
        v = (k < 448) ? W_ih[(size_t)k * 384 + col] : 0.0f;
    } else {
        v = (k < 448) ? 0.0f : W_hh[(size_t)(k - 448) * 384 + (col - 128)];
    }
    Wt[idx] = f2bf(v);
}

// ---------- phase 3a: build X = [msg | mem] in bf16, coalesced ----------
__global__ __launch_bounds__(256) void k_xbuild(
    const unsigned long long* __restrict__ keys,
    const unsigned int* __restrict__ cnt,
    const int* __restrict__ list,
    const int* __restrict__ t,
    const int* __restrict__ last_update,
    const float* __restrict__ event_feat,
    const float* __restrict__ src_embeds,
    const float* __restrict__ dst_embeds,
    const float* __restrict__ mem,
    const float* __restrict__ w2pi,
    const float* __restrict__ b2pi,
    unsigned short* __restrict__ X) {
    const unsigned c = *cnt;
    const unsigned cpad = (c + 127u) & ~127u;
    const unsigned total = cpad * 72u;
    for (unsigned idx = blockIdx.x * 256 + threadIdx.x; idx < total;
         idx += gridDim.x * 256) {
        const unsigned row = idx / 72u;
        const int s = (int)(idx - row * 72u);
        unsigned short* xp = X + (size_t)row * K_TOT + s * 8;
        s16x8 v;
        if (row >= c) {
#pragma unroll
            for (int j = 0; j < 8; ++j) v[j] = 0;
            *(s16x8*)xp = v;
            continue;
        }
        const int node = list[row];
        const unsigned long long key = keys[node];
        const int ia = (int)(key & 0xffffffffull) - 1;
        const int e = (ia < N_EVENTS) ? ia : ia - N_EVENTS;
        if (s < 48) {
            const float* p;
            if (s < 16)
                p = ((ia < N_EVENTS) ? src_embeds : dst_embeds) + (size_t)e * 128 + s * 8;
            else if (s < 32)
                p = ((ia < N_EVENTS) ? dst_embeds : src_embeds) + (size_t)e * 128 + (s - 16) * 8;
            else
                p = event_feat + (size_t)e * 128 + (s - 32) * 8;
            float4 a = *(const float4*)p;
            float4 b = *(const float4*)(p + 4);
            v[0] = (short)f2bf(a.x); v[1] = (short)f2bf(a.y);
            v[2] = (short)f2bf(a.z); v[3] = (short)f2bf(a.w);
            v[4] = (short)f2bf(b.x); v[5] = (short)f2bf(b.y);
            v[6] = (short)f2bf(b.z); v[7] = (short)f2bf(b.w);
        } else if (s < 56) {
            const float dt = (float)(t[e] - last_update[node]);
            const int c0 = (s - 48) * 8;
#pragma unroll
            for (int j = 0; j < 8; ++j) {
                float rev = fmaf(dt, w2pi[c0 + j], b2pi[c0 + j]);
                v[j] = (short)f2bf(cos_rev(rev));
            }
        } else {
            const float* p = mem + (size_t)node * 128 + (s - 56) * 8;
            float4 a = *(const float4*)p;
            float4 b = *(const float4*)(p + 4);
            v[0] = (short)f2bf(a.x); v[1] = (short)f2bf(a.y);
            v[2] = (short)f2bf(a.z); v[3] = (short)f2bf(a.w);
            v[4] = (short)f2bf(b.x); v[5] = (short)f2bf(b.y);
            v[6] = (short)f2bf(b.z); v[7] = (short)f2bf(b.w);
        }
        *(s16x8*)xp = v;
    }
}

// ---------- phase 3b: streaming MFMA GEMM + GRU epilogue ----------
// BM=128, BN=512, BK=64. 1024 threads = 16 waves, wave grid 2(M) x 8(N).
// Wave wn owns col-tiles {wn, wn+8, wn+16, wn+24} = r,z,xn,hn of m-tile wn.
__global__ __launch_bounds__(1024) void k_gemm2(
    const unsigned int* __restrict__ cnt,
    const int* __restrict__ list,
    const unsigned short* __restrict__ X,
    const unsigned short* __restrict__ Wt,
    const float* __restrict__ mem,
    const float* __restrict__ b_ih,
    const float* __restrict__ b_hh,
    float* __restrict__ out) {
    __shared__ unsigned short Xs[2][128][64];  // 32 KB

    const unsigned c = *cnt;
    const int base = blockIdx.x * 128;
    if ((unsigned)base >= c) return;
    const int tid = threadIdx.x;
    const int w = tid >> 6, l = tid & 63;
    const int lr = l & 15, lk = l >> 4;
    const int wm = w >> 3, wn = w & 7;

    // staging: wave w covers rows w*8 .. w*8+7 (1024 B); lane l -> (row', slot sd)
    const int srow = w * 8 + (l >> 3);
    const int sd = l & 7;
    const unsigned short* gsrc0 =
        X + (size_t)(base + srow) * K_TOT + ((sd ^ (srow & 7)) << 3);

    auto stage = [&](int ch) {
        __builtin_amdgcn_global_load_lds(
            (const __attribute__((address_space(1))) unsigned int*)(gsrc0 + ch * 64),
            (__attribute__((address_space(3))) unsigned int*)&Xs[ch & 1][w * 8][0],
            16, 0, 0);
    };

    f32x4 acc[4][4];
#pragma unroll
    for (int rt = 0; rt < 4; ++rt)
#pragma unroll
        for (int i = 0; i < 4; ++i) acc[rt][i] = (f32x4){0.f, 0.f, 0.f, 0.f};

    stage(0);
    __syncthreads();

    for (int ch = 0; ch < 9; ++ch) {
        if (ch < 8) stage(ch + 1);
        const int buf = ch & 1;
#pragma unroll
        for (int ks = 0; ks < 2; ++ks) {
            s16x8 a[4];
#pragma unroll
            for (int rt = 0; rt < 4; ++rt) {
                const int r = wm * 64 + rt * 16 + lr;
                const int sl = (ks * 4 + lk) ^ (r & 7);
                a[rt] = *(const s16x8*)&Xs[buf][r][sl << 3];
            }
#pragma unroll
            for (int i = 0; i < 4; ++i) {
                const int col = (wn + 8 * i) * 16 + lr;
                s16x8 b = *(const s16x8*)&Wt[(size_t)col * K_TOT + ch * 64 + ks * 32 + lk * 8];
#pragma unroll
                for (int rt = 0; rt < 4; ++rt)
                    acc[rt][i] = __builtin_amdgcn_mfma_f32_16x16x32_bf16(
                        a[rt], b, acc[rt][i], 0, 0, 0);
            }
        }
        __syncthreads();
    }

    // ---- epilogue: i = {0:r, 1:z, 2:xn, 3:hn} for m-col wn*16+lr ----
    const int mcol = wn * 16 + lr;
    const float b_r  = b_ih[mcol] + b_hh[mcol];
    const float b_z  = b_ih[128 + mcol] + b_hh[128 + mcol];
    const float b_xn = b_ih[256 + mcol];
    const float b_hn = b_hh[256 + mcol];
#pragma unroll
    for (int rt = 0; rt < 4; ++rt) {
#pragma unroll
        for (int reg = 0; reg < 4; ++reg) {
            const int grow = base + wm * 64 + rt * 16 + lk * 4 + reg;
            if ((unsigned)grow < c) {
                const int node = list[grow];
                const float h = mem[(size_t)node * 128 + mcol];
                float rr = acc[rt][0][reg] + b_r;
                float zz = acc[rt][1][reg] + b_z;
                float xn = acc[rt][2][reg] + b_xn;
                float hn = acc[rt][3][reg] + b_hn;
                rr = 1.0f / (1.0f + expf(-rr));
                zz = 1.0f / (1.0f + expf(-zz));
                float nn = tanhf(xn + rr * hn);
                out[(size_t)node * 128 + mcol] = (1.0f - zz) * nn + zz * h;
            }
        }
    }
}

// ---------- phase 4: copy-through for nodes without messages ----------
__global__ __launch_bounds__(256) void k_copy(const unsigned long long* __restrict__ keys,
                                              const float* __restrict__ nm,
                                              float* __restrict__ out) {
    int idx = blockIdx.x * 256 + threadIdx.x;
    int n = idx >> 5;
    if (n >= N_NODES) return;
    if (keys[n] != 0ULL) return;
    ((float4*)out)[idx] = ((const float4*)nm)[idx];
}

// ---------- phase 5a: comm via MFMA, register-gathered fragments ----------
// C[c=256][m=128] = sum_n inc[n][c] * newmem[n][m]. Block = n-chunk of CPN_M.
// 512 threads = 8 waves; wave w owns c-tiles {2w, 2w+1} x all 8 m-tiles.
template<bool G>
__device__ __forceinline__ void comm_step(const float* __restrict__ inc,
                                          const float* __restrict__ nm,
                                          int ns, int n1, int w, int lr, int lk,
                                          f32x4 (&acc)[2][8]) {
    const int nb = ns + lk * 8;
    s16x8 a[2];
#pragma unroll
    for (int rt = 0; rt < 2; ++rt) {
        const int cc = (w * 2 + rt) * 16 + lr;
#pragma unroll
        for (int j = 0; j < 8; ++j) {
            const int n = nb + j;
            float v = (!G || n < n1) ? inc[(size_t)n * N_COMM + cc] : 0.0f;
            a[rt][j] = (short)f2bf(v);
        }
    }
#pragma unroll
    for (int i = 0; i < 8; ++i) {
        const int mm = i * 16 + lr;
        s16x8 b;
#pragma unroll
        for (int j = 0; j < 8; ++j) {
            const int n = nb + j;
            float v = (!G || n < n1) ? nm[(size_t)n * DIM_M + mm] : 0.0f;
            b[j] = (short)f2bf(v);
        }
#pragma unroll
        for (int rt = 0; rt < 2; ++rt)
            acc[rt][i] = __builtin_amdgcn_mfma_f32_16x16x32_bf16(
                a[rt], b, acc[rt][i], 0, 0, 0);
    }
}

__global__ __launch_bounds__(512) void k_comm_m(const float* __restrict__ inc,
                                                const float* __restrict__ nm,
                                                float* __restrict__ partials) {
    const int bid = blockIdx.x;
    const int n0 = bid * CPN_M;
    const int n1 = min(N_NODES, n0 + CPN_M);
    const int tid = threadIdx.x;
    const int w = tid >> 6, l = tid & 63;
    const int lr = l & 15, lk = l >> 4;

    f32x4 acc[2][8];
#pragma unroll
    for (int rt = 0; rt < 2; ++rt)
#pragma unroll
        for (int i = 0; i < 8; ++i) acc[rt][i] = (f32x4){0.f, 0.f, 0.f, 0.f};

    const int nfull = n0 + ((n1 - n0) & ~31);
    for (int ns = n0; ns < nfull; ns += 32)
        comm_step<false>(inc, nm, ns, n1, w, lr, lk, acc);
    if (nfull < n1)
        comm_step<true>(inc, nm, nfull, n1, w, lr, lk, acc);

    float* p = partials + (size_t)bid * (N_COMM * DIM_M);
#pragma unroll
    for (int rt = 0; rt < 2; ++rt) {
#pragma unroll
        for (int i = 0; i < 8; ++i) {
#pragma unroll
            for (int reg = 0; reg < 4; ++reg) {
                const int cc = (w * 2 + rt) * 16 + lk * 4 + reg;
                p[(size_t)cc * DIM_M + i * 16 + lr] = acc[rt][i][reg];
            }
        }
    }
}

// ---------- phase 5b: reduce comm partials ----------
__global__ __launch_bounds__(256) void k_comm2_m(const float* __restrict__ partials,
                                                 float* __restrict__ out) {
    int idx = blockIdx.x * 256 + threadIdx.x;
    if (idx >= N_COMM * DIM_M) return;
    float s = 0.0f;
    for (int ch = 0; ch < NCH_M; ++ch)
        s += partials[(size_t)ch * (N_COMM * DIM_M) + idx];
    out[(size_t)N_NODES * DIM_M + idx] = s;
}

// ================= FALLBACK PATH (small ws) =================
__global__ __launch_bounds__(256) void k_tenc(const unsigned long long* __restrict__ keys,
                                              const unsigned int* __restrict__ cnt,
                                              const int* __restrict__ list,
                                              const int* __restrict__ t,
                                              const int* __restrict__ last_update,
                                              const float* __restrict__ w_time,
                                              const float* __restrict__ b_time,
                                              unsigned short* __restrict__ tenc) {
    int idx = blockIdx.x * 256 + threadIdx.x;
    int r = idx >> 3, slot = idx & 7;
    const unsigned c = *cnt;
    const unsigned cpad = (c + 63u) & ~63u;
    if ((unsigned)r >= cpad) return;
    s16x8 v;
    if ((unsigned)r < c) {
        int node = list[r];
        unsigned long long key = keys[node];
        int ia = (int)(key & 0xffffffffull) - 1;
        int e = (ia < N_EVENTS) ? ia : ia - N_EVENTS;
        float dt = (float)(t[e] - last_update[node]);
#pragma unroll
        for (int j = 0; j < 8; ++j) {
            int cix = slot * 8 + j;
            float arg = __fadd_rn(__fmul_rn(dt, w_time[cix]), b_time[cix]);
            v[j] = (short)f2bf(cosf(arg));
        }
    } else {
#pragma unroll
        for (int j = 0; j < 8; ++j) v[j] = 0;
    }
    *(s16x8*)&tenc[(size_t)r * 64 + slot * 8] = v;
}

__global__ __launch_bounds__(256, 2) void k_gemm_fused(
    const unsigned long long* __restrict__ keys,
    const unsigned int* __restrict__ cnt,
    const int* __restrict__ list,
    const float* __restrict__ event_feat,
    const float* __restrict__ src_embeds,
    const float* __restrict__ dst_embeds,
    const float* __restrict__ mem,
    const unsigned short* __restrict__ tenc,
    const unsigned short* __restrict__ Wt,
    const float* __restrict__ b_ih,
    const float* __restrict__ b_hh,
    float* __restrict__ out) {
    __shared__ unsigned short Xs[2][4][64][8];

    const unsigned c = *cnt;
    const int base = blockIdx.x * 64;
    if ((unsigned)base >= c) return;
    const int tid = threadIdx.x;

    const int srow = tid >> 2;
    const int kslot = tid & 3;
    const int sgrow = base + srow;
    const bool valid = (unsigned)sgrow < c;
    const float *p_es = nullptr, *p_ed = nullptr, *p_ef = nullptr, *p_mem = nullptr;
    const unsigned short* p_te = nullptr;
    if (valid) {
        int node = list[sgrow];
        unsigned long long key = keys[node];
        int ia = (int)(key & 0xffffffffull) - 1;
        int e = (ia < N_EVENTS) ? ia : ia - N_EVENTS;
        const float* sp = src_embeds + (size_t)e * 128;
        const float* dp = dst_embeds + (size_t)e * 128;
        p_es = (ia < N_EVENTS) ? sp : dp;
        p_ed = (ia < N_EVENTS) ? dp : sp;
        p_ef = event_feat + (size_t)e * 128;
        p_te = tenc + (size_t)sgrow * 64;
        p_mem = mem + (size_t)node * 128;
    }

    auto stage = [&](int ch) {
        const int buf = ch & 1;
        const int k0 = ch * 32 + kslot * 8;
        s16x8 v;
        if (valid) {
            if (k0 < 384) {
                const float* p = (k0 < 128) ? (p_es + k0)
                               : (k0 < 256) ? (p_ed + (k0 - 128))
                                            : (p_ef + (k0 - 256));
                float4 a = *(const float4*)p;
                float4 b = *(const float4*)(p + 4);
                v[0] = (short)f2bf(a.x); v[1] = (short)f2bf(a.y);
                v[2] = (short)f2bf(a.z); v[3] = (short)f2bf(a.w);
                v[4] = (short)f2bf(b.x); v[5] = (short)f2bf(b.y);
                v[6] = (short)f2bf(b.z); v[7] = (short)f2bf(b.w);
            } else if (k0 < 448) {
                v = *(const s16x8*)(p_te + (k0 - 384));
            } else {
                const float* p = p_mem + (k0 - 448);
                float4 a = *(const float4*)p;
                float4 b = *(const float4*)(p + 4);
                v[0] = (short)f2bf(a.x); v[1] = (short)f2bf(a.y);
                v[2] = (short)f2bf(a.z); v[3] = (short)f2bf(a.w);
                v[4] = (short)f2bf(b.x); v[5] = (short)f2bf(b.y);
                v[6] = (short)f2bf(b.z); v[7] = (short)f2bf(b.w);
            }
        } else {
#pragma unroll
            for (int j = 0; j < 8; ++j) v[j] = 0;
        }
        *(s16x8*)&Xs[buf][kslot][srow][0] = v;
    };

    const int w = tid >> 6;
    const int l = tid & 63;
    const int lr = l & 15;
    const int lk = l >> 4;

    f32x4 acc[4][8];
#pragma unroll
    for (int rt = 0; rt < 4; ++rt)
#pragma unroll
        for (int i = 0; i < 8; ++i) acc[rt][i] = (f32x4){0.f, 0.f, 0.f, 0.f};

    stage(0);
    __syncthreads();

    for (int ch = 0; ch < 18; ++ch) {
        if (ch < 17) stage(ch + 1);
        const int buf = ch & 1;
        s16x8 a[4];
#pragma unroll
        for (int rt = 0; rt < 4; ++rt)
            a[rt] = *(const s16x8*)&Xs[buf][lk][rt * 16 + lr][0];
#pragma unroll
        for (int i = 0; i < 8; ++i) {
            const int col = (w + 4 * i) * 16 + lr;
            s16x8 b = *(const s16x8*)&Wt[(size_t)col * K_TOT + ch * 32 + lk * 8];
#pragma unroll
            for (int rt = 0; rt < 4; ++rt)
                acc[rt][i] = __builtin_amdgcn_mfma_f32_16x16x32_bf16(
                    a[rt], b, acc[rt][i], 0, 0, 0);
        }
        __syncthreads();
    }

#pragma unroll
    for (int jj = 0; jj < 2; ++jj) {
        const int mcol = (w + 4 * jj) * 16 + lr;
        const float b_r  = b_ih[mcol] + b_hh[mcol];
        const float b_z  = b_ih[128 + mcol] + b_hh[128 + mcol];
        const float b_xn = b_ih[256 + mcol];
        const float b_hn = b_hh[256 + mcol];
#pragma unroll
        for (int rt = 0; rt < 4; ++rt) {
#pragma unroll
            for (int reg = 0; reg < 4; ++reg) {
                const int grow = base + rt * 16 + lk * 4 + reg;
                if ((unsigned)grow < c) {
                    const int node = list[grow];
                    const float h = mem[(size_t)node * 128 + mcol];
                    float rr = acc[rt][0 + jj][reg] + b_r;
                    float zz = acc[rt][2 + jj][reg] + b_z;
                    float xn = acc[rt][4 + jj][reg] + b_xn;
                    float hn = acc[rt][6 + jj][reg] + b_hn;
                    rr = 1.0f / (1.0f + expf(-rr));
                    zz = 1.0f / (1.0f + expf(-zz));
                    float nn = tanhf(xn + rr * hn);
                    out[(size_t)node * 128 + mcol] = (1.0f - zz) * nn + zz * h;
                }
            }
        }
    }
}

__global__ __launch_bounds__(256) void k_comm1(const float* __restrict__ inc,
                                               const float* __restrict__ nm,
                                               float* __restrict__ partials,
                                               int nch, int cpn) {
    __shared__ float inc_s[2][8][128];
    __shared__ float mem_s[2][8][128];

    const int bid = blockIdx.x;
    const int ct2 = bid / nch;
    const int ch  = bid % nch;
    const int n0 = ch * cpn;
    const int n1 = min(N_NODES, n0 + cpn);
    const int tid = threadIdx.x;

    const int srow = tid >> 5;
    const int scol = (tid & 31) * 4;

    auto stage = [&](int g, int buf) {
        const int n = n0 + g * 8 + srow;
        float4 iv = make_float4(0.f, 0.f, 0.f, 0.f);
        float4 mv = make_float4(0.f, 0.f, 0.f, 0.f);
        if (n < n1) {
            iv = *(const float4*)(inc + (size_t)n * N_COMM + ct2 * 128 + scol);
            mv = *(const float4*)(nm + (size_t)n * DIM_M + scol);
        }
        *(float4*)&inc_s[buf][srow][scol] = iv;
        *(float4*)&mem_s[buf][srow][scol] = mv;
    };

    const int c0 = (tid >> 3) * 4;
    const int mb = (tid & 7) * 4;

    float acc[4][4][4];
#pragma unroll
    for (int a = 0; a < 4; ++a)
#pragma unroll
        for (int b = 0; b < 4; ++b)
#pragma unroll
            for (int d = 0; d < 4; ++d) acc[a][b][d] = 0.0f;

    const int ngrp = (n1 - n0 + 7) >> 3;
    stage(0, 0);
    __syncthreads();

    for (int g = 0; g < ngrp; ++g) {
        if (g + 1 < ngrp) stage(g + 1, (g + 1) & 1);
        const int buf = g & 1;
#pragma unroll
        for (int i = 0; i < 8; ++i) {
            const float4 cv = *(const float4*)&inc_s[buf][i][c0];
            const float ca[4] = {cv.x, cv.y, cv.z, cv.w};
#pragma unroll
            for (int j = 0; j < 4; ++j) {
                const float4 mv = *(const float4*)&mem_s[buf][i][j * 32 + mb];
                const float ma[4] = {mv.x, mv.y, mv.z, mv.w};
#pragma unroll
                for (int ci = 0; ci < 4; ++ci)
#pragma unroll
                    for (int mi = 0; mi < 4; ++mi)
                        acc[ci][j][mi] = fmaf(ca[ci], ma[mi], acc[ci][j][mi]);
            }
        }
        __syncthreads();
    }

    float* p = partials + (size_t)bid * (128 * 128);
#pragma unroll
    for (int ci = 0; ci < 4; ++ci)
#pragma unroll
        for (int j = 0; j < 4; ++j)
            *(float4*)(p + (size_t)(c0 + ci) * 128 + j * 32 + mb) =
                make_float4(acc[ci][j][0], acc[ci][j][1], acc[ci][j][2], acc[ci][j][3]);
}

__global__ __launch_bounds__(256) void k_comm2_f(const float* __restrict__ partials,
                                                 float* __restrict__ out,
                                                 int nch) {
    int idx = blockIdx.x * 256 + threadIdx.x;
    if (idx >= N_COMM * DIM_M) return;
    int cg = idx >> 7;
    int m = idx & 127;
    int ct2 = cg >> 7;
    int cl = cg & 127;
    float s = 0.0f;
    for (int ch = 0; ch < nch; ++ch)
        s += partials[((size_t)ct2 * nch + ch) * 16384 + (size_t)cl * 128 + m];
    out[(size_t)N_NODES * DIM_M + idx] = s;
}

extern "C" void kernel_launch(void* const* d_in, const int* in_sizes, int n_in,
                              void* d_out, int out_size, void* d_ws, size_t ws_size,
                              hipStream_t stream) {
    const int* src          = (const int*)d_in[0];
    const int* dst          = (const int*)d_in[1];
    const int* t            = (const int*)d_in[2];
    const int* last_update  = (const int*)d_in[3];
    const float* event_feat = (const float*)d_in[4];
    const float* src_embeds = (const float*)d_in[5];
    const float* dst_embeds = (const float*)d_in[6];
    const float* nodes_mem  = (const float*)d_in[7];
    const float* incidence  = (const float*)d_in[8];
    const float* w_time     = (const float*)d_in[9];
    const float* b_time     = (const float*)d_in[10];
    const float* W_ih       = (const float*)d_in[11];
    const float* W_hh       = (const float*)d_in[12];
    const float* b_ih       = (const float*)d_in[13];
    const float* b_hh       = (const float*)d_in[14];
    float* out = (float*)d_out;

    char* ws = (char*)d_ws;
    unsigned long long* keys = (unsigned long long*)(ws + KEYS_OFF);
    unsigned int* cnt        = (unsigned int*)(ws + CNT_OFF);
    int* list                = (int*)(ws + LIST_OFF);
    float* w2pi              = (float*)(ws + W2PI_OFF);
    float* b2pi              = (float*)(ws + B2PI_OFF);
    unsigned short* Wt       = (unsigned short*)(ws + WT_OFF);

    const bool xfit = ws_size >= (size_t)X_OFF + (size_t)X_ROWS * (K_TOT * 2);

    hipMemsetAsync(d_ws, 0, LIST_OFF, stream);  // keys + cnt

    k_agg<<<(2 * N_EVENTS + 255) / 256, 256, 0, stream>>>(src, dst, t, keys);
    k_compact<<<(N_NODES + 255) / 256, 256, 0, stream>>>(keys, cnt, list);
    k_prep<<<1, 64, 0, stream>>>(w_time, b_time, w2pi, b2pi);
    k_wconv<<<(GCOLS * K_TOT + 255) / 256, 256, 0, stream>>>(W_ih, W_hh, Wt);

    if (xfit) {
        unsigned short* X = (unsigned short*)(ws + X_OFF);
        float* partials   = (float*)(ws + PART_M_OFF);  // overlays dead X

        k_xbuild<<<4096, 256, 0, stream>>>(keys, cnt, list, t, last_update,
                                           event_feat, src_embeds, dst_embeds,
                                           nodes_mem, w2pi, b2pi, X);
        k_gemm2<<<X_ROWS / 128, 1024, 0, stream>>>(cnt, list, X, Wt, nodes_mem,
                                                   b_ih, b_hh, out);
        k_copy<<<(N_NODES * 32 + 255) / 256, 256, 0, stream>>>(keys, nodes_mem, out);
        k_comm_m<<<NCH_M, 512, 0, stream>>>(incidence, out, partials);
        k_comm2_m<<<(N_COMM * DIM_M + 255) / 256, 256, 0, stream>>>(partials, out);
    } else {
        unsigned short* tenc = (unsigned short*)(ws + TENC_OFF);
        float* partials      = (float*)(ws + PART_F_OFF);
        int NCH = 512;
        while (NCH > 8 && (size_t)PART_F_OFF + (size_t)NCH * 131072 > ws_size) NCH >>= 1;
        int cpn = (N_NODES + NCH - 1) / NCH;

        k_tenc<<<(100032 * 8) / 256, 256, 0, stream>>>(keys, cnt, list, t, last_update,
                                                       w_time, b_time, tenc);
        k_gemm_fused<<<100032 / 64, 256, 0, stream>>>(keys, cnt, list, event_feat,
                                                      src_embeds, dst_embeds, nodes_mem,
                                                      tenc, Wt, b_ih, b_hh, out);
        k_copy<<<(N_NODES * 32 + 255) / 256, 256, 0, stream>>>(keys, nodes_mem, out);
        k_comm1<<<2 * NCH, 256, 0, stream>>>(incidence, out, partials, NCH, cpn);
        k_comm2_f<<<(N_COMM * DIM_M + 255) / 256, 256, 0, stream>>>(partials, out, NCH);
    }
}

// Round 6
// 279.339 us; speedup vs baseline: 7.0921x; 1.0991x over previous
//
#include <hip/hip_runtime.h>
#include <hip/hip_bf16.h>
#include <stdint.h>

#define N_NODES   100000
#define N_EVENTS  50000
#define N_COMM    256
#define DIM_M     128
#define K_TOT     576   // 448 msg + 128 mem
#define GCOLS     512   // r(128) z(128) xn(128) hn(128)
#define INV2PI    0.15915494309189535f

typedef float f32x4 __attribute__((ext_vector_type(4)));
typedef short s16x8 __attribute__((ext_vector_type(8)));
typedef short s16x4 __attribute__((ext_vector_type(4)));

// ---------------- ws layout ----------------
#define KEYS_OFF   0                     // u64[N]
#define CNT_OFF    800000                // u32
#define LIST_OFF   800008                // i32[N] -> ends 1200008
#define W2PI_OFF   1200128               // f32[64]
#define B2PI_OFF   1200384               // f32[64]
#define WT_OFF     1200640               // bf16 [512][576] -> ends 1790464
#define X_ROWS     100096
#define X_OFF      1790464               // bf16 [100096][576] = 115310592
// comm partials OVERLAY the X region (X dead before comm runs)
#define PART_M_OFF X_OFF                 // f32 [CT_NCH][256][128] = 58.6MB
#define CT_NCH     447
#define CT_CPN     224                   // 447*224 = 100128 >= 100000
// fallback path:
#define TENC_OFF   1790464               // bf16 [100032][64]
#define PART_F_OFF 14594560

__device__ inline unsigned short f2bf(float x) {
    union { float f; unsigned u; } v; v.f = x;
    unsigned r = v.u + 0x7FFFu + ((v.u >> 16) & 1u);
    return (unsigned short)(r >> 16);
}
__device__ inline float bf2f(unsigned short u) {
    union { unsigned u; float f; } v; v.u = ((unsigned)u) << 16;
    return v.f;
}
__device__ inline float cos_rev(float rev) {
    float fr = rev - floorf(rev);
#if __has_builtin(__builtin_amdgcn_cosf)
    return __builtin_amdgcn_cosf(fr);
#else
    return cosf(fr * 6.283185307179586f);
#endif
}
__device__ inline float sigmoid_f(float x) { return 1.0f / (1.0f + __expf(-x)); }
__device__ inline float tanh_f(float x) {
    float t = __expf(2.0f * x);            // inf-safe: t=inf -> 1, t=0 -> -1
    return 1.0f - 2.0f / (t + 1.0f);
}

// ---------- phase 1: per-node last-event via atomicMax on (t<<32 | idx+1) ----------
__global__ __launch_bounds__(256) void k_agg(const int* __restrict__ src,
                                             const int* __restrict__ dst,
                                             const int* __restrict__ t,
                                             unsigned long long* __restrict__ keys) {
    int i = blockIdx.x * 256 + threadIdx.x;
    if (i >= 2 * N_EVENTS) return;
    int e = (i < N_EVENTS) ? i : i - N_EVENTS;
    int node = (i < N_EVENTS) ? src[i] : dst[e];
    unsigned long long key =
        ((unsigned long long)(unsigned)t[e] << 32) | (unsigned)(i + 1);
    atomicMax(&keys[node], key);
}

// ---------- phase 2: compact node list ----------
__global__ __launch_bounds__(256) void k_compact(const unsigned long long* __restrict__ keys,
                                                 unsigned int* __restrict__ cnt,
                                                 int* __restrict__ list) {
    int n = blockIdx.x * 256 + threadIdx.x;
    if (n >= N_NODES) return;
    if (keys[n] != 0ULL) {
        unsigned p = atomicAdd(cnt, 1u);
        list[p] = n;
    }
}

// ---------- tiny prep: time weights in revolution space ----------
__global__ void k_prep(const float* __restrict__ w_time, const float* __restrict__ b_time,
                       float* __restrict__ w2, float* __restrict__ b2) {
    int i = threadIdx.x;
    if (i < 64) { w2[i] = w_time[i] * INV2PI; b2[i] = b_time[i] * INV2PI; }
}

// ---------- fused gate weights, bf16, [col][k] (K-contiguous) ----------
__global__ __launch_bounds__(256) void k_wconv(const float* __restrict__ W_ih,
                                               const float* __restrict__ W_hh,
                                               unsigned short* __restrict__ Wt) {
    int idx = blockIdx.x * 256 + threadIdx.x;
    if (idx >= GCOLS * K_TOT) return;
    int col = idx / K_TOT, k = idx % K_TOT;
    float v;
    if (col < 256) {
        v = (k < 448) ? W_ih[(size_t)k * 384 + col]
                      : W_hh[(size_t)(k - 448) * 384 + col];
    } else if (col < 384) {
        v = (k < 448) ? W_ih[(size_t)k * 384 + col] : 0.0f;
    } else {
        v = (k < 448) ? 0.0f : W_hh[(size_t)(k - 448) * 384 + (col - 128)];
    }
    Wt[idx] = f2bf(v);
}

// ---------- phase 3a: build X = [msg | mem] in bf16, coalesced ----------
__global__ __launch_bounds__(256) void k_xbuild(
    const unsigned long long* __restrict__ keys,
    const unsigned int* __restrict__ cnt,
    const int* __restrict__ list,
    const int* __restrict__ t,
    const int* __restrict__ last_update,
    const float* __restrict__ event_feat,
    const float* __restrict__ src_embeds,
    const float* __restrict__ dst_embeds,
    const float* __restrict__ mem,
    const float* __restrict__ w2pi,
    const float* __restrict__ b2pi,
    unsigned short* __restrict__ X) {
    const unsigned c = *cnt;
    const unsigned cpad = (c + 127u) & ~127u;
    const unsigned total = cpad * 72u;
    for (unsigned idx = blockIdx.x * 256 + threadIdx.x; idx < total;
         idx += gridDim.x * 256) {
        const unsigned row = idx / 72u;
        const int s = (int)(idx - row * 72u);
        unsigned short* xp = X + (size_t)row * K_TOT + s * 8;
        s16x8 v;
        if (row >= c) {
#pragma unroll
            for (int j = 0; j < 8; ++j) v[j] = 0;
            *(s16x8*)xp = v;
            continue;
        }
        const int node = list[row];
        const unsigned long long key = keys[node];
        const int ia = (int)(key & 0xffffffffull) - 1;
        const int e = (ia < N_EVENTS) ? ia : ia - N_EVENTS;
        if (s < 48) {
            const float* p;
            if (s < 16)
                p = ((ia < N_EVENTS) ? src_embeds : dst_embeds) + (size_t)e * 128 + s * 8;
            else if (s < 32)
                p = ((ia < N_EVENTS) ? dst_embeds : src_embeds) + (size_t)e * 128 + (s - 16) * 8;
            else
                p = event_feat + (size_t)e * 128 + (s - 32) * 8;
            float4 a = *(const float4*)p;
            float4 b = *(const float4*)(p + 4);
            v[0] = (short)f2bf(a.x); v[1] = (short)f2bf(a.y);
            v[2] = (short)f2bf(a.z); v[3] = (short)f2bf(a.w);
            v[4] = (short)f2bf(b.x); v[5] = (short)f2bf(b.y);
            v[6] = (short)f2bf(b.z); v[7] = (short)f2bf(b.w);
        } else if (s < 56) {
            const float dt = (float)(t[e] - last_update[node]);
            const int c0 = (s - 48) * 8;
#pragma unroll
            for (int j = 0; j < 8; ++j) {
                float rev = fmaf(dt, w2pi[c0 + j], b2pi[c0 + j]);
                v[j] = (short)f2bf(cos_rev(rev));
            }
        } else {
            const float* p = mem + (size_t)node * 128 + (s - 56) * 8;
            float4 a = *(const float4*)p;
            float4 b = *(const float4*)(p + 4);
            v[0] = (short)f2bf(a.x); v[1] = (short)f2bf(a.y);
            v[2] = (short)f2bf(a.z); v[3] = (short)f2bf(a.w);
            v[4] = (short)f2bf(b.x); v[5] = (short)f2bf(b.y);
            v[6] = (short)f2bf(b.z); v[7] = (short)f2bf(b.w);
        }
        *(s16x8*)xp = v;
    }
}

// ---------- phase 3b: pipelined MFMA GEMM + GRU epilogue ----------
// BM=128, BN=512, BK=64, 1024 thr = 16 waves (2M x 8N). 3 LDS bufs, depth-2
// prefetch, single raw barrier per chunk with counted vmcnt (never 0 in loop).
__global__ __launch_bounds__(1024) void k_gemm2(
    const unsigned int* __restrict__ cnt,
    const int* __restrict__ list,
    const unsigned short* __restrict__ X,
    const unsigned short* __restrict__ Wt,
    const float* __restrict__ b_ih,
    const float* __restrict__ b_hh,
    float* __restrict__ out) {
    __shared__ unsigned short Xs[3][128][64];  // 48 KB
    __shared__ int Ls[128];

    const unsigned c = *cnt;
    const int base = blockIdx.x * 128;
    if ((unsigned)base >= c) return;
    const int tid = threadIdx.x;
    const int w = tid >> 6, l = tid & 63;
    const int lr = l & 15, lk = l >> 4;
    const int wm = w >> 3, wn = w & 7;

    if (tid < 128)
        Ls[tid] = ((unsigned)(base + tid) < c) ? list[base + tid] : 0;

    // staging: wave w covers rows w*8..w*8+7; lane l -> (row w*8+(l>>3), slot l&7)
    const int srow = w * 8 + (l >> 3);
    const int sd = l & 7;
    const unsigned short* gsrc0 =
        X + (size_t)(base + srow) * K_TOT + ((sd ^ (srow & 7)) << 3);

    auto stage = [&](int ch, int buf) {
        __builtin_amdgcn_global_load_lds(
            (const __attribute__((address_space(1))) unsigned int*)(gsrc0 + ch * 64),
            (__attribute__((address_space(3))) unsigned int*)&Xs[buf][w * 8][0],
            16, 0, 0);
    };

    f32x4 acc[4][4];
#pragma unroll
    for (int rt = 0; rt < 4; ++rt)
#pragma unroll
        for (int i = 0; i < 4; ++i) acc[rt][i] = (f32x4){0.f, 0.f, 0.f, 0.f};

    stage(0, 0);
    stage(1, 1);
    __syncthreads();   // full drain once; chunks 0,1 resident

    int buf = 0;
    for (int ch = 0; ch < 9; ++ch) {
        // ---- compute chunk ch from Xs[buf]; Wt loads issued here (before stage) ----
#pragma unroll
        for (int ks = 0; ks < 2; ++ks) {
            s16x8 a[4];
#pragma unroll
            for (int rt = 0; rt < 4; ++rt) {
                const int r = wm * 64 + rt * 16 + lr;
                const int sl = (ks * 4 + lk) ^ (r & 7);
                a[rt] = *(const s16x8*)&Xs[buf][r][sl << 3];
            }
#pragma unroll
            for (int i = 0; i < 4; ++i) {
                const int col = (wn + 8 * i) * 16 + lr;
                s16x8 b = *(const s16x8*)&Wt[(size_t)col * K_TOT + ch * 64 + ks * 32 + lk * 8];
#pragma unroll
                for (int rt = 0; rt < 4; ++rt)
                    acc[rt][i] = __builtin_amdgcn_mfma_f32_16x16x32_bf16(
                        a[rt], b, acc[rt][i], 0, 0, 0);
            }
        }
        // ---- prefetch chunk ch+2, then counted-vmcnt barrier ----
        if (ch <= 6) {
            int nbuf = buf + 2; if (nbuf >= 3) nbuf -= 3;
            stage(ch + 2, nbuf);
        }
        if (ch < 8) {
            __builtin_amdgcn_sched_barrier(0);
            if (ch < 7) asm volatile("s_waitcnt vmcnt(9)" ::: "memory");
            else        asm volatile("s_waitcnt vmcnt(8)" ::: "memory");
            __builtin_amdgcn_s_barrier();
            __builtin_amdgcn_sched_barrier(0);
        }
        if (++buf == 3) buf = 0;
    }

    // ---- epilogue: h from LDS (chunk7 -> buf1, chunk8 -> buf2) ----
    const int mcol = wn * 16 + lr;
    const float b_r  = b_ih[mcol] + b_hh[mcol];
    const float b_z  = b_ih[128 + mcol] + b_hh[128 + mcol];
    const float b_xn = b_ih[256 + mcol];
    const float b_hn = b_hh[256 + mcol];
    const int hbuf = (mcol < 64) ? 1 : 2;
    const int kk   = (mcol < 64) ? mcol : mcol - 64;
#pragma unroll
    for (int rt = 0; rt < 4; ++rt) {
#pragma unroll
        for (int reg = 0; reg < 4; ++reg) {
            const int r = wm * 64 + rt * 16 + lk * 4 + reg;
            const int grow = base + r;
            if ((unsigned)grow < c) {
                const int node = Ls[r];
                const float h = bf2f(Xs[hbuf][r][(((kk >> 3) ^ (r & 7)) << 3) + (kk & 7)]);
                float rr = sigmoid_f(acc[rt][0][reg] + b_r);
                float zz = sigmoid_f(acc[rt][1][reg] + b_z);
                float nn = tanh_f(acc[rt][2][reg] + b_xn + rr * (acc[rt][3][reg] + b_hn));
                out[(size_t)node * 128 + mcol] = (1.0f - zz) * nn + zz * h;
            }
        }
    }
}

// ---------- phase 4: copy-through for nodes without messages ----------
__global__ __launch_bounds__(256) void k_copy(const unsigned long long* __restrict__ keys,
                                              const float* __restrict__ nm,
                                              float* __restrict__ out) {
    int idx = blockIdx.x * 256 + threadIdx.x;
    int n = idx >> 5;
    if (n >= N_NODES) return;
    if (keys[n] != 0ULL) return;
    ((float4*)out)[idx] = ((const float4*)nm)[idx];
}

// ---------- phase 5a: comm = inc^T @ new_mem via LDS-transposed MFMA ----------
// Block = n-chunk of CT_CPN (7 sub-chunks of 32 n). 512 thr = 8 waves.
// LDS: incT [256c][32n] bf16 + nmT [128m][32n] bf16, XOR-8B-block swizzled,
// double-buffered. T14 split: load(g+1) -> compute(g) -> write(g+1) -> barrier.
__global__ __launch_bounds__(512) void k_comm_t(const float* __restrict__ inc,
                                                const float* __restrict__ nm,
                                                float* __restrict__ partials) {
    __shared__ unsigned short T[2][12288];  // per buf: inc 8192 + nm 4096 shorts (48KB)

    const int bid = blockIdx.x;
    const int n0 = bid * CT_CPN;
    const int n1 = min(N_NODES, n0 + CT_CPN);
    const int ng = (n1 - n0 + 31) >> 5;
    const int tid = threadIdx.x;
    const int w = tid >> 6, l = tid & 63;
    const int lr = l & 15, lk = l >> 4;

    float vi[4][4];  // inc rows nb+ri, cols l+64j
    float vm[4][2];  // nm  rows nb+ri, cols l+64j

    auto load_chunk = [&](int g) {
        const int nb = n0 + g * 32 + w * 4;
#pragma unroll
        for (int ri = 0; ri < 4; ++ri) {
            const int n = nb + ri;
            const bool ok = n < n1;
#pragma unroll
            for (int j = 0; j < 4; ++j)
                vi[ri][j] = ok ? inc[(size_t)n * N_COMM + l + 64 * j] : 0.0f;
#pragma unroll
            for (int j = 0; j < 2; ++j)
                vm[ri][j] = ok ? nm[(size_t)n * DIM_M + l + 64 * j] : 0.0f;
        }
    };
    // element (c, n): short index c*32 + ((nblk ^ (c&7))<<2) + (n&3), nblk = n>>2
    auto write_chunk = [&](int buf) {
        unsigned short* bi = &T[buf][0];
#pragma unroll
        for (int j = 0; j < 4; ++j) {
            const int cc = l + 64 * j;
            ushort4 p = make_ushort4(f2bf(vi[0][j]), f2bf(vi[1][j]),
                                     f2bf(vi[2][j]), f2bf(vi[3][j]));
            *(ushort4*)&bi[cc * 32 + ((w ^ (cc & 7)) << 2)] = p;
        }
        unsigned short* bm = &T[buf][8192];
#pragma unroll
        for (int j = 0; j < 2; ++j) {
            const int mm = l + 64 * j;
            ushort4 p = make_ushort4(f2bf(vm[0][j]), f2bf(vm[1][j]),
                                     f2bf(vm[2][j]), f2bf(vm[3][j]));
            *(ushort4*)&bm[mm * 32 + ((w ^ (mm & 7)) << 2)] = p;
        }
    };

    f32x4 acc[2][8];
#pragma unroll
    for (int ct = 0; ct < 2; ++ct)
#pragma unroll
        for (int mt = 0; mt < 8; ++mt) acc[ct][mt] = (f32x4){0.f, 0.f, 0.f, 0.f};

    auto compute_chunk = [&](int buf) {
        const unsigned short* bi = &T[buf][0];
        const unsigned short* bm = &T[buf][8192];
        s16x8 a[2];
#pragma unroll
        for (int ct = 0; ct < 2; ++ct) {
            const int cc = (w * 2 + ct) * 16 + lr;
            s16x4 lo = *(const s16x4*)&bi[cc * 32 + (((lk * 2) ^ (cc & 7)) << 2)];
            s16x4 hi = *(const s16x4*)&bi[cc * 32 + (((lk * 2 + 1) ^ (cc & 7)) << 2)];
            a[ct] = __builtin_shufflevector(lo, hi, 0, 1, 2, 3, 4, 5, 6, 7);
        }
#pragma unroll
        for (int mt = 0; mt < 8; ++mt) {
            const int mm = mt * 16 + lr;
            s16x4 lo = *(const s16x4*)&bm[mm * 32 + (((lk * 2) ^ (mm & 7)) << 2)];
            s16x4 hi = *(const s16x4*)&bm[mm * 32 + (((lk * 2 + 1) ^ (mm & 7)) << 2)];
            s16x8 b = __builtin_shufflevector(lo, hi, 0, 1, 2, 3, 4, 5, 6, 7);
            acc[0][mt] = __builtin_amdgcn_mfma_f32_16x16x32_bf16(a[0], b, acc[0][mt], 0, 0, 0);
            acc[1][mt] = __builtin_amdgcn_mfma_f32_16x16x32_bf16(a[1], b, acc[1][mt], 0, 0, 0);
        }
    };

    load_chunk(0);
    write_chunk(0);
    __syncthreads();
    for (int g = 0; g < ng; ++g) {
        if (g + 1 < ng) load_chunk(g + 1);   // issue early: HBM latency under MFMA
        compute_chunk(g & 1);
        if (g + 1 < ng) write_chunk((g + 1) & 1);
        __syncthreads();
    }

    float* p = partials + (size_t)bid * (N_COMM * DIM_M);
#pragma unroll
    for (int ct = 0; ct < 2; ++ct) {
#pragma unroll
        for (int mt = 0; mt < 8; ++mt) {
#pragma unroll
            for (int reg = 0; reg < 4; ++reg) {
                const int cc = (w * 2 + ct) * 16 + lk * 4 + reg;
                p[(size_t)cc * DIM_M + mt * 16 + lr] = acc[ct][mt][reg];
            }
        }
    }
}

// ---------- phase 5b: reduce comm partials (float4) ----------
__global__ __launch_bounds__(256) void k_comm2v(const float* __restrict__ partials,
                                                float* __restrict__ out) {
    int idx = blockIdx.x * 256 + threadIdx.x;  // float4 index over 32768 floats
    if (idx >= (N_COMM * DIM_M) / 4) return;
    float4 s = make_float4(0.f, 0.f, 0.f, 0.f);
    for (int ch = 0; ch < CT_NCH; ++ch) {
        float4 v = *(const float4*)&partials[(size_t)ch * (N_COMM * DIM_M) + idx * 4];
        s.x += v.x; s.y += v.y; s.z += v.z; s.w += v.w;
    }
    *(float4*)&out[(size_t)N_NODES * DIM_M + idx * 4] = s;
}

// ================= FALLBACK PATH (small ws) =================
__global__ __launch_bounds__(256) void k_tenc(const unsigned long long* __restrict__ keys,
                                              const unsigned int* __restrict__ cnt,
                                              const int* __restrict__ list,
                                              const int* __restrict__ t,
                                              const int* __restrict__ last_update,
                                              const float* __restrict__ w_time,
                                              const float* __restrict__ b_time,
                                              unsigned short* __restrict__ tenc) {
    int idx = blockIdx.x * 256 + threadIdx.x;
    int r = idx >> 3, slot = idx & 7;
    const unsigned c = *cnt;
    const unsigned cpad = (c + 63u) & ~63u;
    if ((unsigned)r >= cpad) return;
    s16x8 v;
    if ((unsigned)r < c) {
        int node = list[r];
        unsigned long long key = keys[node];
        int ia = (int)(key & 0xffffffffull) - 1;
        int e = (ia < N_EVENTS) ? ia : ia - N_EVENTS;
        float dt = (float)(t[e] - last_update[node]);
#pragma unroll
        for (int j = 0; j < 8; ++j) {
            int cix = slot * 8 + j;
            float arg = __fadd_rn(__fmul_rn(dt, w_time[cix]), b_time[cix]);
            v[j] = (short)f2bf(cosf(arg));
        }
    } else {
#pragma unroll
        for (int j = 0; j < 8; ++j) v[j] = 0;
    }
    *(s16x8*)&tenc[(size_t)r * 64 + slot * 8] = v;
}

__global__ __launch_bounds__(256, 2) void k_gemm_fused(
    const unsigned long long* __restrict__ keys,
    const unsigned int* __restrict__ cnt,
    const int* __restrict__ list,
    const float* __restrict__ event_feat,
    const float* __restrict__ src_embeds,
    const float* __restrict__ dst_embeds,
    const float* __restrict__ mem,
    const unsigned short* __restrict__ tenc,
    const unsigned short* __restrict__ Wt,
    const float* __restrict__ b_ih,
    const float* __restrict__ b_hh,
    float* __restrict__ out) {
    __shared__ unsigned short Xs[2][4][64][8];

    const unsigned c = *cnt;
    const int base = blockIdx.x * 64;
    if ((unsigned)base >= c) return;
    const int tid = threadIdx.x;

    const int srow = tid >> 2;
    const int kslot = tid & 3;
    const int sgrow = base + srow;
    const bool valid = (unsigned)sgrow < c;
    const float *p_es = nullptr, *p_ed = nullptr, *p_ef = nullptr, *p_mem = nullptr;
    const unsigned short* p_te = nullptr;
    if (valid) {
        int node = list[sgrow];
        unsigned long long key = keys[node];
        int ia = (int)(key & 0xffffffffull) - 1;
        int e = (ia < N_EVENTS) ? ia : ia - N_EVENTS;
        const float* sp = src_embeds + (size_t)e * 128;
        const float* dp = dst_embeds + (size_t)e * 128;
        p_es = (ia < N_EVENTS) ? sp : dp;
        p_ed = (ia < N_EVENTS) ? dp : sp;
        p_ef = event_feat + (size_t)e * 128;
        p_te = tenc + (size_t)sgrow * 64;
        p_mem = mem + (size_t)node * 128;
    }

    auto stage = [&](int ch) {
        const int buf = ch & 1;
        const int k0 = ch * 32 + kslot * 8;
        s16x8 v;
        if (valid) {
            if (k0 < 384) {
                const float* p = (k0 < 128) ? (p_es + k0)
                               : (k0 < 256) ? (p_ed + (k0 - 128))
                                            : (p_ef + (k0 - 256));
                float4 a = *(const float4*)p;
                float4 b = *(const float4*)(p + 4);
                v[0] = (short)f2bf(a.x); v[1] = (short)f2bf(a.y);
                v[2] = (short)f2bf(a.z); v[3] = (short)f2bf(a.w);
                v[4] = (short)f2bf(b.x); v[5] = (short)f2bf(b.y);
                v[6] = (short)f2bf(b.z); v[7] = (short)f2bf(b.w);
            } else if (k0 < 448) {
                v = *(const s16x8*)(p_te + (k0 - 384));
            } else {
                const float* p = p_mem + (k0 - 448);
                float4 a = *(const float4*)p;
                float4 b = *(const float4*)(p + 4);
                v[0] = (short)f2bf(a.x); v[1] = (short)f2bf(a.y);
                v[2] = (short)f2bf(a.z); v[3] = (short)f2bf(a.w);
                v[4] = (short)f2bf(b.x); v[5] = (short)f2bf(b.y);
                v[6] = (short)f2bf(b.z); v[7] = (short)f2bf(b.w);
            }
        } else {
#pragma unroll
            for (int j = 0; j < 8; ++j) v[j] = 0;
        }
        *(s16x8*)&Xs[buf][kslot][srow][0] = v;
    };

    const int w = tid >> 6;
    const int l = tid & 63;
    const int lr = l & 15;
    const int lk = l >> 4;

    f32x4 acc[4][8];
#pragma unroll
    for (int rt = 0; rt < 4; ++rt)
#pragma unroll
        for (int i = 0; i < 8; ++i) acc[rt][i] = (f32x4){0.f, 0.f, 0.f, 0.f};

    stage(0);
    __syncthreads();

    for (int ch = 0; ch < 18; ++ch) {
        if (ch < 17) stage(ch + 1);
        const int buf = ch & 1;
        s16x8 a[4];
#pragma unroll
        for (int rt = 0; rt < 4; ++rt)
            a[rt] = *(const s16x8*)&Xs[buf][lk][rt * 16 + lr][0];
#pragma unroll
        for (int i = 0; i < 8; ++i) {
            const int col = (w + 4 * i) * 16 + lr;
            s16x8 b = *(const s16x8*)&Wt[(size_t)col * K_TOT + ch * 32 + lk * 8];
#pragma unroll
            for (int rt = 0; rt < 4; ++rt)
                acc[rt][i] = __builtin_amdgcn_mfma_f32_16x16x32_bf16(
                    a[rt], b, acc[rt][i], 0, 0, 0);
        }
        __syncthreads();
    }

#pragma unroll
    for (int jj = 0; jj < 2; ++jj) {
        const int mcol = (w + 4 * jj) * 16 + lr;
        const float b_r  = b_ih[mcol] + b_hh[mcol];
        const float b_z  = b_ih[128 + mcol] + b_hh[128 + mcol];
        const float b_xn = b_ih[256 + mcol];
        const float b_hn = b_hh[256 + mcol];
#pragma unroll
        for (int rt = 0; rt < 4; ++rt) {
#pragma unroll
            for (int reg = 0; reg < 4; ++reg) {
                const int grow = base + rt * 16 + lk * 4 + reg;
                if ((unsigned)grow < c) {
                    const int node = list[grow];
                    const float h = mem[(size_t)node * 128 + mcol];
                    float rr = sigmoid_f(acc[rt][0 + jj][reg] + b_r);
                    float zz = sigmoid_f(acc[rt][2 + jj][reg] + b_z);
                    float nn = tanh_f(acc[rt][4 + jj][reg] + b_xn +
                                      rr * (acc[rt][6 + jj][reg] + b_hn));
                    out[(size_t)node * 128 + mcol] = (1.0f - zz) * nn + zz * h;
                }
            }
        }
    }
}

__global__ __launch_bounds__(256) void k_comm1(const float* __restrict__ inc,
                                               const float* __restrict__ nm,
                                               float* __restrict__ partials,
                                               int nch, int cpn) {
    __shared__ float inc_s[2][8][128];
    __shared__ float mem_s[2][8][128];

    const int bid = blockIdx.x;
    const int ct2 = bid / nch;
    const int ch  = bid % nch;
    const int n0 = ch * cpn;
    const int n1 = min(N_NODES, n0 + cpn);
    const int tid = threadIdx.x;

    const int srow = tid >> 5;
    const int scol = (tid & 31) * 4;

    auto stage = [&](int g, int buf) {
        const int n = n0 + g * 8 + srow;
        float4 iv = make_float4(0.f, 0.f, 0.f, 0.f);
        float4 mv = make_float4(0.f, 0.f, 0.f, 0.f);
        if (n < n1) {
            iv = *(const float4*)(inc + (size_t)n * N_COMM + ct2 * 128 + scol);
            mv = *(const float4*)(nm + (size_t)n * DIM_M + scol);
        }
        *(float4*)&inc_s[buf][srow][scol] = iv;
        *(float4*)&mem_s[buf][srow][scol] = mv;
    };

    const int c0 = (tid >> 3) * 4;
    const int mb = (tid & 7) * 4;

    float acc[4][4][4];
#pragma unroll
    for (int a = 0; a < 4; ++a)
#pragma unroll
        for (int b = 0; b < 4; ++b)
#pragma unroll
            for (int d = 0; d < 4; ++d) acc[a][b][d] = 0.0f;

    const int ngrp = (n1 - n0 + 7) >> 3;
    stage(0, 0);
    __syncthreads();

    for (int g = 0; g < ngrp; ++g) {
        if (g + 1 < ngrp) stage(g + 1, (g + 1) & 1);
        const int buf = g & 1;
#pragma unroll
        for (int i = 0; i < 8; ++i) {
            const float4 cv = *(const float4*)&inc_s[buf][i][c0];
            const float ca[4] = {cv.x, cv.y, cv.z, cv.w};
#pragma unroll
            for (int j = 0; j < 4; ++j) {
                const float4 mv = *(const float4*)&mem_s[buf][i][j * 32 + mb];
                const float ma[4] = {mv.x, mv.y, mv.z, mv.w};
#pragma unroll
                for (int ci = 0; ci < 4; ++ci)
#pragma unroll
                    for (int mi = 0; mi < 4; ++mi)
                        acc[ci][j][mi] = fmaf(ca[ci], ma[mi], acc[ci][j][mi]);
            }
        }
        __syncthreads();
    }

    float* p = partials + (size_t)bid * (128 * 128);
#pragma unroll
    for (int ci = 0; ci < 4; ++ci)
#pragma unroll
        for (int j = 0; j < 4; ++j)
            *(float4*)(p + (size_t)(c0 + ci) * 128 + j * 32 + mb) =
                make_float4(acc[ci][j][0], acc[ci][j][1], acc[ci][j][2], acc[ci][j][3]);
}

__global__ __launch_bounds__(256) void k_comm2_f(const float* __restrict__ partials,
                                                 float* __restrict__ out,
                                                 int nch) {
    int idx = blockIdx.x * 256 + threadIdx.x;
    if (idx >= N_COMM * DIM_M) return;
    int cg = idx >> 7;
    int m = idx & 127;
    int ct2 = cg >> 7;
    int cl = cg & 127;
    float s = 0.0f;
    for (int ch = 0; ch < nch; ++ch)
        s += partials[((size_t)ct2 * nch + ch) * 16384 + (size_t)cl * 128 + m];
    out[(size_t)N_NODES * DIM_M + idx] = s;
}

extern "C" void kernel_launch(void* const* d_in, const int* in_sizes, int n_in,
                              void* d_out, int out_size, void* d_ws, size_t ws_size,
                              hipStream_t stream) {
    const int* src          = (const int*)d_in[0];
    const int* dst          = (const int*)d_in[1];
    const int* t            = (const int*)d_in[2];
    const int* last_update  = (const int*)d_in[3];
    const float* event_feat = (const float*)d_in[4];
    const float* src_embeds = (const float*)d_in[5];
    const float* dst_embeds = (const float*)d_in[6];
    const float* nodes_mem  = (const float*)d_in[7];
    const float* incidence  = (const float*)d_in[8];
    const float* w_time     = (const float*)d_in[9];
    const float* b_time     = (const float*)d_in[10];
    const float* W_ih       = (const float*)d_in[11];
    const float* W_hh       = (const float*)d_in[12];
    const float* b_ih       = (const float*)d_in[13];
    const float* b_hh       = (const float*)d_in[14];
    float* out = (float*)d_out;

    char* ws = (char*)d_ws;
    unsigned long long* keys = (unsigned long long*)(ws + KEYS_OFF);
    unsigned int* cnt        = (unsigned int*)(ws + CNT_OFF);
    int* list                = (int*)(ws + LIST_OFF);
    float* w2pi              = (float*)(ws + W2PI_OFF);
    float* b2pi              = (float*)(ws + B2PI_OFF);
    unsigned short* Wt       = (unsigned short*)(ws + WT_OFF);

    const bool xfit = ws_size >= (size_t)X_OFF + (size_t)X_ROWS * (K_TOT * 2);

    hipMemsetAsync(d_ws, 0, LIST_OFF, stream);  // keys + cnt

    k_agg<<<(2 * N_EVENTS + 255) / 256, 256, 0, stream>>>(src, dst, t, keys);
    k_compact<<<(N_NODES + 255) / 256, 256, 0, stream>>>(keys, cnt, list);
    k_prep<<<1, 64, 0, stream>>>(w_time, b_time, w2pi, b2pi);
    k_wconv<<<(GCOLS * K_TOT + 255) / 256, 256, 0, stream>>>(W_ih, W_hh, Wt);

    if (xfit) {
        unsigned short* X = (unsigned short*)(ws + X_OFF);
        float* partials   = (float*)(ws + PART_M_OFF);  // overlays dead X

        k_xbuild<<<4096, 256, 0, stream>>>(keys, cnt, list, t, last_update,
                                           event_feat, src_embeds, dst_embeds,
                                           nodes_mem, w2pi, b2pi, X);
        k_gemm2<<<X_ROWS / 128, 1024, 0, stream>>>(cnt, list, X, Wt, b_ih, b_hh, out);
        k_copy<<<(N_NODES * 32 + 255) / 256, 256, 0, stream>>>(keys, nodes_mem, out);
        k_comm_t<<<CT_NCH, 512, 0, stream>>>(incidence, out, partials);
        k_comm2v<<<(N_COMM * DIM_M / 4 + 255) / 256, 256, 0, stream>>>(partials, out);
    } else {
        unsigned short* tenc = (unsigned short*)(ws + TENC_OFF);
        float* partials      = (float*)(ws + PART_F_OFF);
        int NCH = 512;
        while (NCH > 8 && (size_t)PART_F_OFF + (size_t)NCH * 131072 > ws_size) NCH >>= 1;
        int cpn = (N_NODES + NCH - 1) / NCH;

        k_tenc<<<(100032 * 8) / 256, 256, 0, stream>>>(keys, cnt, list, t, last_update,
                                                       w_time, b_time, tenc);
        k_gemm_fused<<<100032 / 64, 256, 0, stream>>>(keys, cnt, list, event_feat,
                                                      src_embeds, dst_embeds, nodes_mem,
                                                      tenc, Wt, b_ih, b_hh, out);
        k_copy<<<(N_NODES * 32 + 255) / 256, 256, 0, stream>>>(keys, nodes_mem, out);
        k_comm1<<<2 * NCH, 256, 0, stream>>>(incidence, out, partials, NCH, cpn);
        k_comm2_f<<<(N_COMM * DIM_M + 255) / 256, 256, 0, stream>>>(partials, out, NCH);
    }
}

// Round 7
// 232.739 us; speedup vs baseline: 8.5121x; 1.2002x over previous
//
#include <hip/hip_runtime.h>
#include <hip/hip_bf16.h>
#include <stdint.h>

#define N_NODES   100000
#define N_EVENTS  50000
#define N_COMM    256
#define DIM_M     128
#define K_TOT     576   // 448 msg + 128 mem
#define GCOLS     512
#define INV2PI    0.15915494309189535f

typedef float f32x4 __attribute__((ext_vector_type(4)));
typedef short s16x8 __attribute__((ext_vector_type(8)));
typedef short s16x4 __attribute__((ext_vector_type(4)));

// ---------------- ws layout ----------------
#define KEYS_OFF   0                     // u64[N]
#define CNT_OFF    800000                // u32
#define LIST_OFF   800008                // i32[N] -> ends 1200008
#define W2PI_OFF   1200128               // f32[64]
#define B2PI_OFF   1200384               // f32[64]
#define WT_OFF     1200640               // bf16 [512][576] -> ends 1790464
#define X_ROWS     100096
#define X_OFF      1790464               // bf16 [100096][576] = 115310592
// comm scratch OVERLAYS X region (X dead before comm runs)
#define PART_M_OFF X_OFF                 // f32 [256][256*128] = 33.5MB
#define CT_NCH     256
#define CT_CPN     392                   // 256*392 = 100352 >= 100000
#define TMP2_OFF   (PART_M_OFF + 33554432)  // f32 [16][32768] = 2MB
// fallback path:
#define TENC_OFF   1790464
#define PART_F_OFF 14594560

__device__ inline unsigned short f2bf(float x) {
    union { float f; unsigned u; } v; v.f = x;
    unsigned r = v.u + 0x7FFFu + ((v.u >> 16) & 1u);
    return (unsigned short)(r >> 16);
}
__device__ inline float bf2f(unsigned short u) {
    union { unsigned u; float f; } v; v.u = ((unsigned)u) << 16;
    return v.f;
}
__device__ inline float cos_rev(float rev) {
    float fr = rev - floorf(rev);
#if __has_builtin(__builtin_amdgcn_cosf)
    return __builtin_amdgcn_cosf(fr);
#else
    return cosf(fr * 6.283185307179586f);
#endif
}
__device__ inline float sigmoid_f(float x) { return 1.0f / (1.0f + __expf(-x)); }
__device__ inline float tanh_f(float x) {
    float t = __expf(2.0f * x);
    return 1.0f - 2.0f / (t + 1.0f);
}

// ---------- phase 1 ----------
__global__ __launch_bounds__(256) void k_agg(const int* __restrict__ src,
                                             const int* __restrict__ dst,
                                             const int* __restrict__ t,
                                             unsigned long long* __restrict__ keys) {
    int i = blockIdx.x * 256 + threadIdx.x;
    if (i >= 2 * N_EVENTS) return;
    int e = (i < N_EVENTS) ? i : i - N_EVENTS;
    int node = (i < N_EVENTS) ? src[i] : dst[e];
    unsigned long long key =
        ((unsigned long long)(unsigned)t[e] << 32) | (unsigned)(i + 1);
    atomicMax(&keys[node], key);
}

// ---------- phase 2 ----------
__global__ __launch_bounds__(256) void k_compact(const unsigned long long* __restrict__ keys,
                                                 unsigned int* __restrict__ cnt,
                                                 int* __restrict__ list) {
    int n = blockIdx.x * 256 + threadIdx.x;
    if (n >= N_NODES) return;
    if (keys[n] != 0ULL) {
        unsigned p = atomicAdd(cnt, 1u);
        list[p] = n;
    }
}

__global__ void k_prep(const float* __restrict__ w_time, const float* __restrict__ b_time,
                       float* __restrict__ w2, float* __restrict__ b2) {
    int i = threadIdx.x;
    if (i < 64) { w2[i] = w_time[i] * INV2PI; b2[i] = b_time[i] * INV2PI; }
}

// ---------- fused gate weights, GATE-INTERLEAVED layout ----------
// col2 = mh*256 + g*64 + ml; m = mh*64+ml; g: 0=r 1=z 2=xn 3=hn. [col2][k] K-contig.
__global__ __launch_bounds__(256) void k_wconv(const float* __restrict__ W_ih,
                                               const float* __restrict__ W_hh,
                                               unsigned short* __restrict__ Wt) {
    int idx = blockIdx.x * 256 + threadIdx.x;
    if (idx >= GCOLS * K_TOT) return;
    int col2 = idx / K_TOT, k = idx % K_TOT;
    int mh = col2 >> 8, rem = col2 & 255;
    int g = rem >> 6, m = mh * 64 + (rem & 63);
    float v;
    if (g == 0)      v = (k < 448) ? W_ih[(size_t)k * 384 + m]
                                   : W_hh[(size_t)(k - 448) * 384 + m];
    else if (g == 1) v = (k < 448) ? W_ih[(size_t)k * 384 + 128 + m]
                                   : W_hh[(size_t)(k - 448) * 384 + 128 + m];
    else if (g == 2) v = (k < 448) ? W_ih[(size_t)k * 384 + 256 + m] : 0.0f;
    else             v = (k < 448) ? 0.0f : W_hh[(size_t)(k - 448) * 384 + 256 + m];
    Wt[idx] = f2bf(v);
}

// ---------- old layout for fallback ----------
__global__ __launch_bounds__(256) void k_wconv_old(const float* __restrict__ W_ih,
                                                   const float* __restrict__ W_hh,
                                                   unsigned short* __restrict__ Wt) {
    int idx = blockIdx.x * 256 + threadIdx.x;
    if (idx >= GCOLS * K_TOT) return;
    int col = idx / K_TOT, k = idx % K_TOT;
    float v;
    if (col < 256) {
        v = (k < 448) ? W_ih[(size_t)k * 384 + col]
                      : W_hh[(size_t)(k - 448) * 384 + col];
    } else if (col < 384) {
        v = (k < 448) ? W_ih[(size_t)k * 384 + col] : 0.0f;
    } else {
        v = (k < 448) ? 0.0f : W_hh[(size_t)(k - 448) * 384 + (col - 128)];
    }
    Wt[idx] = f2bf(v);
}

// ---------- phase 3a: build X ----------
__global__ __launch_bounds__(256) void k_xbuild(
    const unsigned long long* __restrict__ keys,
    const unsigned int* __restrict__ cnt,
    const int* __restrict__ list,
    const int* __restrict__ t,
    const int* __restrict__ last_update,
    const float* __restrict__ event_feat,
    const float* __restrict__ src_embeds,
    const float* __restrict__ dst_embeds,
    const float* __restrict__ mem,
    const float* __restrict__ w2pi,
    const float* __restrict__ b2pi,
    unsigned short* __restrict__ X) {
    const unsigned c = *cnt;
    const unsigned cpad = (c + 127u) & ~127u;
    const unsigned total = cpad * 72u;
    for (unsigned idx = blockIdx.x * 256 + threadIdx.x; idx < total;
         idx += gridDim.x * 256) {
        const unsigned row = idx / 72u;
        const int s = (int)(idx - row * 72u);
        unsigned short* xp = X + (size_t)row * K_TOT + s * 8;
        s16x8 v;
        if (row >= c) {
#pragma unroll
            for (int j = 0; j < 8; ++j) v[j] = 0;
            *(s16x8*)xp = v;
            continue;
        }
        const int node = list[row];
        const unsigned long long key = keys[node];
        const int ia = (int)(key & 0xffffffffull) - 1;
        const int e = (ia < N_EVENTS) ? ia : ia - N_EVENTS;
        if (s < 48) {
            const float* p;
            if (s < 16)
                p = ((ia < N_EVENTS) ? src_embeds : dst_embeds) + (size_t)e * 128 + s * 8;
            else if (s < 32)
                p = ((ia < N_EVENTS) ? dst_embeds : src_embeds) + (size_t)e * 128 + (s - 16) * 8;
            else
                p = event_feat + (size_t)e * 128 + (s - 32) * 8;
            float4 a = *(const float4*)p;
            float4 b = *(const float4*)(p + 4);
            v[0] = (short)f2bf(a.x); v[1] = (short)f2bf(a.y);
            v[2] = (short)f2bf(a.z); v[3] = (short)f2bf(a.w);
            v[4] = (short)f2bf(b.x); v[5] = (short)f2bf(b.y);
            v[6] = (short)f2bf(b.z); v[7] = (short)f2bf(b.w);
        } else if (s < 56) {
            const float dt = (float)(t[e] - last_update[node]);
            const int c0 = (s - 48) * 8;
#pragma unroll
            for (int j = 0; j < 8; ++j) {
                float rev = fmaf(dt, w2pi[c0 + j], b2pi[c0 + j]);
                v[j] = (short)f2bf(cos_rev(rev));
            }
        } else {
            const float* p = mem + (size_t)node * 128 + (s - 56) * 8;
            float4 a = *(const float4*)p;
            float4 b = *(const float4*)(p + 4);
            v[0] = (short)f2bf(a.x); v[1] = (short)f2bf(a.y);
            v[2] = (short)f2bf(a.z); v[3] = (short)f2bf(a.w);
            v[4] = (short)f2bf(b.x); v[5] = (short)f2bf(b.y);
            v[6] = (short)f2bf(b.z); v[7] = (short)f2bf(b.w);
        }
        *(s16x8*)xp = v;
    }
}

// ---------- phase 3b: pipelined MFMA GEMM + GRU epilogue ----------
// 512 thr = 8 waves (2M x 4N). BM=128, BN=256 (one m-half, all 4 gates), BK=64.
// grid = 2*(rows/128): rb = bid>>1, mh = bid&1. 2 blocks resident per CU.
__global__ __launch_bounds__(512, 4) void k_gemm2(
    const unsigned int* __restrict__ cnt,
    const int* __restrict__ list,
    const unsigned short* __restrict__ X,
    const unsigned short* __restrict__ Wt,
    const float* __restrict__ b_ih,
    const float* __restrict__ b_hh,
    float* __restrict__ out) {
    __shared__ unsigned short Xs[3][128][64];  // 48 KB
    __shared__ int Ls[128];

    const unsigned c = *cnt;
    const int rb = blockIdx.x >> 1;
    const int mh = blockIdx.x & 1;
    const int base = rb * 128;
    if ((unsigned)base >= c) return;
    const int tid = threadIdx.x;
    const int w = tid >> 6, l = tid & 63;
    const int lr = l & 15, lk = l >> 4;
    const int wm = w >> 2, wn = w & 3;

    if (tid < 128)
        Ls[tid] = ((unsigned)(base + tid) < c) ? list[base + tid] : 0;

    // staging: wave w covers rows w*16..w*16+15 in two 8-row calls
    const int sroff = l >> 3;                      // 0..7
    const int sslot = ((l & 7) ^ sroff) << 3;      // LDS slot sd holds src slot sd^(r&7)
    const unsigned short* gsrc0 =
        X + (size_t)(base + w * 16 + sroff) * K_TOT + sslot;

    auto stage = [&](int ch, int buf) {
        __builtin_amdgcn_global_load_lds(
            (const __attribute__((address_space(1))) unsigned int*)(gsrc0 + ch * 64),
            (__attribute__((address_space(3))) unsigned int*)&Xs[buf][w * 16][0],
            16, 0, 0);
        __builtin_amdgcn_global_load_lds(
            (const __attribute__((address_space(1))) unsigned int*)(gsrc0 + 8 * K_TOT + ch * 64),
            (__attribute__((address_space(3))) unsigned int*)&Xs[buf][w * 16 + 8][0],
            16, 0, 0);
    };

    f32x4 acc[4][4];  // [row-tile][gate]
#pragma unroll
    for (int rt = 0; rt < 4; ++rt)
#pragma unroll
        for (int i = 0; i < 4; ++i) acc[rt][i] = (f32x4){0.f, 0.f, 0.f, 0.f};

    stage(0, 0);
    stage(1, 1);
    asm volatile("s_waitcnt vmcnt(2)" ::: "memory");
    __builtin_amdgcn_s_barrier();

    int buf = 0;
    for (int ch = 0; ch < 9; ++ch) {
        __builtin_amdgcn_s_setprio(1);
#pragma unroll
        for (int ks = 0; ks < 2; ++ks) {
            s16x8 a[4];
#pragma unroll
            for (int rt = 0; rt < 4; ++rt) {
                const int r = wm * 64 + rt * 16 + lr;
                const int sl = (ks * 4 + lk) ^ (r & 7);
                a[rt] = *(const s16x8*)&Xs[buf][r][sl << 3];
            }
#pragma unroll
            for (int i = 0; i < 4; ++i) {
                const int col2 = mh * 256 + i * 64 + wn * 16 + lr;
                s16x8 b = *(const s16x8*)&Wt[(size_t)col2 * K_TOT + ch * 64 + ks * 32 + lk * 8];
#pragma unroll
                for (int rt = 0; rt < 4; ++rt)
                    acc[rt][i] = __builtin_amdgcn_mfma_f32_16x16x32_bf16(
                        a[rt], b, acc[rt][i], 0, 0, 0);
            }
        }
        __builtin_amdgcn_s_setprio(0);
        if (ch <= 6) {
            int nbuf = buf + 2; if (nbuf >= 3) nbuf -= 3;
            stage(ch + 2, nbuf);
        }
        if (ch < 8) {
            __builtin_amdgcn_sched_barrier(0);
            if (ch < 7) asm volatile("s_waitcnt vmcnt(2)" ::: "memory");
            else        asm volatile("s_waitcnt vmcnt(0)" ::: "memory");
            __builtin_amdgcn_s_barrier();
            __builtin_amdgcn_sched_barrier(0);
        }
        if (++buf == 3) buf = 0;
    }

    // epilogue: acc[rt][{0,1,2,3}] = r,z,xn,hn for m-col mh*64 + wn*16 + lr
    const int mcol = mh * 64 + wn * 16 + lr;
    const float b_r  = b_ih[mcol] + b_hh[mcol];
    const float b_z  = b_ih[128 + mcol] + b_hh[128 + mcol];
    const float b_xn = b_ih[256 + mcol];
    const float b_hn = b_hh[256 + mcol];
    const int hbuf = (mcol < 64) ? 1 : 2;   // chunk7 -> buf1, chunk8 -> buf2
    const int kk   = (mcol < 64) ? mcol : mcol - 64;
#pragma unroll
    for (int rt = 0; rt < 4; ++rt) {
#pragma unroll
        for (int reg = 0; reg < 4; ++reg) {
            const int r = wm * 64 + rt * 16 + lk * 4 + reg;
            const int grow = base + r;
            if ((unsigned)grow < c) {
                const int node = Ls[r];
                const float h = bf2f(Xs[hbuf][r][(((kk >> 3) ^ (r & 7)) << 3) + (kk & 7)]);
                float rr = sigmoid_f(acc[rt][0][reg] + b_r);
                float zz = sigmoid_f(acc[rt][1][reg] + b_z);
                float nn = tanh_f(acc[rt][2][reg] + b_xn + rr * (acc[rt][3][reg] + b_hn));
                out[(size_t)node * 128 + mcol] = (1.0f - zz) * nn + zz * h;
            }
        }
    }
}

// ---------- phase 4: copy-through ----------
__global__ __launch_bounds__(256) void k_copy(const unsigned long long* __restrict__ keys,
                                              const float* __restrict__ nm,
                                              float* __restrict__ out) {
    int idx = blockIdx.x * 256 + threadIdx.x;
    int n = idx >> 5;
    if (n >= N_NODES) return;
    if (keys[n] != 0ULL) return;
    ((float4*)out)[idx] = ((const float4*)nm)[idx];
}

// ---------- phase 5a: comm = inc^T @ new_mem via LDS-transposed MFMA ----------
__global__ __launch_bounds__(512) void k_comm_t(const float* __restrict__ inc,
                                                const float* __restrict__ nm,
                                                float* __restrict__ partials) {
    __shared__ unsigned short T[2][12288];  // per buf: inc 8192 + nm 4096 shorts

    const int bid = blockIdx.x;
    const int n0 = bid * CT_CPN;
    const int n1 = min(N_NODES, n0 + CT_CPN);
    const int ng = (n1 - n0 + 31) >> 5;
    const int tid = threadIdx.x;
    const int w = tid >> 6, l = tid & 63;
    const int lr = l & 15, lk = l >> 4;

    float vi[4][4];
    float vm[4][2];

    auto load_chunk = [&](int g) {
        const int nb = n0 + g * 32 + w * 4;
#pragma unroll
        for (int ri = 0; ri < 4; ++ri) {
            const int n = nb + ri;
            const bool ok = n < n1;
#pragma unroll
            for (int j = 0; j < 4; ++j)
                vi[ri][j] = ok ? inc[(size_t)n * N_COMM + l + 64 * j] : 0.0f;
#pragma unroll
            for (int j = 0; j < 2; ++j)
                vm[ri][j] = ok ? nm[(size_t)n * DIM_M + l + 64 * j] : 0.0f;
        }
    };
    auto write_chunk = [&](int buf) {
        unsigned short* bi = &T[buf][0];
#pragma unroll
        for (int j = 0; j < 4; ++j) {
            const int cc = l + 64 * j;
            ushort4 p = make_ushort4(f2bf(vi[0][j]), f2bf(vi[1][j]),
                                     f2bf(vi[2][j]), f2bf(vi[3][j]));
            *(ushort4*)&bi[cc * 32 + ((w ^ (cc & 7)) << 2)] = p;
        }
        unsigned short* bm = &T[buf][8192];
#pragma unroll
        for (int j = 0; j < 2; ++j) {
            const int mm = l + 64 * j;
            ushort4 p = make_ushort4(f2bf(vm[0][j]), f2bf(vm[1][j]),
                                     f2bf(vm[2][j]), f2bf(vm[3][j]));
            *(ushort4*)&bm[mm * 32 + ((w ^ (mm & 7)) << 2)] = p;
        }
    };

    f32x4 acc[2][8];
#pragma unroll
    for (int ct = 0; ct < 2; ++ct)
#pragma unroll
        for (int mt = 0; mt < 8; ++mt) acc[ct][mt] = (f32x4){0.f, 0.f, 0.f, 0.f};

    auto compute_chunk = [&](int buf) {
        const unsigned short* bi = &T[buf][0];
        const unsigned short* bm = &T[buf][8192];
        s16x8 a[2];
#pragma unroll
        for (int ct = 0; ct < 2; ++ct) {
            const int cc = (w * 2 + ct) * 16 + lr;
            s16x4 lo = *(const s16x4*)&bi[cc * 32 + (((lk * 2) ^ (cc & 7)) << 2)];
            s16x4 hi = *(const s16x4*)&bi[cc * 32 + (((lk * 2 + 1) ^ (cc & 7)) << 2)];
            a[ct] = __builtin_shufflevector(lo, hi, 0, 1, 2, 3, 4, 5, 6, 7);
        }
#pragma unroll
        for (int mt = 0; mt < 8; ++mt) {
            const int mm = mt * 16 + lr;
            s16x4 lo = *(const s16x4*)&bm[mm * 32 + (((lk * 2) ^ (mm & 7)) << 2)];
            s16x4 hi = *(const s16x4*)&bm[mm * 32 + (((lk * 2 + 1) ^ (mm & 7)) << 2)];
            s16x8 b = __builtin_shufflevector(lo, hi, 0, 1, 2, 3, 4, 5, 6, 7);
            acc[0][mt] = __builtin_amdgcn_mfma_f32_16x16x32_bf16(a[0], b, acc[0][mt], 0, 0, 0);
            acc[1][mt] = __builtin_amdgcn_mfma_f32_16x16x32_bf16(a[1], b, acc[1][mt], 0, 0, 0);
        }
    };

    load_chunk(0);
    write_chunk(0);
    __syncthreads();
    for (int g = 0; g < ng; ++g) {
        if (g + 1 < ng) load_chunk(g + 1);
        compute_chunk(g & 1);
        if (g + 1 < ng) write_chunk((g + 1) & 1);
        __syncthreads();
    }

    float* p = partials + (size_t)bid * (N_COMM * DIM_M);
#pragma unroll
    for (int ct = 0; ct < 2; ++ct) {
#pragma unroll
        for (int mt = 0; mt < 8; ++mt) {
#pragma unroll
            for (int reg = 0; reg < 4; ++reg) {
                const int cc = (w * 2 + ct) * 16 + lk * 4 + reg;
                p[(size_t)cc * DIM_M + mt * 16 + lr] = acc[ct][mt][reg];
            }
        }
    }
}

// ---------- phase 5b: two-stage partial reduction ----------
__global__ __launch_bounds__(256) void k_comm2a(const float* __restrict__ partials,
                                                float* __restrict__ tmp) {
    const int bid = blockIdx.x;        // 512 blocks: y = bid>>5, x = bid&31
    const int y = bid >> 5, x = bid & 31;
    const int idx4 = x * 256 + threadIdx.x;   // [0,8192)
    float4 s = make_float4(0.f, 0.f, 0.f, 0.f);
    for (int ci = 0; ci < CT_NCH / 16; ++ci) {
        float4 v = *(const float4*)&partials[(size_t)(y * (CT_NCH / 16) + ci) * (N_COMM * DIM_M) + idx4 * 4];
        s.x += v.x; s.y += v.y; s.z += v.z; s.w += v.w;
    }
    *(float4*)&tmp[(size_t)y * (N_COMM * DIM_M) + idx4 * 4] = s;
}

__global__ __launch_bounds__(256) void k_comm2b(const float* __restrict__ tmp,
                                                float* __restrict__ out) {
    const int idx4 = blockIdx.x * 256 + threadIdx.x;   // [0,8192)
    float4 s = make_float4(0.f, 0.f, 0.f, 0.f);
    for (int y = 0; y < 16; ++y) {
        float4 v = *(const float4*)&tmp[(size_t)y * (N_COMM * DIM_M) + idx4 * 4];
        s.x += v.x; s.y += v.y; s.z += v.z; s.w += v.w;
    }
    *(float4*)&out[(size_t)N_NODES * DIM_M + idx4 * 4] = s;
}

// ================= FALLBACK PATH (small ws) =================
__global__ __launch_bounds__(256) void k_tenc(const unsigned long long* __restrict__ keys,
                                              const unsigned int* __restrict__ cnt,
                                              const int* __restrict__ list,
                                              const int* __restrict__ t,
                                              const int* __restrict__ last_update,
                                              const float* __restrict__ w_time,
                                              const float* __restrict__ b_time,
                                              unsigned short* __restrict__ tenc) {
    int idx = blockIdx.x * 256 + threadIdx.x;
    int r = idx >> 3, slot = idx & 7;
    const unsigned c = *cnt;
    const unsigned cpad = (c + 63u) & ~63u;
    if ((unsigned)r >= cpad) return;
    s16x8 v;
    if ((unsigned)r < c) {
        int node = list[r];
        unsigned long long key = keys[node];
        int ia = (int)(key & 0xffffffffull) - 1;
        int e = (ia < N_EVENTS) ? ia : ia - N_EVENTS;
        float dt = (float)(t[e] - last_update[node]);
#pragma unroll
        for (int j = 0; j < 8; ++j) {
            int cix = slot * 8 + j;
            float arg = __fadd_rn(__fmul_rn(dt, w_time[cix]), b_time[cix]);
            v[j] = (short)f2bf(cosf(arg));
        }
    } else {
#pragma unroll
        for (int j = 0; j < 8; ++j) v[j] = 0;
    }
    *(s16x8*)&tenc[(size_t)r * 64 + slot * 8] = v;
}

__global__ __launch_bounds__(256, 2) void k_gemm_fused(
    const unsigned long long* __restrict__ keys,
    const unsigned int* __restrict__ cnt,
    const int* __restrict__ list,
    const float* __restrict__ event_feat,
    const float* __restrict__ src_embeds,
    const float* __restrict__ dst_embeds,
    const float* __restrict__ mem,
    const unsigned short* __restrict__ tenc,
    const unsigned short* __restrict__ Wt,
    const float* __restrict__ b_ih,
    const float* __restrict__ b_hh,
    float* __restrict__ out) {
    __shared__ unsigned short Xs[2][4][64][8];

    const unsigned c = *cnt;
    const int base = blockIdx.x * 64;
    if ((unsigned)base >= c) return;
    const int tid = threadIdx.x;

    const int srow = tid >> 2;
    const int kslot = tid & 3;
    const int sgrow = base + srow;
    const bool valid = (unsigned)sgrow < c;
    const float *p_es = nullptr, *p_ed = nullptr, *p_ef = nullptr, *p_mem = nullptr;
    const unsigned short* p_te = nullptr;
    if (valid) {
        int node = list[sgrow];
        unsigned long long key = keys[node];
        int ia = (int)(key & 0xffffffffull) - 1;
        int e = (ia < N_EVENTS) ? ia : ia - N_EVENTS;
        const float* sp = src_embeds + (size_t)e * 128;
        const float* dp = dst_embeds + (size_t)e * 128;
        p_es = (ia < N_EVENTS) ? sp : dp;
        p_ed = (ia < N_EVENTS) ? dp : sp;
        p_ef = event_feat + (size_t)e * 128;
        p_te = tenc + (size_t)sgrow * 64;
        p_mem = mem + (size_t)node * 128;
    }

    auto stage = [&](int ch) {
        const int buf = ch & 1;
        const int k0 = ch * 32 + kslot * 8;
        s16x8 v;
        if (valid) {
            if (k0 < 384) {
                const float* p = (k0 < 128) ? (p_es + k0)
                               : (k0 < 256) ? (p_ed + (k0 - 128))
                                            : (p_ef + (k0 - 256));
                float4 a = *(const float4*)p;
                float4 b = *(const float4*)(p + 4);
                v[0] = (short)f2bf(a.x); v[1] = (short)f2bf(a.y);
                v[2] = (short)f2bf(a.z); v[3] = (short)f2bf(a.w);
                v[4] = (short)f2bf(b.x); v[5] = (short)f2bf(b.y);
                v[6] = (short)f2bf(b.z); v[7] = (short)f2bf(b.w);
            } else if (k0 < 448) {
                v = *(const s16x8*)(p_te + (k0 - 384));
            } else {
                const float* p = p_mem + (k0 - 448);
                float4 a = *(const float4*)p;
                float4 b = *(const float4*)(p + 4);
                v[0] = (short)f2bf(a.x); v[1] = (short)f2bf(a.y);
                v[2] = (short)f2bf(a.z); v[3] = (short)f2bf(a.w);
                v[4] = (short)f2bf(b.x); v[5] = (short)f2bf(b.y);
                v[6] = (short)f2bf(b.z); v[7] = (short)f2bf(b.w);
            }
        } else {
#pragma unroll
            for (int j = 0; j < 8; ++j) v[j] = 0;
        }
        *(s16x8*)&Xs[buf][kslot][srow][0] = v;
    };

    const int w = tid >> 6;
    const int l = tid & 63;
    const int lr = l & 15;
    const int lk = l >> 4;

    f32x4 acc[4][8];
#pragma unroll
    for (int rt = 0; rt < 4; ++rt)
#pragma unroll
        for (int i = 0; i < 8; ++i) acc[rt][i] = (f32x4){0.f, 0.f, 0.f, 0.f};

    stage(0);
    __syncthreads();

    for (int ch = 0; ch < 18; ++ch) {
        if (ch < 17) stage(ch + 1);
        const int buf = ch & 1;
        s16x8 a[4];
#pragma unroll
        for (int rt = 0; rt < 4; ++rt)
            a[rt] = *(const s16x8*)&Xs[buf][lk][rt * 16 + lr][0];
#pragma unroll
        for (int i = 0; i < 8; ++i) {
            const int col = (w + 4 * i) * 16 + lr;
            s16x8 b = *(const s16x8*)&Wt[(size_t)col * K_TOT + ch * 32 + lk * 8];
#pragma unroll
            for (int rt = 0; rt < 4; ++rt)
                acc[rt][i] = __builtin_amdgcn_mfma_f32_16x16x32_bf16(
                    a[rt], b, acc[rt][i], 0, 0, 0);
        }
        __syncthreads();
    }

#pragma unroll
    for (int jj = 0; jj < 2; ++jj) {
        const int mcol = (w + 4 * jj) * 16 + lr;
        const float b_r  = b_ih[mcol] + b_hh[mcol];
        const float b_z  = b_ih[128 + mcol] + b_hh[128 + mcol];
        const float b_xn = b_ih[256 + mcol];
        const float b_hn = b_hh[256 + mcol];
#pragma unroll
        for (int rt = 0; rt < 4; ++rt) {
#pragma unroll
            for (int reg = 0; reg < 4; ++reg) {
                const int grow = base + rt * 16 + lk * 4 + reg;
                if ((unsigned)grow < c) {
                    const int node = list[grow];
                    const float h = mem[(size_t)node * 128 + mcol];
                    float rr = sigmoid_f(acc[rt][0 + jj][reg] + b_r);
                    float zz = sigmoid_f(acc[rt][2 + jj][reg] + b_z);
                    float nn = tanh_f(acc[rt][4 + jj][reg] + b_xn +
                                      rr * (acc[rt][6 + jj][reg] + b_hn));
                    out[(size_t)node * 128 + mcol] = (1.0f - zz) * nn + zz * h;
                }
            }
        }
    }
}

__global__ __launch_bounds__(256) void k_comm1(const float* __restrict__ inc,
                                               const float* __restrict__ nm,
                                               float* __restrict__ partials,
                                               int nch, int cpn) {
    __shared__ float inc_s[2][8][128];
    __shared__ float mem_s[2][8][128];

    const int bid = blockIdx.x;
    const int ct2 = bid / nch;
    const int ch  = bid % nch;
    const int n0 = ch * cpn;
    const int n1 = min(N_NODES, n0 + cpn);
    const int tid = threadIdx.x;

    const int srow = tid >> 5;
    const int scol = (tid & 31) * 4;

    auto stage = [&](int g, int buf) {
        const int n = n0 + g * 8 + srow;
        float4 iv = make_float4(0.f, 0.f, 0.f, 0.f);
        float4 mv = make_float4(0.f, 0.f, 0.f, 0.f);
        if (n < n1) {
            iv = *(const float4*)(inc + (size_t)n * N_COMM + ct2 * 128 + scol);
            mv = *(const float4*)(nm + (size_t)n * DIM_M + scol);
        }
        *(float4*)&inc_s[buf][srow][scol] = iv;
        *(float4*)&mem_s[buf][srow][scol] = mv;
    };

    const int c0 = (tid >> 3) * 4;
    const int mb = (tid & 7) * 4;

    float acc[4][4][4];
#pragma unroll
    for (int a = 0; a < 4; ++a)
#pragma unroll
        for (int b = 0; b < 4; ++b)
#pragma unroll
            for (int d = 0; d < 4; ++d) acc[a][b][d] = 0.0f;

    const int ngrp = (n1 - n0 + 7) >> 3;
    stage(0, 0);
    __syncthreads();

    for (int g = 0; g < ngrp; ++g) {
        if (g + 1 < ngrp) stage(g + 1, (g + 1) & 1);
        const int buf = g & 1;
#pragma unroll
        for (int i = 0; i < 8; ++i) {
            const float4 cv = *(const float4*)&inc_s[buf][i][c0];
            const float ca[4] = {cv.x, cv.y, cv.z, cv.w};
#pragma unroll
            for (int j = 0; j < 4; ++j) {
                const float4 mv = *(const float4*)&mem_s[buf][i][j * 32 + mb];
                const float ma[4] = {mv.x, mv.y, mv.z, mv.w};
#pragma unroll
                for (int ci = 0; ci < 4; ++ci)
#pragma unroll
                    for (int mi = 0; mi < 4; ++mi)
                        acc[ci][j][mi] = fmaf(ca[ci], ma[mi], acc[ci][j][mi]);
            }
        }
        __syncthreads();
    }

    float* p = partials + (size_t)bid * (128 * 128);
#pragma unroll
    for (int ci = 0; ci < 4; ++ci)
#pragma unroll
        for (int j = 0; j < 4; ++j)
            *(float4*)(p + (size_t)(c0 + ci) * 128 + j * 32 + mb) =
                make_float4(acc[ci][j][0], acc[ci][j][1], acc[ci][j][2], acc[ci][j][3]);
}

__global__ __launch_bounds__(256) void k_comm2_f(const float* __restrict__ partials,
                                                 float* __restrict__ out,
                                                 int nch) {
    int idx = blockIdx.x * 256 + threadIdx.x;
    if (idx >= N_COMM * DIM_M) return;
    int cg = idx >> 7;
    int m = idx & 127;
    int ct2 = cg >> 7;
    int cl = cg & 127;
    float s = 0.0f;
    for (int ch = 0; ch < nch; ++ch)
        s += partials[((size_t)ct2 * nch + ch) * 16384 + (size_t)cl * 128 + m];
    out[(size_t)N_NODES * DIM_M + idx] = s;
}

extern "C" void kernel_launch(void* const* d_in, const int* in_sizes, int n_in,
                              void* d_out, int out_size, void* d_ws, size_t ws_size,
                              hipStream_t stream) {
    const int* src          = (const int*)d_in[0];
    const int* dst          = (const int*)d_in[1];
    const int* t            = (const int*)d_in[2];
    const int* last_update  = (const int*)d_in[3];
    const float* event_feat = (const float*)d_in[4];
    const float* src_embeds = (const float*)d_in[5];
    const float* dst_embeds = (const float*)d_in[6];
    const float* nodes_mem  = (const float*)d_in[7];
    const float* incidence  = (const float*)d_in[8];
    const float* w_time     = (const float*)d_in[9];
    const float* b_time     = (const float*)d_in[10];
    const float* W_ih       = (const float*)d_in[11];
    const float* W_hh       = (const float*)d_in[12];
    const float* b_ih       = (const float*)d_in[13];
    const float* b_hh       = (const float*)d_in[14];
    float* out = (float*)d_out;

    char* ws = (char*)d_ws;
    unsigned long long* keys = (unsigned long long*)(ws + KEYS_OFF);
    unsigned int* cnt        = (unsigned int*)(ws + CNT_OFF);
    int* list                = (int*)(ws + LIST_OFF);
    float* w2pi              = (float*)(ws + W2PI_OFF);
    float* b2pi              = (float*)(ws + B2PI_OFF);
    unsigned short* Wt       = (unsigned short*)(ws + WT_OFF);

    const bool xfit = ws_size >= (size_t)X_OFF + (size_t)X_ROWS * (K_TOT * 2);

    hipMemsetAsync(d_ws, 0, LIST_OFF, stream);  // keys + cnt

    k_agg<<<(2 * N_EVENTS + 255) / 256, 256, 0, stream>>>(src, dst, t, keys);
    k_compact<<<(N_NODES + 255) / 256, 256, 0, stream>>>(keys, cnt, list);
    k_prep<<<1, 64, 0, stream>>>(w_time, b_time, w2pi, b2pi);

    if (xfit) {
        unsigned short* X = (unsigned short*)(ws + X_OFF);
        float* partials   = (float*)(ws + PART_M_OFF);
        float* tmp2       = (float*)(ws + TMP2_OFF);

        k_wconv<<<(GCOLS * K_TOT + 255) / 256, 256, 0, stream>>>(W_ih, W_hh, Wt);
        k_xbuild<<<4096, 256, 0, stream>>>(keys, cnt, list, t, last_update,
                                           event_feat, src_embeds, dst_embeds,
                                           nodes_mem, w2pi, b2pi, X);
        k_gemm2<<<(X_ROWS / 128) * 2, 512, 0, stream>>>(cnt, list, X, Wt, b_ih, b_hh, out);
        k_copy<<<(N_NODES * 32 + 255) / 256, 256, 0, stream>>>(keys, nodes_mem, out);
        k_comm_t<<<CT_NCH, 512, 0, stream>>>(incidence, out, partials);
        k_comm2a<<<512, 256, 0, stream>>>(partials, tmp2);
        k_comm2b<<<32, 256, 0, stream>>>(tmp2, out);
    } else {
        unsigned short* tenc = (unsigned short*)(ws + TENC_OFF);
        float* partials      = (float*)(ws + PART_F_OFF);
        int NCH = 512;
        while (NCH > 8 && (size_t)PART_F_OFF + (size_t)NCH * 131072 > ws_size) NCH >>= 1;
        int cpn = (N_NODES + NCH - 1) / NCH;

        k_wconv_old<<<(GCOLS * K_TOT + 255) / 256, 256, 0, stream>>>(W_ih, W_hh, Wt);
        k_tenc<<<(100032 * 8) / 256, 256, 0, stream>>>(keys, cnt, list, t, last_update,
                                                       w_time, b_time, tenc);
        k_gemm_fused<<<100032 / 64, 256, 0, stream>>>(keys, cnt, list, event_feat,
                                                      src_embeds, dst_embeds, nodes_mem,
                                                      tenc, Wt, b_ih, b_hh, out);
        k_copy<<<(N_NODES * 32 + 255) / 256, 256, 0, stream>>>(keys, nodes_mem, out);
        k_comm1<<<2 * NCH, 256, 0, stream>>>(incidence, out, partials, NCH, cpn);
        k_comm2_f<<<(N_COMM * DIM_M + 255) / 256, 256, 0, stream>>>(partials, out, NCH);
    }
}

// Round 8
// 202.981 us; speedup vs baseline: 9.7600x; 1.1466x over previous
//
#include <hip/hip_runtime.h>
#include <hip/hip_bf16.h>
#include <stdint.h>

#define N_NODES   100000
#define N_EVENTS  50000
#define N_COMM    256
#define DIM_M     128
#define K_TOT     576   // 448 msg + 128 mem
#define GCOLS     512
#define INV2PI    0.15915494309189535f

typedef float f32x4 __attribute__((ext_vector_type(4)));
typedef short s16x8 __attribute__((ext_vector_type(8)));
typedef short s16x4 __attribute__((ext_vector_type(4)));

// ---------------- ws layout ----------------
#define KEYS_OFF   0                     // u64[N]
#define CNT_OFF    800000                // u32
#define LIST_OFF   800008                // i32[N] -> ends 1200008
#define W2PI_OFF   1200128               // f32[64]
#define B2PI_OFF   1200384               // f32[64]
#define WT_OFF     1200640               // bf16 [512][576] -> ends 1790464
#define X_ROWS     100096
#define X_OFF      1790464               // bf16 [100096][576] = 115310592
// comm scratch OVERLAYS X region (X dead before comm runs)
#define PART_M_OFF X_OFF                 // f32 [256][256*128] = 33.5MB
#define CT_NCH     256
#define CT_CPN     392                   // 256*392 = 100352 >= 100000
#define TMP2_OFF   (PART_M_OFF + 33554432)  // f32 [16][32768] = 2MB
// fallback path:
#define TENC_OFF   1790464
#define PART_F_OFF 14594560

__device__ inline unsigned short f2bf(float x) {
    union { float f; unsigned u; } v; v.f = x;
    unsigned r = v.u + 0x7FFFu + ((v.u >> 16) & 1u);
    return (unsigned short)(r >> 16);
}
__device__ inline float bf2f(unsigned short u) {
    union { unsigned u; float f; } v; v.u = ((unsigned)u) << 16;
    return v.f;
}
__device__ inline float cos_rev(float rev) {
    float fr = rev - floorf(rev);
#if __has_builtin(__builtin_amdgcn_cosf)
    return __builtin_amdgcn_cosf(fr);
#else
    return cosf(fr * 6.283185307179586f);
#endif
}
__device__ inline float sigmoid_f(float x) { return 1.0f / (1.0f + __expf(-x)); }
__device__ inline float tanh_f(float x) {
    float t = __expf(2.0f * x);
    return 1.0f - 2.0f / (t + 1.0f);
}

// ---------- phase 1 ----------
__global__ __launch_bounds__(256) void k_agg(const int* __restrict__ src,
                                             const int* __restrict__ dst,
                                             const int* __restrict__ t,
                                             unsigned long long* __restrict__ keys) {
    int i = blockIdx.x * 256 + threadIdx.x;
    if (i >= 2 * N_EVENTS) return;
    int e = (i < N_EVENTS) ? i : i - N_EVENTS;
    int node = (i < N_EVENTS) ? src[i] : dst[e];
    unsigned long long key =
        ((unsigned long long)(unsigned)t[e] << 32) | (unsigned)(i + 1);
    atomicMax(&keys[node], key);
}

// ---------- phase 2 ----------
__global__ __launch_bounds__(256) void k_compact(const unsigned long long* __restrict__ keys,
                                                 unsigned int* __restrict__ cnt,
                                                 int* __restrict__ list) {
    int n = blockIdx.x * 256 + threadIdx.x;
    if (n >= N_NODES) return;
    if (keys[n] != 0ULL) {
        unsigned p = atomicAdd(cnt, 1u);
        list[p] = n;
    }
}

__global__ void k_prep(const float* __restrict__ w_time, const float* __restrict__ b_time,
                       float* __restrict__ w2, float* __restrict__ b2) {
    int i = threadIdx.x;
    if (i < 64) { w2[i] = w_time[i] * INV2PI; b2[i] = b_time[i] * INV2PI; }
}

// ---------- fused gate weights, GATE-INTERLEAVED layout ----------
// col2 = mh*256 + g*64 + ml; m = mh*64+ml; g: 0=r 1=z 2=xn 3=hn. [col2][k] K-contig.
__global__ __launch_bounds__(256) void k_wconv(const float* __restrict__ W_ih,
                                               const float* __restrict__ W_hh,
                                               unsigned short* __restrict__ Wt) {
    int idx = blockIdx.x * 256 + threadIdx.x;
    if (idx >= GCOLS * K_TOT) return;
    int col2 = idx / K_TOT, k = idx % K_TOT;
    int mh = col2 >> 8, rem = col2 & 255;
    int g = rem >> 6, m = mh * 64 + (rem & 63);
    float v;
    if (g == 0)      v = (k < 448) ? W_ih[(size_t)k * 384 + m]
                                   : W_hh[(size_t)(k - 448) * 384 + m];
    else if (g == 1) v = (k < 448) ? W_ih[(size_t)k * 384 + 128 + m]
                                   : W_hh[(size_t)(k - 448) * 384 + 128 + m];
    else if (g == 2) v = (k < 448) ? W_ih[(size_t)k * 384 + 256 + m] : 0.0f;
    else             v = (k < 448) ? 0.0f : W_hh[(size_t)(k - 448) * 384 + 256 + m];
    Wt[idx] = f2bf(v);
}

// ---------- old layout for fallback ----------
__global__ __launch_bounds__(256) void k_wconv_old(const float* __restrict__ W_ih,
                                                   const float* __restrict__ W_hh,
                                                   unsigned short* __restrict__ Wt) {
    int idx = blockIdx.x * 256 + threadIdx.x;
    if (idx >= GCOLS * K_TOT) return;
    int col = idx / K_TOT, k = idx % K_TOT;
    float v;
    if (col < 256) {
        v = (k < 448) ? W_ih[(size_t)k * 384 + col]
                      : W_hh[(size_t)(k - 448) * 384 + col];
    } else if (col < 384) {
        v = (k < 448) ? W_ih[(size_t)k * 384 + col] : 0.0f;
    } else {
        v = (k < 448) ? 0.0f : W_hh[(size_t)(k - 448) * 384 + (col - 128)];
    }
    Wt[idx] = f2bf(v);
}

// ---------- phase 3a: build X ----------
__global__ __launch_bounds__(256) void k_xbuild(
    const unsigned long long* __restrict__ keys,
    const unsigned int* __restrict__ cnt,
    const int* __restrict__ list,
    const int* __restrict__ t,
    const int* __restrict__ last_update,
    const float* __restrict__ event_feat,
    const float* __restrict__ src_embeds,
    const float* __restrict__ dst_embeds,
    const float* __restrict__ mem,
    const float* __restrict__ w2pi,
    const float* __restrict__ b2pi,
    unsigned short* __restrict__ X) {
    const unsigned c = *cnt;
    const unsigned cpad = (c + 127u) & ~127u;
    const unsigned total = cpad * 72u;
    for (unsigned idx = blockIdx.x * 256 + threadIdx.x; idx < total;
         idx += gridDim.x * 256) {
        const unsigned row = idx / 72u;
        const int s = (int)(idx - row * 72u);
        unsigned short* xp = X + (size_t)row * K_TOT + s * 8;
        s16x8 v;
        if (row >= c) {
#pragma unroll
            for (int j = 0; j < 8; ++j) v[j] = 0;
            *(s16x8*)xp = v;
            continue;
        }
        const int node = list[row];
        const unsigned long long key = keys[node];
        const int ia = (int)(key & 0xffffffffull) - 1;
        const int e = (ia < N_EVENTS) ? ia : ia - N_EVENTS;
        if (s < 48) {
            const float* p;
            if (s < 16)
                p = ((ia < N_EVENTS) ? src_embeds : dst_embeds) + (size_t)e * 128 + s * 8;
            else if (s < 32)
                p = ((ia < N_EVENTS) ? dst_embeds : src_embeds) + (size_t)e * 128 + (s - 16) * 8;
            else
                p = event_feat + (size_t)e * 128 + (s - 32) * 8;
            float4 a = *(const float4*)p;
            float4 b = *(const float4*)(p + 4);
            v[0] = (short)f2bf(a.x); v[1] = (short)f2bf(a.y);
            v[2] = (short)f2bf(a.z); v[3] = (short)f2bf(a.w);
            v[4] = (short)f2bf(b.x); v[5] = (short)f2bf(b.y);
            v[6] = (short)f2bf(b.z); v[7] = (short)f2bf(b.w);
        } else if (s < 56) {
            const float dt = (float)(t[e] - last_update[node]);
            const int c0 = (s - 48) * 8;
#pragma unroll
            for (int j = 0; j < 8; ++j) {
                float rev = fmaf(dt, w2pi[c0 + j], b2pi[c0 + j]);
                v[j] = (short)f2bf(cos_rev(rev));
            }
        } else {
            const float* p = mem + (size_t)node * 128 + (s - 56) * 8;
            float4 a = *(const float4*)p;
            float4 b = *(const float4*)(p + 4);
            v[0] = (short)f2bf(a.x); v[1] = (short)f2bf(a.y);
            v[2] = (short)f2bf(a.z); v[3] = (short)f2bf(a.w);
            v[4] = (short)f2bf(b.x); v[5] = (short)f2bf(b.y);
            v[6] = (short)f2bf(b.z); v[7] = (short)f2bf(b.w);
        }
        *(s16x8*)xp = v;
    }
}

// ---------- phase 3b: MFMA GEMM, A AND B both staged via global_load_lds ----------
// 512 thr = 8 waves (2M x 4N). BM=128, BN=256 (one m-half, 4 gates), BK=64.
// 3 LDS bufs x (A 16KB + B 32KB) = 144KB, depth-2 counted vmcnt(6) (pure stage
// counting: no flat loads in the K-loop, so nothing force-drains the queue).
__global__ __launch_bounds__(512, 4) void k_gemm2(
    const unsigned int* __restrict__ cnt,
    const int* __restrict__ list,
    const unsigned short* __restrict__ X,
    const unsigned short* __restrict__ Wt,
    const float* __restrict__ b_ih,
    const float* __restrict__ b_hh,
    float* __restrict__ out) {
    __shared__ unsigned short As[3][128][64];  // 48 KB
    __shared__ unsigned short Bs[3][256][64];  // 96 KB
    __shared__ int Ls[128];

    const unsigned c = *cnt;
    const int rb = blockIdx.x >> 1;
    const int mh = blockIdx.x & 1;
    const int base = rb * 128;
    if ((unsigned)base >= c) return;
    const int tid = threadIdx.x;
    const int w = tid >> 6, l = tid & 63;
    const int lr = l & 15, lk = l >> 4;
    const int wm = w >> 2, wn = w & 3;

    if (tid < 128)
        Ls[tid] = ((unsigned)(base + tid) < c) ? list[base + tid] : 0;

    // staging identity: r8 = tid>>3 in [0,64); slot sj = tid&7; src slot = sj^(r8&7)
    const int r8 = tid >> 3;
    const int sj = tid & 7;
    const int srcsl = (sj ^ (r8 & 7)) << 3;
    const unsigned short* gA0 = X + (size_t)(base + r8) * K_TOT + srcsl;
    const unsigned short* gA1 = X + (size_t)(base + 64 + r8) * K_TOT + srcsl;
    const unsigned short* gB0 = Wt + (size_t)(mh * 256 + r8) * K_TOT + srcsl;

#define GLD(SRC, DST) __builtin_amdgcn_global_load_lds( \
        (const __attribute__((address_space(1))) unsigned int*)(SRC), \
        (__attribute__((address_space(3))) unsigned int*)(DST), 16, 0, 0)

    auto stage = [&](int ch, int buf) {
        GLD(gA0 + ch * 64, &As[buf][w * 8][0]);
        GLD(gA1 + ch * 64, &As[buf][64 + w * 8][0]);
        GLD(gB0 + ch * 64,                          &Bs[buf][w * 8][0]);
        GLD(gB0 + (size_t)64 * K_TOT + ch * 64,     &Bs[buf][64 + w * 8][0]);
        GLD(gB0 + (size_t)128 * K_TOT + ch * 64,    &Bs[buf][128 + w * 8][0]);
        GLD(gB0 + (size_t)192 * K_TOT + ch * 64,    &Bs[buf][192 + w * 8][0]);
    };

    f32x4 acc[4][4];  // [row-tile][gate]
#pragma unroll
    for (int rt = 0; rt < 4; ++rt)
#pragma unroll
        for (int i = 0; i < 4; ++i) acc[rt][i] = (f32x4){0.f, 0.f, 0.f, 0.f};

    stage(0, 0);
    stage(1, 1);
    __syncthreads();   // full drain once; chunks 0,1 resident

#pragma unroll
    for (int ch = 0; ch < 9; ++ch) {
        const int buf = ch % 3;
        if (ch <= 6) stage(ch + 2, (ch + 2) % 3);
        __builtin_amdgcn_s_setprio(1);
#pragma unroll
        for (int ks = 0; ks < 2; ++ks) {
            s16x8 a[4];
#pragma unroll
            for (int rt = 0; rt < 4; ++rt) {
                const int r = wm * 64 + rt * 16 + lr;
                const int sl = (ks * 4 + lk) ^ (r & 7);
                a[rt] = *(const s16x8*)&As[buf][r][sl << 3];
            }
#pragma unroll
            for (int i = 0; i < 4; ++i) {
                const int col = i * 64 + wn * 16 + lr;     // local col in [0,256)
                const int slb = (ks * 4 + lk) ^ (col & 7);
                s16x8 b = *(const s16x8*)&Bs[buf][col][slb << 3];
#pragma unroll
                for (int rt = 0; rt < 4; ++rt)
                    acc[rt][i] = __builtin_amdgcn_mfma_f32_16x16x32_bf16(
                        a[rt], b, acc[rt][i], 0, 0, 0);
            }
        }
        __builtin_amdgcn_s_setprio(0);
        if (ch < 8) {
            __builtin_amdgcn_sched_barrier(0);
            if (ch < 7) asm volatile("s_waitcnt vmcnt(6)" ::: "memory");
            else        asm volatile("s_waitcnt vmcnt(0)" ::: "memory");
            __builtin_amdgcn_s_barrier();
            __builtin_amdgcn_sched_barrier(0);
        }
    }

    // epilogue: h from LDS A-bufs (chunk7 -> buf1, chunk8 -> buf2)
    const int mcol = mh * 64 + wn * 16 + lr;
    const float b_r  = b_ih[mcol] + b_hh[mcol];
    const float b_z  = b_ih[128 + mcol] + b_hh[128 + mcol];
    const float b_xn = b_ih[256 + mcol];
    const float b_hn = b_hh[256 + mcol];
    const int hbuf = (mcol < 64) ? 1 : 2;
    const int kk   = (mcol < 64) ? mcol : mcol - 64;
#pragma unroll
    for (int rt = 0; rt < 4; ++rt) {
#pragma unroll
        for (int reg = 0; reg < 4; ++reg) {
            const int r = wm * 64 + rt * 16 + lk * 4 + reg;
            const int grow = base + r;
            if ((unsigned)grow < c) {
                const int node = Ls[r];
                const float h = bf2f(As[hbuf][r][(((kk >> 3) ^ (r & 7)) << 3) + (kk & 7)]);
                float rr = sigmoid_f(acc[rt][0][reg] + b_r);
                float zz = sigmoid_f(acc[rt][1][reg] + b_z);
                float nn = tanh_f(acc[rt][2][reg] + b_xn + rr * (acc[rt][3][reg] + b_hn));
                out[(size_t)node * 128 + mcol] = (1.0f - zz) * nn + zz * h;
            }
        }
    }
#undef GLD
}

// ---------- phase 4: copy-through ----------
__global__ __launch_bounds__(256) void k_copy(const unsigned long long* __restrict__ keys,
                                              const float* __restrict__ nm,
                                              float* __restrict__ out) {
    int idx = blockIdx.x * 256 + threadIdx.x;
    int n = idx >> 5;
    if (n >= N_NODES) return;
    if (keys[n] != 0ULL) return;
    ((float4*)out)[idx] = ((const float4*)nm)[idx];
}

// ---------- phase 5a: comm = inc^T @ new_mem via LDS-transposed MFMA ----------
__global__ __launch_bounds__(512) void k_comm_t(const float* __restrict__ inc,
                                                const float* __restrict__ nm,
                                                float* __restrict__ partials) {
    __shared__ unsigned short T[2][12288];  // per buf: inc 8192 + nm 4096 shorts

    const int bid = blockIdx.x;
    const int n0 = bid * CT_CPN;
    const int n1 = min(N_NODES, n0 + CT_CPN);
    const int ng = (n1 - n0 + 31) >> 5;
    const int tid = threadIdx.x;
    const int w = tid >> 6, l = tid & 63;
    const int lr = l & 15, lk = l >> 4;

    float vi[4][4];
    float vm[4][2];

    auto load_chunk = [&](int g) {
        const int nb = n0 + g * 32 + w * 4;
#pragma unroll
        for (int ri = 0; ri < 4; ++ri) {
            const int n = nb + ri;
            const bool ok = n < n1;
#pragma unroll
            for (int j = 0; j < 4; ++j)
                vi[ri][j] = ok ? inc[(size_t)n * N_COMM + l + 64 * j] : 0.0f;
#pragma unroll
            for (int j = 0; j < 2; ++j)
                vm[ri][j] = ok ? nm[(size_t)n * DIM_M + l + 64 * j] : 0.0f;
        }
    };
    auto write_chunk = [&](int buf) {
        unsigned short* bi = &T[buf][0];
#pragma unroll
        for (int j = 0; j < 4; ++j) {
            const int cc = l + 64 * j;
            ushort4 p = make_ushort4(f2bf(vi[0][j]), f2bf(vi[1][j]),
                                     f2bf(vi[2][j]), f2bf(vi[3][j]));
            *(ushort4*)&bi[cc * 32 + ((w ^ (cc & 7)) << 2)] = p;
        }
        unsigned short* bm = &T[buf][8192];
#pragma unroll
        for (int j = 0; j < 2; ++j) {
            const int mm = l + 64 * j;
            ushort4 p = make_ushort4(f2bf(vm[0][j]), f2bf(vm[1][j]),
                                     f2bf(vm[2][j]), f2bf(vm[3][j]));
            *(ushort4*)&bm[mm * 32 + ((w ^ (mm & 7)) << 2)] = p;
        }
    };

    f32x4 acc[2][8];
#pragma unroll
    for (int ct = 0; ct < 2; ++ct)
#pragma unroll
        for (int mt = 0; mt < 8; ++mt) acc[ct][mt] = (f32x4){0.f, 0.f, 0.f, 0.f};

    auto compute_chunk = [&](int buf) {
        const unsigned short* bi = &T[buf][0];
        const unsigned short* bm = &T[buf][8192];
        s16x8 a[2];
#pragma unroll
        for (int ct = 0; ct < 2; ++ct) {
            const int cc = (w * 2 + ct) * 16 + lr;
            s16x4 lo = *(const s16x4*)&bi[cc * 32 + (((lk * 2) ^ (cc & 7)) << 2)];
            s16x4 hi = *(const s16x4*)&bi[cc * 32 + (((lk * 2 + 1) ^ (cc & 7)) << 2)];
            a[ct] = __builtin_shufflevector(lo, hi, 0, 1, 2, 3, 4, 5, 6, 7);
        }
#pragma unroll
        for (int mt = 0; mt < 8; ++mt) {
            const int mm = mt * 16 + lr;
            s16x4 lo = *(const s16x4*)&bm[mm * 32 + (((lk * 2) ^ (mm & 7)) << 2)];
            s16x4 hi = *(const s16x4*)&bm[mm * 32 + (((lk * 2 + 1) ^ (mm & 7)) << 2)];
            s16x8 b = __builtin_shufflevector(lo, hi, 0, 1, 2, 3, 4, 5, 6, 7);
            acc[0][mt] = __builtin_amdgcn_mfma_f32_16x16x32_bf16(a[0], b, acc[0][mt], 0, 0, 0);
            acc[1][mt] = __builtin_amdgcn_mfma_f32_16x16x32_bf16(a[1], b, acc[1][mt], 0, 0, 0);
        }
    };

    load_chunk(0);
    write_chunk(0);
    __syncthreads();
    for (int g = 0; g < ng; ++g) {
        if (g + 1 < ng) load_chunk(g + 1);
        compute_chunk(g & 1);
        if (g + 1 < ng) write_chunk((g + 1) & 1);
        __syncthreads();
    }

    float* p = partials + (size_t)bid * (N_COMM * DIM_M);
#pragma unroll
    for (int ct = 0; ct < 2; ++ct) {
#pragma unroll
        for (int mt = 0; mt < 8; ++mt) {
#pragma unroll
            for (int reg = 0; reg < 4; ++reg) {
                const int cc = (w * 2 + ct) * 16 + lk * 4 + reg;
                p[(size_t)cc * DIM_M + mt * 16 + lr] = acc[ct][mt][reg];
            }
        }
    }
}

// ---------- phase 5b: two-stage partial reduction ----------
__global__ __launch_bounds__(256) void k_comm2a(const float* __restrict__ partials,
                                                float* __restrict__ tmp) {
    const int bid = blockIdx.x;        // 512 blocks: y = bid>>5, x = bid&31
    const int y = bid >> 5, x = bid & 31;
    const int idx4 = x * 256 + threadIdx.x;   // [0,8192)
    float4 s = make_float4(0.f, 0.f, 0.f, 0.f);
    for (int ci = 0; ci < CT_NCH / 16; ++ci) {
        float4 v = *(const float4*)&partials[(size_t)(y * (CT_NCH / 16) + ci) * (N_COMM * DIM_M) + idx4 * 4];
        s.x += v.x; s.y += v.y; s.z += v.z; s.w += v.w;
    }
    *(float4*)&tmp[(size_t)y * (N_COMM * DIM_M) + idx4 * 4] = s;
}

__global__ __launch_bounds__(256) void k_comm2b(const float* __restrict__ tmp,
                                                float* __restrict__ out) {
    const int idx4 = blockIdx.x * 256 + threadIdx.x;   // [0,8192)
    float4 s = make_float4(0.f, 0.f, 0.f, 0.f);
    for (int y = 0; y < 16; ++y) {
        float4 v = *(const float4*)&tmp[(size_t)y * (N_COMM * DIM_M) + idx4 * 4];
        s.x += v.x; s.y += v.y; s.z += v.z; s.w += v.w;
    }
    *(float4*)&out[(size_t)N_NODES * DIM_M + idx4 * 4] = s;
}

// ================= FALLBACK PATH (small ws) =================
__global__ __launch_bounds__(256) void k_tenc(const unsigned long long* __restrict__ keys,
                                              const unsigned int* __restrict__ cnt,
                                              const int* __restrict__ list,
                                              const int* __restrict__ t,
                                              const int* __restrict__ last_update,
                                              const float* __restrict__ w_time,
                                              const float* __restrict__ b_time,
                                              unsigned short* __restrict__ tenc) {
    int idx = blockIdx.x * 256 + threadIdx.x;
    int r = idx >> 3, slot = idx & 7;
    const unsigned c = *cnt;
    const unsigned cpad = (c + 63u) & ~63u;
    if ((unsigned)r >= cpad) return;
    s16x8 v;
    if ((unsigned)r < c) {
        int node = list[r];
        unsigned long long key = keys[node];
        int ia = (int)(key & 0xffffffffull) - 1;
        int e = (ia < N_EVENTS) ? ia : ia - N_EVENTS;
        float dt = (float)(t[e] - last_update[node]);
#pragma unroll
        for (int j = 0; j < 8; ++j) {
            int cix = slot * 8 + j;
            float arg = __fadd_rn(__fmul_rn(dt, w_time[cix]), b_time[cix]);
            v[j] = (short)f2bf(cosf(arg));
        }
    } else {
#pragma unroll
        for (int j = 0; j < 8; ++j) v[j] = 0;
    }
    *(s16x8*)&tenc[(size_t)r * 64 + slot * 8] = v;
}

__global__ __launch_bounds__(256, 2) void k_gemm_fused(
    const unsigned long long* __restrict__ keys,
    const unsigned int* __restrict__ cnt,
    const int* __restrict__ list,
    const float* __restrict__ event_feat,
    const float* __restrict__ src_embeds,
    const float* __restrict__ dst_embeds,
    const float* __restrict__ mem,
    const unsigned short* __restrict__ tenc,
    const unsigned short* __restrict__ Wt,
    const float* __restrict__ b_ih,
    const float* __restrict__ b_hh,
    float* __restrict__ out) {
    __shared__ unsigned short Xs[2][4][64][8];

    const unsigned c = *cnt;
    const int base = blockIdx.x * 64;
    if ((unsigned)base >= c) return;
    const int tid = threadIdx.x;

    const int srow = tid >> 2;
    const int kslot = tid & 3;
    const int sgrow = base + srow;
    const bool valid = (unsigned)sgrow < c;
    const float *p_es = nullptr, *p_ed = nullptr, *p_ef = nullptr, *p_mem = nullptr;
    const unsigned short* p_te = nullptr;
    if (valid) {
        int node = list[sgrow];
        unsigned long long key = keys[node];
        int ia = (int)(key & 0xffffffffull) - 1;
        int e = (ia < N_EVENTS) ? ia : ia - N_EVENTS;
        const float* sp = src_embeds + (size_t)e * 128;
        const float* dp = dst_embeds + (size_t)e * 128;
        p_es = (ia < N_EVENTS) ? sp : dp;
        p_ed = (ia < N_EVENTS) ? dp : sp;
        p_ef = event_feat + (size_t)e * 128;
        p_te = tenc + (size_t)sgrow * 64;
        p_mem = mem + (size_t)node * 128;
    }

    auto stage = [&](int ch) {
        const int buf = ch & 1;
        const int k0 = ch * 32 + kslot * 8;
        s16x8 v;
        if (valid) {
            if (k0 < 384) {
                const float* p = (k0 < 128) ? (p_es + k0)
                               : (k0 < 256) ? (p_ed + (k0 - 128))
                                            : (p_ef + (k0 - 256));
                float4 a = *(const float4*)p;
                float4 b = *(const float4*)(p + 4);
                v[0] = (short)f2bf(a.x); v[1] = (short)f2bf(a.y);
                v[2] = (short)f2bf(a.z); v[3] = (short)f2bf(a.w);
                v[4] = (short)f2bf(b.x); v[5] = (short)f2bf(b.y);
                v[6] = (short)f2bf(b.z); v[7] = (short)f2bf(b.w);
            } else if (k0 < 448) {
                v = *(const s16x8*)(p_te + (k0 - 384));
            } else {
                const float* p = p_mem + (k0 - 448);
                float4 a = *(const float4*)p;
                float4 b = *(const float4*)(p + 4);
                v[0] = (short)f2bf(a.x); v[1] = (short)f2bf(a.y);
                v[2] = (short)f2bf(a.z); v[3] = (short)f2bf(a.w);
                v[4] = (short)f2bf(b.x); v[5] = (short)f2bf(b.y);
                v[6] = (short)f2bf(b.z); v[7] = (short)f2bf(b.w);
            }
        } else {
#pragma unroll
            for (int j = 0; j < 8; ++j) v[j] = 0;
        }
        *(s16x8*)&Xs[buf][kslot][srow][0] = v;
    };

    const int w = tid >> 6;
    const int l = tid & 63;
    const int lr = l & 15;
    const int lk = l >> 4;

    f32x4 acc[4][8];
#pragma unroll
    for (int rt = 0; rt < 4; ++rt)
#pragma unroll
        for (int i = 0; i < 8; ++i) acc[rt][i] = (f32x4){0.f, 0.f, 0.f, 0.f};

    stage(0);
    __syncthreads();

    for (int ch = 0; ch < 18; ++ch) {
        if (ch < 17) stage(ch + 1);
        const int buf = ch & 1;
        s16x8 a[4];
#pragma unroll
        for (int rt = 0; rt < 4; ++rt)
            a[rt] = *(const s16x8*)&Xs[buf][lk][rt * 16 + lr][0];
#pragma unroll
        for (int i = 0; i < 8; ++i) {
            const int col = (w + 4 * i) * 16 + lr;
            s16x8 b = *(const s16x8*)&Wt[(size_t)col * K_TOT + ch * 32 + lk * 8];
#pragma unroll
            for (int rt = 0; rt < 4; ++rt)
                acc[rt][i] = __builtin_amdgcn_mfma_f32_16x16x32_bf16(
                    a[rt], b, acc[rt][i], 0, 0, 0);
        }
        __syncthreads();
    }

#pragma unroll
    for (int jj = 0; jj < 2; ++jj) {
        const int mcol = (w + 4 * jj) * 16 + lr;
        const float b_r  = b_ih[mcol] + b_hh[mcol];
        const float b_z  = b_ih[128 + mcol] + b_hh[128 + mcol];
        const float b_xn = b_ih[256 + mcol];
        const float b_hn = b_hh[256 + mcol];
#pragma unroll
        for (int rt = 0; rt < 4; ++rt) {
#pragma unroll
            for (int reg = 0; reg < 4; ++reg) {
                const int grow = base + rt * 16 + lk * 4 + reg;
                if ((unsigned)grow < c) {
                    const int node = list[grow];
                    const float h = mem[(size_t)node * 128 + mcol];
                    float rr = sigmoid_f(acc[rt][0 + jj][reg] + b_r);
                    float zz = sigmoid_f(acc[rt][2 + jj][reg] + b_z);
                    float nn = tanh_f(acc[rt][4 + jj][reg] + b_xn +
                                      rr * (acc[rt][6 + jj][reg] + b_hn));
                    out[(size_t)node * 128 + mcol] = (1.0f - zz) * nn + zz * h;
                }
            }
        }
    }
}

__global__ __launch_bounds__(256) void k_comm1(const float* __restrict__ inc,
                                               const float* __restrict__ nm,
                                               float* __restrict__ partials,
                                               int nch, int cpn) {
    __shared__ float inc_s[2][8][128];
    __shared__ float mem_s[2][8][128];

    const int bid = blockIdx.x;
    const int ct2 = bid / nch;
    const int ch  = bid % nch;
    const int n0 = ch * cpn;
    const int n1 = min(N_NODES, n0 + cpn);
    const int tid = threadIdx.x;

    const int srow = tid >> 5;
    const int scol = (tid & 31) * 4;

    auto stage = [&](int g, int buf) {
        const int n = n0 + g * 8 + srow;
        float4 iv = make_float4(0.f, 0.f, 0.f, 0.f);
        float4 mv = make_float4(0.f, 0.f, 0.f, 0.f);
        if (n < n1) {
            iv = *(const float4*)(inc + (size_t)n * N_COMM + ct2 * 128 + scol);
            mv = *(const float4*)(nm + (size_t)n * DIM_M + scol);
        }
        *(float4*)&inc_s[buf][srow][scol] = iv;
        *(float4*)&mem_s[buf][srow][scol] = mv;
    };

    const int c0 = (tid >> 3) * 4;
    const int mb = (tid & 7) * 4;

    float acc[4][4][4];
#pragma unroll
    for (int a = 0; a < 4; ++a)
#pragma unroll
        for (int b = 0; b < 4; ++b)
#pragma unroll
            for (int d = 0; d < 4; ++d) acc[a][b][d] = 0.0f;

    const int ngrp = (n1 - n0 + 7) >> 3;
    stage(0, 0);
    __syncthreads();

    for (int g = 0; g < ngrp; ++g) {
        if (g + 1 < ngrp) stage(g + 1, (g + 1) & 1);
        const int buf = g & 1;
#pragma unroll
        for (int i = 0; i < 8; ++i) {
            const float4 cv = *(const float4*)&inc_s[buf][i][c0];
            const float ca[4] = {cv.x, cv.y, cv.z, cv.w};
#pragma unroll
            for (int j = 0; j < 4; ++j) {
                const float4 mv = *(const float4*)&mem_s[buf][i][j * 32 + mb];
                const float ma[4] = {mv.x, mv.y, mv.z, mv.w};
#pragma unroll
                for (int ci = 0; ci < 4; ++ci)
#pragma unroll
                    for (int mi = 0; mi < 4; ++mi)
                        acc[ci][j][mi] = fmaf(ca[ci], ma[mi], acc[ci][j][mi]);
            }
        }
        __syncthreads();
    }

    float* p = partials + (size_t)bid * (128 * 128);
#pragma unroll
    for (int ci = 0; ci < 4; ++ci)
#pragma unroll
        for (int j = 0; j < 4; ++j)
            *(float4*)(p + (size_t)(c0 + ci) * 128 + j * 32 + mb) =
                make_float4(acc[ci][j][0], acc[ci][j][1], acc[ci][j][2], acc[ci][j][3]);
}

__global__ __launch_bounds__(256) void k_comm2_f(const float* __restrict__ partials,
                                                 float* __restrict__ out,
                                                 int nch) {
    int idx = blockIdx.x * 256 + threadIdx.x;
    if (idx >= N_COMM * DIM_M) return;
    int cg = idx >> 7;
    int m = idx & 127;
    int ct2 = cg >> 7;
    int cl = cg & 127;
    float s = 0.0f;
    for (int ch = 0; ch < nch; ++ch)
        s += partials[((size_t)ct2 * nch + ch) * 16384 + (size_t)cl * 128 + m];
    out[(size_t)N_NODES * DIM_M + idx] = s;
}

extern "C" void kernel_launch(void* const* d_in, const int* in_sizes, int n_in,
                              void* d_out, int out_size, void* d_ws, size_t ws_size,
                              hipStream_t stream) {
    const int* src          = (const int*)d_in[0];
    const int* dst          = (const int*)d_in[1];
    const int* t            = (const int*)d_in[2];
    const int* last_update  = (const int*)d_in[3];
    const float* event_feat = (const float*)d_in[4];
    const float* src_embeds = (const float*)d_in[5];
    const float* dst_embeds = (const float*)d_in[6];
    const float* nodes_mem  = (const float*)d_in[7];
    const float* incidence  = (const float*)d_in[8];
    const float* w_time     = (const float*)d_in[9];
    const float* b_time     = (const float*)d_in[10];
    const float* W_ih       = (const float*)d_in[11];
    const float* W_hh       = (const float*)d_in[12];
    const float* b_ih       = (const float*)d_in[13];
    const float* b_hh       = (const float*)d_in[14];
    float* out = (float*)d_out;

    char* ws = (char*)d_ws;
    unsigned long long* keys = (unsigned long long*)(ws + KEYS_OFF);
    unsigned int* cnt        = (unsigned int*)(ws + CNT_OFF);
    int* list                = (int*)(ws + LIST_OFF);
    float* w2pi              = (float*)(ws + W2PI_OFF);
    float* b2pi              = (float*)(ws + B2PI_OFF);
    unsigned short* Wt       = (unsigned short*)(ws + WT_OFF);

    const bool xfit = ws_size >= (size_t)X_OFF + (size_t)X_ROWS * (K_TOT * 2);

    hipMemsetAsync(d_ws, 0, LIST_OFF, stream);  // keys + cnt

    k_agg<<<(2 * N_EVENTS + 255) / 256, 256, 0, stream>>>(src, dst, t, keys);
    k_compact<<<(N_NODES + 255) / 256, 256, 0, stream>>>(keys, cnt, list);
    k_prep<<<1, 64, 0, stream>>>(w_time, b_time, w2pi, b2pi);

    if (xfit) {
        unsigned short* X = (unsigned short*)(ws + X_OFF);
        float* partials   = (float*)(ws + PART_M_OFF);
        float* tmp2       = (float*)(ws + TMP2_OFF);

        k_wconv<<<(GCOLS * K_TOT + 255) / 256, 256, 0, stream>>>(W_ih, W_hh, Wt);
        k_xbuild<<<4096, 256, 0, stream>>>(keys, cnt, list, t, last_update,
                                           event_feat, src_embeds, dst_embeds,
                                           nodes_mem, w2pi, b2pi, X);
        k_gemm2<<<(X_ROWS / 128) * 2, 512, 0, stream>>>(cnt, list, X, Wt, b_ih, b_hh, out);
        k_copy<<<(N_NODES * 32 + 255) / 256, 256, 0, stream>>>(keys, nodes_mem, out);
        k_comm_t<<<CT_NCH, 512, 0, stream>>>(incidence, out, partials);
        k_comm2a<<<512, 256, 0, stream>>>(partials, tmp2);
        k_comm2b<<<32, 256, 0, stream>>>(tmp2, out);
    } else {
        unsigned short* tenc = (unsigned short*)(ws + TENC_OFF);
        float* partials      = (float*)(ws + PART_F_OFF);
        int NCH = 512;
        while (NCH > 8 && (size_t)PART_F_OFF + (size_t)NCH * 131072 > ws_size) NCH >>= 1;
        int cpn = (N_NODES + NCH - 1) / NCH;

        k_wconv_old<<<(GCOLS * K_TOT + 255) / 256, 256, 0, stream>>>(W_ih, W_hh, Wt);
        k_tenc<<<(100032 * 8) / 256, 256, 0, stream>>>(keys, cnt, list, t, last_update,
                                                       w_time, b_time, tenc);
        k_gemm_fused<<<100032 / 64, 256, 0, stream>>>(keys, cnt, list, event_feat,
                                                      src_embeds, dst_embeds, nodes_mem,
                                                      tenc, Wt, b_ih, b_hh, out);
        k_copy<<<(N_NODES * 32 + 255) / 256, 256, 0, stream>>>(keys, nodes_mem, out);
        k_comm1<<<2 * NCH, 256, 0, stream>>>(incidence, out, partials, NCH, cpn);
        k_comm2_f<<<(N_COMM * DIM_M + 255) / 256, 256, 0, stream>>>(partials, out, NCH);
    }
}

// Round 9
// 201.845 us; speedup vs baseline: 9.8149x; 1.0056x over previous
//
#include <hip/hip_runtime.h>
#include <hip/hip_bf16.h>
#include <stdint.h>

#define N_NODES   100000
#define N_EVENTS  50000
#define N_COMM    256
#define DIM_M     128
#define K_TOT     576   // 448 msg + 128 mem
#define GCOLS     512
#define INV2PI    0.15915494309189535f
#define XB_GRID   4096

typedef float f32x4 __attribute__((ext_vector_type(4)));
typedef short s16x8 __attribute__((ext_vector_type(8)));
typedef short s16x4 __attribute__((ext_vector_type(4)));

// ---------------- ws layout ----------------
#define KEYS_OFF   0                     // u64[N]
#define CNT_OFF    800000                // u32
#define LIST_OFF   800008                // i32[N] -> ends 1200008
#define WT_OFF     1200640               // bf16 [512][576] -> ends 1790464
#define X_ROWS     100096
#define X_OFF      1790464               // bf16 [100096][576] = 115310592
// comm scratch OVERLAYS X region (X dead before comm runs)
#define PART_M_OFF X_OFF                 // f32 [256][256*128] = 33.5MB
#define CT_NCH     256
#define CT_CPN     392                   // 256*392 = 100352 >= 100000
#define TMP2_OFF   (PART_M_OFF + 33554432)  // f32 [16][32768] = 2MB
// fallback path:
#define TENC_OFF   1790464
#define PART_F_OFF 14594560

__device__ inline unsigned short f2bf(float x) {
    union { float f; unsigned u; } v; v.f = x;
    unsigned r = v.u + 0x7FFFu + ((v.u >> 16) & 1u);
    return (unsigned short)(r >> 16);
}
__device__ inline float bf2f(unsigned short u) {
    union { unsigned u; float f; } v; v.u = ((unsigned)u) << 16;
    return v.f;
}
__device__ inline float cos_rev(float rev) {
    float fr = rev - floorf(rev);
#if __has_builtin(__builtin_amdgcn_cosf)
    return __builtin_amdgcn_cosf(fr);
#else
    return cosf(fr * 6.283185307179586f);
#endif
}
__device__ inline float sigmoid_f(float x) { return 1.0f / (1.0f + __expf(-x)); }
__device__ inline float tanh_f(float x) {
    float t = __expf(2.0f * x);
    return 1.0f - 2.0f / (t + 1.0f);
}

// ---------- phase 1 ----------
__global__ __launch_bounds__(256) void k_agg(const int* __restrict__ src,
                                             const int* __restrict__ dst,
                                             const int* __restrict__ t,
                                             unsigned long long* __restrict__ keys) {
    int i = blockIdx.x * 256 + threadIdx.x;
    if (i >= 2 * N_EVENTS) return;
    int e = (i < N_EVENTS) ? i : i - N_EVENTS;
    int node = (i < N_EVENTS) ? src[i] : dst[e];
    unsigned long long key =
        ((unsigned long long)(unsigned)t[e] << 32) | (unsigned)(i + 1);
    atomicMax(&keys[node], key);
}

// ---------- phase 2 ----------
__global__ __launch_bounds__(256) void k_compact(const unsigned long long* __restrict__ keys,
                                                 unsigned int* __restrict__ cnt,
                                                 int* __restrict__ list) {
    int n = blockIdx.x * 256 + threadIdx.x;
    if (n >= N_NODES) return;
    if (keys[n] != 0ULL) {
        unsigned p = atomicAdd(cnt, 1u);
        list[p] = n;
    }
}

// ---------- phase 3a: build X (blocks < XB_GRID) + wconv (blocks >= XB_GRID) ----------
// Wt layout (gate-interleaved): col2 = mh*256 + g*64 + ml; m = mh*64+ml;
// g: 0=r 1=z 2=xn 3=hn. [col2][k], K-contiguous.
__global__ __launch_bounds__(256) void k_xbuild(
    const unsigned long long* __restrict__ keys,
    const unsigned int* __restrict__ cnt,
    const int* __restrict__ list,
    const int* __restrict__ t,
    const int* __restrict__ last_update,
    const float* __restrict__ event_feat,
    const float* __restrict__ src_embeds,
    const float* __restrict__ dst_embeds,
    const float* __restrict__ mem,
    const float* __restrict__ w_time,
    const float* __restrict__ b_time,
    const float* __restrict__ W_ih,
    const float* __restrict__ W_hh,
    unsigned short* __restrict__ Wt,
    unsigned short* __restrict__ X) {
    if (blockIdx.x >= XB_GRID) {   // ---- fused weight conversion ----
        int idx = (blockIdx.x - XB_GRID) * 256 + threadIdx.x;
        if (idx >= GCOLS * K_TOT) return;
        int col2 = idx / K_TOT, k = idx % K_TOT;
        int mh = col2 >> 8, rem = col2 & 255;
        int g = rem >> 6, m = mh * 64 + (rem & 63);
        float v;
        if (g == 0)      v = (k < 448) ? W_ih[(size_t)k * 384 + m]
                                       : W_hh[(size_t)(k - 448) * 384 + m];
        else if (g == 1) v = (k < 448) ? W_ih[(size_t)k * 384 + 128 + m]
                                       : W_hh[(size_t)(k - 448) * 384 + 128 + m];
        else if (g == 2) v = (k < 448) ? W_ih[(size_t)k * 384 + 256 + m] : 0.0f;
        else             v = (k < 448) ? 0.0f : W_hh[(size_t)(k - 448) * 384 + 256 + m];
        Wt[idx] = f2bf(v);
        return;
    }
    const unsigned c = *cnt;
    const unsigned cpad = (c + 127u) & ~127u;
    const unsigned total = cpad * 72u;
    for (unsigned idx = blockIdx.x * 256 + threadIdx.x; idx < total;
         idx += XB_GRID * 256) {
        const unsigned row = idx / 72u;
        const int s = (int)(idx - row * 72u);
        unsigned short* xp = X + (size_t)row * K_TOT + s * 8;
        s16x8 v;
        if (row >= c) {
#pragma unroll
            for (int j = 0; j < 8; ++j) v[j] = 0;
            *(s16x8*)xp = v;
            continue;
        }
        const int node = list[row];
        const unsigned long long key = keys[node];
        const int ia = (int)(key & 0xffffffffull) - 1;
        const int e = (ia < N_EVENTS) ? ia : ia - N_EVENTS;
        if (s < 48) {
            const float* p;
            if (s < 16)
                p = ((ia < N_EVENTS) ? src_embeds : dst_embeds) + (size_t)e * 128 + s * 8;
            else if (s < 32)
                p = ((ia < N_EVENTS) ? dst_embeds : src_embeds) + (size_t)e * 128 + (s - 16) * 8;
            else
                p = event_feat + (size_t)e * 128 + (s - 32) * 8;
            float4 a = *(const float4*)p;
            float4 b = *(const float4*)(p + 4);
            v[0] = (short)f2bf(a.x); v[1] = (short)f2bf(a.y);
            v[2] = (short)f2bf(a.z); v[3] = (short)f2bf(a.w);
            v[4] = (short)f2bf(b.x); v[5] = (short)f2bf(b.y);
            v[6] = (short)f2bf(b.z); v[7] = (short)f2bf(b.w);
        } else if (s < 56) {
            const float dt = (float)(t[e] - last_update[node]);
            const int c0 = (s - 48) * 8;
#pragma unroll
            for (int j = 0; j < 8; ++j) {
                float rev = fmaf(dt, w_time[c0 + j] * INV2PI, b_time[c0 + j] * INV2PI);
                v[j] = (short)f2bf(cos_rev(rev));
            }
        } else {
            const float* p = mem + (size_t)node * 128 + (s - 56) * 8;
            float4 a = *(const float4*)p;
            float4 b = *(const float4*)(p + 4);
            v[0] = (short)f2bf(a.x); v[1] = (short)f2bf(a.y);
            v[2] = (short)f2bf(a.z); v[3] = (short)f2bf(a.w);
            v[4] = (short)f2bf(b.x); v[5] = (short)f2bf(b.y);
            v[6] = (short)f2bf(b.z); v[7] = (short)f2bf(b.w);
        }
        *(s16x8*)xp = v;
    }
}

// ---------- phase 3b: MFMA GEMM, BK=32, 3 bufs, 2 blocks/CU ----------
// 512 thr = 8 waves (2M x 4N). BM=128, BN=256 (one m-half, 4 gates).
// LDS 72.5 KB -> 2 blocks/CU -> 4 waves/SIMD. stage = 3 GLD/wave -> vmcnt(3).
__global__ __launch_bounds__(512, 4) void k_gemm2(
    const unsigned int* __restrict__ cnt,
    const int* __restrict__ list,
    const unsigned short* __restrict__ X,
    const unsigned short* __restrict__ Wt,
    const float* __restrict__ b_ih,
    const float* __restrict__ b_hh,
    float* __restrict__ out) {
    __shared__ unsigned short As[3][128][32];  // 3 x 8 KB
    __shared__ unsigned short Bs[3][256][32];  // 3 x 16 KB
    __shared__ int Ls[128];

    const unsigned c = *cnt;
    const int rb = blockIdx.x >> 1;
    const int mh = blockIdx.x & 1;
    const int base = rb * 128;
    if ((unsigned)base >= c) return;
    const int tid = threadIdx.x;
    const int w = tid >> 6, l = tid & 63;
    const int lr = l & 15, lk = l >> 4;
    const int wm = w >> 2, wn = w & 3;

    if (tid < 128)
        Ls[tid] = ((unsigned)(base + tid) < c) ? list[base + tid] : 0;

    const int mcol = mh * 64 + wn * 16 + lr;

    // ---- h preload from X (k = 448 + mcol). Issued before prologue drain:
    // these are the OLDEST vmcnt entries, so counted waits can only over-drain.
    unsigned short hreg[16];
#pragma unroll
    for (int rt = 0; rt < 4; ++rt)
#pragma unroll
        for (int reg = 0; reg < 4; ++reg) {
            const int r = wm * 64 + rt * 16 + lk * 4 + reg;
            hreg[rt * 4 + reg] = X[(size_t)(base + r) * K_TOT + 448 + mcol];
        }

    // staging: thread t -> row t>>2 in [0,128), dest slot t&3 (16B slots);
    // src slot = sd ^ ((row>>1)&3)  [4-slot swizzle, 2 lanes/bank on read]
    const int srow = tid >> 2;
    const int sd = tid & 3;
    const int ssl = (sd ^ ((srow >> 1) & 3)) << 3;
    const unsigned short* gA  = X  + (size_t)(base + srow) * K_TOT + ssl;
    const unsigned short* gB0 = Wt + (size_t)(mh * 256 + srow) * K_TOT + ssl;
    const unsigned short* gB1 = Wt + (size_t)(mh * 256 + 128 + srow) * K_TOT + ssl;

#define GLD(SRC, DST) __builtin_amdgcn_global_load_lds( \
        (const __attribute__((address_space(1))) unsigned int*)(SRC), \
        (__attribute__((address_space(3))) unsigned int*)(DST), 16, 0, 0)

    auto stage = [&](int ch, int buf) {
        GLD(gA  + ch * 32, &As[buf][w * 16][0]);
        GLD(gB0 + ch * 32, &Bs[buf][w * 16][0]);
        GLD(gB1 + ch * 32, &Bs[buf][128 + w * 16][0]);
    };

    f32x4 acc[4][4];  // [row-tile][gate]
#pragma unroll
    for (int rt = 0; rt < 4; ++rt)
#pragma unroll
        for (int i = 0; i < 4; ++i) acc[rt][i] = (f32x4){0.f, 0.f, 0.f, 0.f};

    stage(0, 0);
    stage(1, 1);
    __syncthreads();   // full drain; chunks 0,1 resident, hreg loaded

#pragma unroll
    for (int ch = 0; ch < 18; ++ch) {
        const int buf = ch % 3;
        if (ch <= 15) stage(ch + 2, (ch + 2) % 3);
        __builtin_amdgcn_s_setprio(1);
        s16x8 a[4];
#pragma unroll
        for (int rt = 0; rt < 4; ++rt) {
            const int r = wm * 64 + rt * 16 + lr;
            const int sl = lk ^ ((r >> 1) & 3);
            a[rt] = *(const s16x8*)&As[buf][r][sl << 3];
        }
#pragma unroll
        for (int i = 0; i < 4; ++i) {
            const int cl = i * 64 + wn * 16 + lr;
            const int slb = lk ^ ((cl >> 1) & 3);
            s16x8 b = *(const s16x8*)&Bs[buf][cl][slb << 3];
#pragma unroll
            for (int rt = 0; rt < 4; ++rt)
                acc[rt][i] = __builtin_amdgcn_mfma_f32_16x16x32_bf16(
                    a[rt], b, acc[rt][i], 0, 0, 0);
        }
        __builtin_amdgcn_s_setprio(0);
        if (ch < 17) {
            __builtin_amdgcn_sched_barrier(0);
            if (ch < 16) asm volatile("s_waitcnt vmcnt(3)" ::: "memory");
            else         asm volatile("s_waitcnt vmcnt(0)" ::: "memory");
            __builtin_amdgcn_s_barrier();
            __builtin_amdgcn_sched_barrier(0);
        }
    }

    // ---- epilogue: acc[rt][{0,1,2,3}] = r,z,xn,hn for column mcol ----
    const float b_r  = b_ih[mcol] + b_hh[mcol];
    const float b_z  = b_ih[128 + mcol] + b_hh[128 + mcol];
    const float b_xn = b_ih[256 + mcol];
    const float b_hn = b_hh[256 + mcol];
#pragma unroll
    for (int rt = 0; rt < 4; ++rt) {
#pragma unroll
        for (int reg = 0; reg < 4; ++reg) {
            const int r = wm * 64 + rt * 16 + lk * 4 + reg;
            const int grow = base + r;
            if ((unsigned)grow < c) {
                const int node = Ls[r];
                const float h = bf2f(hreg[rt * 4 + reg]);
                float rr = sigmoid_f(acc[rt][0][reg] + b_r);
                float zz = sigmoid_f(acc[rt][1][reg] + b_z);
                float nn = tanh_f(acc[rt][2][reg] + b_xn + rr * (acc[rt][3][reg] + b_hn));
                out[(size_t)node * 128 + mcol] = (1.0f - zz) * nn + zz * h;
            }
        }
    }
#undef GLD
}

// ---------- phase 4: copy-through ----------
__global__ __launch_bounds__(256) void k_copy(const unsigned long long* __restrict__ keys,
                                              const float* __restrict__ nm,
                                              float* __restrict__ out) {
    int idx = blockIdx.x * 256 + threadIdx.x;
    int n = idx >> 5;
    if (n >= N_NODES) return;
    if (keys[n] != 0ULL) return;
    ((float4*)out)[idx] = ((const float4*)nm)[idx];
}

// ---------- phase 5a: comm = inc^T @ new_mem via LDS-transposed MFMA ----------
__global__ __launch_bounds__(512) void k_comm_t(const float* __restrict__ inc,
                                                const float* __restrict__ nm,
                                                float* __restrict__ partials) {
    __shared__ unsigned short T[2][12288];

    const int bid = blockIdx.x;
    const int n0 = bid * CT_CPN;
    const int n1 = min(N_NODES, n0 + CT_CPN);
    const int ng = (n1 - n0 + 31) >> 5;
    const int tid = threadIdx.x;
    const int w = tid >> 6, l = tid & 63;
    const int lr = l & 15, lk = l >> 4;

    float vi[4][4];
    float vm[4][2];

    auto load_chunk = [&](int g) {
        const int nb = n0 + g * 32 + w * 4;
#pragma unroll
        for (int ri = 0; ri < 4; ++ri) {
            const int n = nb + ri;
            const bool ok = n < n1;
#pragma unroll
            for (int j = 0; j < 4; ++j)
                vi[ri][j] = ok ? inc[(size_t)n * N_COMM + l + 64 * j] : 0.0f;
#pragma unroll
            for (int j = 0; j < 2; ++j)
                vm[ri][j] = ok ? nm[(size_t)n * DIM_M + l + 64 * j] : 0.0f;
        }
    };
    auto write_chunk = [&](int buf) {
        unsigned short* bi = &T[buf][0];
#pragma unroll
        for (int j = 0; j < 4; ++j) {
            const int cc = l + 64 * j;
            ushort4 p = make_ushort4(f2bf(vi[0][j]), f2bf(vi[1][j]),
                                     f2bf(vi[2][j]), f2bf(vi[3][j]));
            *(ushort4*)&bi[cc * 32 + ((w ^ (cc & 7)) << 2)] = p;
        }
        unsigned short* bm = &T[buf][8192];
#pragma unroll
        for (int j = 0; j < 2; ++j) {
            const int mm = l + 64 * j;
            ushort4 p = make_ushort4(f2bf(vm[0][j]), f2bf(vm[1][j]),
                                     f2bf(vm[2][j]), f2bf(vm[3][j]));
            *(ushort4*)&bm[mm * 32 + ((w ^ (mm & 7)) << 2)] = p;
        }
    };

    f32x4 acc[2][8];
#pragma unroll
    for (int ct = 0; ct < 2; ++ct)
#pragma unroll
        for (int mt = 0; mt < 8; ++mt) acc[ct][mt] = (f32x4){0.f, 0.f, 0.f, 0.f};

    auto compute_chunk = [&](int buf) {
        const unsigned short* bi = &T[buf][0];
        const unsigned short* bm = &T[buf][8192];
        s16x8 a[2];
#pragma unroll
        for (int ct = 0; ct < 2; ++ct) {
            const int cc = (w * 2 + ct) * 16 + lr;
            s16x4 lo = *(const s16x4*)&bi[cc * 32 + (((lk * 2) ^ (cc & 7)) << 2)];
            s16x4 hi = *(const s16x4*)&bi[cc * 32 + (((lk * 2 + 1) ^ (cc & 7)) << 2)];
            a[ct] = __builtin_shufflevector(lo, hi, 0, 1, 2, 3, 4, 5, 6, 7);
        }
#pragma unroll
        for (int mt = 0; mt < 8; ++mt) {
            const int mm = mt * 16 + lr;
            s16x4 lo = *(const s16x4*)&bm[mm * 32 + (((lk * 2) ^ (mm & 7)) << 2)];
            s16x4 hi = *(const s16x4*)&bm[mm * 32 + (((lk * 2 + 1) ^ (mm & 7)) << 2)];
            s16x8 b = __builtin_shufflevector(lo, hi, 0, 1, 2, 3, 4, 5, 6, 7);
            acc[0][mt] = __builtin_amdgcn_mfma_f32_16x16x32_bf16(a[0], b, acc[0][mt], 0, 0, 0);
            acc[1][mt] = __builtin_amdgcn_mfma_f32_16x16x32_bf16(a[1], b, acc[1][mt], 0, 0, 0);
        }
    };

    load_chunk(0);
    write_chunk(0);
    __syncthreads();
    for (int g = 0; g < ng; ++g) {
        if (g + 1 < ng) load_chunk(g + 1);
        compute_chunk(g & 1);
        if (g + 1 < ng) write_chunk((g + 1) & 1);
        __syncthreads();
    }

    float* p = partials + (size_t)bid * (N_COMM * DIM_M);
#pragma unroll
    for (int ct = 0; ct < 2; ++ct) {
#pragma unroll
        for (int mt = 0; mt < 8; ++mt) {
#pragma unroll
            for (int reg = 0; reg < 4; ++reg) {
                const int cc = (w * 2 + ct) * 16 + lk * 4 + reg;
                p[(size_t)cc * DIM_M + mt * 16 + lr] = acc[ct][mt][reg];
            }
        }
    }
}

// ---------- phase 5b: two-stage partial reduction ----------
__global__ __launch_bounds__(256) void k_comm2a(const float* __restrict__ partials,
                                                float* __restrict__ tmp) {
    const int bid = blockIdx.x;        // 512 blocks: y = bid>>5, x = bid&31
    const int y = bid >> 5, x = bid & 31;
    const int idx4 = x * 256 + threadIdx.x;
    float4 s = make_float4(0.f, 0.f, 0.f, 0.f);
    for (int ci = 0; ci < CT_NCH / 16; ++ci) {
        float4 v = *(const float4*)&partials[(size_t)(y * (CT_NCH / 16) + ci) * (N_COMM * DIM_M) + idx4 * 4];
        s.x += v.x; s.y += v.y; s.z += v.z; s.w += v.w;
    }
    *(float4*)&tmp[(size_t)y * (N_COMM * DIM_M) + idx4 * 4] = s;
}

__global__ __launch_bounds__(256) void k_comm2b(const float* __restrict__ tmp,
                                                float* __restrict__ out) {
    const int idx4 = blockIdx.x * 256 + threadIdx.x;
    float4 s = make_float4(0.f, 0.f, 0.f, 0.f);
    for (int y = 0; y < 16; ++y) {
        float4 v = *(const float4*)&tmp[(size_t)y * (N_COMM * DIM_M) + idx4 * 4];
        s.x += v.x; s.y += v.y; s.z += v.z; s.w += v.w;
    }
    *(float4*)&out[(size_t)N_NODES * DIM_M + idx4 * 4] = s;
}

// ================= FALLBACK PATH (small ws) =================
__global__ __launch_bounds__(256) void k_wconv_old(const float* __restrict__ W_ih,
                                                   const float* __restrict__ W_hh,
                                                   unsigned short* __restrict__ Wt) {
    int idx = blockIdx.x * 256 + threadIdx.x;
    if (idx >= GCOLS * K_TOT) return;
    int col = idx / K_TOT, k = idx % K_TOT;
    float v;
    if (col < 256) {
        v = (k < 448) ? W_ih[(size_t)k * 384 + col]
                      : W_hh[(size_t)(k - 448) * 384 + col];
    } else if (col < 384) {
        v = (k < 448) ? W_ih[(size_t)k * 384 + col] : 0.0f;
    } else {
        v = (k < 448) ? 0.0f : W_hh[(size_t)(k - 448) * 384 + (col - 128)];
    }
    Wt[idx] = f2bf(v);
}

__global__ __launch_bounds__(256) void k_tenc(const unsigned long long* __restrict__ keys,
                                              const unsigned int* __restrict__ cnt,
                                              const int* __restrict__ list,
                                              const int* __restrict__ t,
                                              const int* __restrict__ last_update,
                                              const float* __restrict__ w_time,
                                              const float* __restrict__ b_time,
                                              unsigned short* __restrict__ tenc) {
    int idx = blockIdx.x * 256 + threadIdx.x;
    int r = idx >> 3, slot = idx & 7;
    const unsigned c = *cnt;
    const unsigned cpad = (c + 63u) & ~63u;
    if ((unsigned)r >= cpad) return;
    s16x8 v;
    if ((unsigned)r < c) {
        int node = list[r];
        unsigned long long key = keys[node];
        int ia = (int)(key & 0xffffffffull) - 1;
        int e = (ia < N_EVENTS) ? ia : ia - N_EVENTS;
        float dt = (float)(t[e] - last_update[node]);
#pragma unroll
        for (int j = 0; j < 8; ++j) {
            int cix = slot * 8 + j;
            float arg = __fadd_rn(__fmul_rn(dt, w_time[cix]), b_time[cix]);
            v[j] = (short)f2bf(cosf(arg));
        }
    } else {
#pragma unroll
        for (int j = 0; j < 8; ++j) v[j] = 0;
    }
    *(s16x8*)&tenc[(size_t)r * 64 + slot * 8] = v;
}

__global__ __launch_bounds__(256, 2) void k_gemm_fused(
    const unsigned long long* __restrict__ keys,
    const unsigned int* __restrict__ cnt,
    const int* __restrict__ list,
    const float* __restrict__ event_feat,
    const float* __restrict__ src_embeds,
    const float* __restrict__ dst_embeds,
    const float* __restrict__ mem,
    const unsigned short* __restrict__ tenc,
    const unsigned short* __restrict__ Wt,
    const float* __restrict__ b_ih,
    const float* __restrict__ b_hh,
    float* __restrict__ out) {
    __shared__ unsigned short Xs[2][4][64][8];

    const unsigned c = *cnt;
    const int base = blockIdx.x * 64;
    if ((unsigned)base >= c) return;
    const int tid = threadIdx.x;

    const int srow = tid >> 2;
    const int kslot = tid & 3;
    const int sgrow = base + srow;
    const bool valid = (unsigned)sgrow < c;
    const float *p_es = nullptr, *p_ed = nullptr, *p_ef = nullptr, *p_mem = nullptr;
    const unsigned short* p_te = nullptr;
    if (valid) {
        int node = list[sgrow];
        unsigned long long key = keys[node];
        int ia = (int)(key & 0xffffffffull) - 1;
        int e = (ia < N_EVENTS) ? ia : ia - N_EVENTS;
        const float* sp = src_embeds + (size_t)e * 128;
        const float* dp = dst_embeds + (size_t)e * 128;
        p_es = (ia < N_EVENTS) ? sp : dp;
        p_ed = (ia < N_EVENTS) ? dp : sp;
        p_ef = event_feat + (size_t)e * 128;
        p_te = tenc + (size_t)sgrow * 64;
        p_mem = mem + (size_t)node * 128;
    }

    auto stage = [&](int ch) {
        const int buf = ch & 1;
        const int k0 = ch * 32 + kslot * 8;
        s16x8 v;
        if (valid) {
            if (k0 < 384) {
                const float* p = (k0 < 128) ? (p_es + k0)
                               : (k0 < 256) ? (p_ed + (k0 - 128))
                                            : (p_ef + (k0 - 256));
                float4 a = *(const float4*)p;
                float4 b = *(const float4*)(p + 4);
                v[0] = (short)f2bf(a.x); v[1] = (short)f2bf(a.y);
                v[2] = (short)f2bf(a.z); v[3] = (short)f2bf(a.w);
                v[4] = (short)f2bf(b.x); v[5] = (short)f2bf(b.y);
                v[6] = (short)f2bf(b.z); v[7] = (short)f2bf(b.w);
            } else if (k0 < 448) {
                v = *(const s16x8*)(p_te + (k0 - 384));
            } else {
                const float* p = p_mem + (k0 - 448);
                float4 a = *(const float4*)p;
                float4 b = *(const float4*)(p + 4);
                v[0] = (short)f2bf(a.x); v[1] = (short)f2bf(a.y);
                v[2] = (short)f2bf(a.z); v[3] = (short)f2bf(a.w);
                v[4] = (short)f2bf(b.x); v[5] = (short)f2bf(b.y);
                v[6] = (short)f2bf(b.z); v[7] = (short)f2bf(b.w);
            }
        } else {
#pragma unroll
            for (int j = 0; j < 8; ++j) v[j] = 0;
        }
        *(s16x8*)&Xs[buf][kslot][srow][0] = v;
    };

    const int w = tid >> 6;
    const int l = tid & 63;
    const int lr = l & 15;
    const int lk = l >> 4;

    f32x4 acc[4][8];
#pragma unroll
    for (int rt = 0; rt < 4; ++rt)
#pragma unroll
        for (int i = 0; i < 8; ++i) acc[rt][i] = (f32x4){0.f, 0.f, 0.f, 0.f};

    stage(0);
    __syncthreads();

    for (int ch = 0; ch < 18; ++ch) {
        if (ch < 17) stage(ch + 1);
        const int buf = ch & 1;
        s16x8 a[4];
#pragma unroll
        for (int rt = 0; rt < 4; ++rt)
            a[rt] = *(const s16x8*)&Xs[buf][lk][rt * 16 + lr][0];
#pragma unroll
        for (int i = 0; i < 8; ++i) {
            const int col = (w + 4 * i) * 16 + lr;
            s16x8 b = *(const s16x8*)&Wt[(size_t)col * K_TOT + ch * 32 + lk * 8];
#pragma unroll
            for (int rt = 0; rt < 4; ++rt)
                acc[rt][i] = __builtin_amdgcn_mfma_f32_16x16x32_bf16(
                    a[rt], b, acc[rt][i], 0, 0, 0);
        }
        __syncthreads();
    }

#pragma unroll
    for (int jj = 0; jj < 2; ++jj) {
        const int mcol = (w + 4 * jj) * 16 + lr;
        const float b_r  = b_ih[mcol] + b_hh[mcol];
        const float b_z  = b_ih[128 + mcol] + b_hh[128 + mcol];
        const float b_xn = b_ih[256 + mcol];
        const float b_hn = b_hh[256 + mcol];
#pragma unroll
        for (int rt = 0; rt < 4; ++rt) {
#pragma unroll
            for (int reg = 0; reg < 4; ++reg) {
                const int grow = base + rt * 16 + lk * 4 + reg;
                if ((unsigned)grow < c) {
                    const int node = list[grow];
                    const float h = mem[(size_t)node * 128 + mcol];
                    float rr = sigmoid_f(acc[rt][0 + jj][reg] + b_r);
                    float zz = sigmoid_f(acc[rt][2 + jj][reg] + b_z);
                    float nn = tanh_f(acc[rt][4 + jj][reg] + b_xn +
                                      rr * (acc[rt][6 + jj][reg] + b_hn));
                    out[(size_t)node * 128 + mcol] = (1.0f - zz) * nn + zz * h;
                }
            }
        }
    }
}

__global__ __launch_bounds__(256) void k_comm1(const float* __restrict__ inc,
                                               const float* __restrict__ nm,
                                               float* __restrict__ partials,
                                               int nch, int cpn) {
    __shared__ float inc_s[2][8][128];
    __shared__ float mem_s[2][8][128];

    const int bid = blockIdx.x;
    const int ct2 = bid / nch;
    const int ch  = bid % nch;
    const int n0 = ch * cpn;
    const int n1 = min(N_NODES, n0 + cpn);
    const int tid = threadIdx.x;

    const int srow = tid >> 5;
    const int scol = (tid & 31) * 4;

    auto stage = [&](int g, int buf) {
        const int n = n0 + g * 8 + srow;
        float4 iv = make_float4(0.f, 0.f, 0.f, 0.f);
        float4 mv = make_float4(0.f, 0.f, 0.f, 0.f);
        if (n < n1) {
            iv = *(const float4*)(inc + (size_t)n * N_COMM + ct2 * 128 + scol);
            mv = *(const float4*)(nm + (size_t)n * DIM_M + scol);
        }
        *(float4*)&inc_s[buf][srow][scol] = iv;
        *(float4*)&mem_s[buf][srow][scol] = mv;
    };

    const int c0 = (tid >> 3) * 4;
    const int mb = (tid & 7) * 4;

    float acc[4][4][4];
#pragma unroll
    for (int a = 0; a < 4; ++a)
#pragma unroll
        for (int b = 0; b < 4; ++b)
#pragma unroll
            for (int d = 0; d < 4; ++d) acc[a][b][d] = 0.0f;

    const int ngrp = (n1 - n0 + 7) >> 3;
    stage(0, 0);
    __syncthreads();

    for (int g = 0; g < ngrp; ++g) {
        if (g + 1 < ngrp) stage(g + 1, (g + 1) & 1);
        const int buf = g & 1;
#pragma unroll
        for (int i = 0; i < 8; ++i) {
            const float4 cv = *(const float4*)&inc_s[buf][i][c0];
            const float ca[4] = {cv.x, cv.y, cv.z, cv.w};
#pragma unroll
            for (int j = 0; j < 4; ++j) {
                const float4 mv = *(const float4*)&mem_s[buf][i][j * 32 + mb];
                const float ma[4] = {mv.x, mv.y, mv.z, mv.w};
#pragma unroll
                for (int ci = 0; ci < 4; ++ci)
#pragma unroll
                    for (int mi = 0; mi < 4; ++mi)
                        acc[ci][j][mi] = fmaf(ca[ci], ma[mi], acc[ci][j][mi]);
            }
        }
        __syncthreads();
    }

    float* p = partials + (size_t)bid * (128 * 128);
#pragma unroll
    for (int ci = 0; ci < 4; ++ci)
#pragma unroll
        for (int j = 0; j < 4; ++j)
            *(float4*)(p + (size_t)(c0 + ci) * 128 + j * 32 + mb) =
                make_float4(acc[ci][j][0], acc[ci][j][1], acc[ci][j][2], acc[ci][j][3]);
}

__global__ __launch_bounds__(256) void k_comm2_f(const float* __restrict__ partials,
                                                 float* __restrict__ out,
                                                 int nch) {
    int idx = blockIdx.x * 256 + threadIdx.x;
    if (idx >= N_COMM * DIM_M) return;
    int cg = idx >> 7;
    int m = idx & 127;
    int ct2 = cg >> 7;
    int cl = cg & 127;
    float s = 0.0f;
    for (int ch = 0; ch < nch; ++ch)
        s += partials[((size_t)ct2 * nch + ch) * 16384 + (size_t)cl * 128 + m];
    out[(size_t)N_NODES * DIM_M + idx] = s;
}

extern "C" void kernel_launch(void* const* d_in, const int* in_sizes, int n_in,
                              void* d_out, int out_size, void* d_ws, size_t ws_size,
                              hipStream_t stream) {
    const int* src          = (const int*)d_in[0];
    const int* dst          = (const int*)d_in[1];
    const int* t            = (const int*)d_in[2];
    const int* last_update  = (const int*)d_in[3];
    const float* event_feat = (const float*)d_in[4];
    const float* src_embeds = (const float*)d_in[5];
    const float* dst_embeds = (const float*)d_in[6];
    const float* nodes_mem  = (const float*)d_in[7];
    const float* incidence  = (const float*)d_in[8];
    const float* w_time     = (const float*)d_in[9];
    const float* b_time     = (const float*)d_in[10];
    const float* W_ih       = (const float*)d_in[11];
    const float* W_hh       = (const float*)d_in[12];
    const float* b_ih       = (const float*)d_in[13];
    const float* b_hh       = (const float*)d_in[14];
    float* out = (float*)d_out;

    char* ws = (char*)d_ws;
    unsigned long long* keys = (unsigned long long*)(ws + KEYS_OFF);
    unsigned int* cnt        = (unsigned int*)(ws + CNT_OFF);
    int* list                = (int*)(ws + LIST_OFF);
    unsigned short* Wt       = (unsigned short*)(ws + WT_OFF);

    const bool xfit = ws_size >= (size_t)X_OFF + (size_t)X_ROWS * (K_TOT * 2);

    hipMemsetAsync(d_ws, 0, LIST_OFF, stream);  // keys + cnt

    k_agg<<<(2 * N_EVENTS + 255) / 256, 256, 0, stream>>>(src, dst, t, keys);
    k_compact<<<(N_NODES + 255) / 256, 256, 0, stream>>>(keys, cnt, list);

    if (xfit) {
        unsigned short* X = (unsigned short*)(ws + X_OFF);
        float* partials   = (float*)(ws + PART_M_OFF);
        float* tmp2       = (float*)(ws + TMP2_OFF);

        const int wconv_blocks = (GCOLS * K_TOT + 255) / 256;   // 1152
        k_xbuild<<<XB_GRID + wconv_blocks, 256, 0, stream>>>(
            keys, cnt, list, t, last_update, event_feat, src_embeds, dst_embeds,
            nodes_mem, w_time, b_time, W_ih, W_hh, Wt, X);
        k_gemm2<<<(X_ROWS / 128) * 2, 512, 0, stream>>>(cnt, list, X, Wt, b_ih, b_hh, out);
        k_copy<<<(N_NODES * 32 + 255) / 256, 256, 0, stream>>>(keys, nodes_mem, out);
        k_comm_t<<<CT_NCH, 512, 0, stream>>>(incidence, out, partials);
        k_comm2a<<<512, 256, 0, stream>>>(partials, tmp2);
        k_comm2b<<<32, 256, 0, stream>>>(tmp2, out);
    } else {
        unsigned short* tenc = (unsigned short*)(ws + TENC_OFF);
        float* partials      = (float*)(ws + PART_F_OFF);
        int NCH = 512;
        while (NCH > 8 && (size_t)PART_F_OFF + (size_t)NCH * 131072 > ws_size) NCH >>= 1;
        int cpn = (N_NODES + NCH - 1) / NCH;

        k_wconv_old<<<(GCOLS * K_TOT + 255) / 256, 256, 0, stream>>>(W_ih, W_hh, Wt);
        k_tenc<<<(100032 * 8) / 256, 256, 0, stream>>>(keys, cnt, list, t, last_update,
                                                       w_time, b_time, tenc);
        k_gemm_fused<<<100032 / 64, 256, 0, stream>>>(keys, cnt, list, event_feat,
                                                      src_embeds, dst_embeds, nodes_mem,
                                                      tenc, Wt, b_ih, b_hh, out);
        k_copy<<<(N_NODES * 32 + 255) / 256, 256, 0, stream>>>(keys, nodes_mem, out);
        k_comm1<<<2 * NCH, 256, 0, stream>>>(incidence, out, partials, NCH, cpn);
        k_comm2_f<<<(N_COMM * DIM_M + 255) / 256, 256, 0, stream>>>(partials, out, NCH);
    }
}